// Round 1
// baseline (525.191 us; speedup 1.0000x reference)
//
#include <hip/hip_runtime.h>
#include <math.h>

#define EPSV 1e-5f

// ---------------- workspace layout (floats) ----------------
// xsp  : (2,8,192,4096) x-branch, spatial d-major (conv input)   | reused as ybuf
// zbuf : (8,8192,192)   z-branch, token-major
// xfor : (8,8192,192)   conv output, token-major (scan input)    | reused as gbuf
// dtBC : (65536,16)     per-token dt(6),B(4),C(4),pad(2)
// hend/Pbuf/hinit : (8,64,192,4) chunk-scan state
// Mg   : (384,96)       fused W_fusion @ W_out, k-major
#define N_XSP   12582912
#define N_ZBUF  12582912
#define N_XFOR  12582912
#define N_DTBC  1048576
#define N_STATE 393216

__device__ __forceinline__ float siluf(float v) {
  return v / (1.f + __expf(-v));
}

// ---------------- Mg = [Wf[:, :96] @ W_out ; Wf[:, 96:] @ W_out], stored [k][o] ----------------
__global__ __launch_bounds__(256) void k_prepM(const float* __restrict__ Wout,
                                               const float* __restrict__ Wf,
                                               float* __restrict__ Mg) {
  int e = blockIdx.x * 256 + threadIdx.x;
  if (e >= 384 * 96) return;
  int k = e / 96, o = e - k * 96;
  int half = (k >= 192) ? 1 : 0;
  int c = k - half * 192;
  const float* wfr = Wf + o * 192 + half * 96;
  float acc = 0.f;
#pragma unroll 4
  for (int j = 0; j < 96; ++j) acc += wfr[j] * Wout[j * 192 + c];
  Mg[e] = acc;
}

// ---------------- in_proj: token-tile GEMM 96 -> 384, split x (d-major) / z (token-major) ----------------
__global__ __launch_bounds__(256) void k_inproj(const float* __restrict__ img,
                                                const float* __restrict__ text,
                                                const float* __restrict__ Wimg,
                                                const float* __restrict__ Wtxt,
                                                float* __restrict__ xsp,
                                                float* __restrict__ zbuf) {
  __shared__ __align__(16) float Xs[96 * 64];   // [c][t]
  __shared__ float Ws[64 * 97];                 // [dd][c] padded
  __shared__ float Ts[64 * 65];                 // [t][dloc] transpose staging
  int bx = blockIdx.x;
  int tile = bx & 63, b = (bx >> 6) & 7, s = bx >> 9;
  int n0 = tile * 64;
  const float* src = s ? text : img;
  const float* W = s ? Wtxt : Wimg;
  int tid = threadIdx.x;
  for (int idx = tid; idx < 96 * 64; idx += 256) {
    int c = idx >> 6, t = idx & 63;
    Xs[c * 64 + t] = src[(b * 96 + c) * 4096 + n0 + t];
  }
  int tx = tid & 15, dy = tid >> 4;
  for (int k = 0; k < 6; ++k) {
    __syncthreads();
    for (int idx = tid; idx < 64 * 96; idx += 256) {
      int dd = idx / 96, c = idx - dd * 96;
      Ws[dd * 97 + c] = W[(k * 64 + dd) * 96 + c];
    }
    __syncthreads();
    float acc[4][4] = {};
#pragma unroll 2
    for (int c = 0; c < 96; ++c) {
      float4 xv = *(const float4*)&Xs[c * 64 + tx * 4];
      float w0 = Ws[(dy * 4 + 0) * 97 + c];
      float w1 = Ws[(dy * 4 + 1) * 97 + c];
      float w2 = Ws[(dy * 4 + 2) * 97 + c];
      float w3 = Ws[(dy * 4 + 3) * 97 + c];
      acc[0][0] += xv.x * w0; acc[0][1] += xv.x * w1; acc[0][2] += xv.x * w2; acc[0][3] += xv.x * w3;
      acc[1][0] += xv.y * w0; acc[1][1] += xv.y * w1; acc[1][2] += xv.y * w2; acc[1][3] += xv.y * w3;
      acc[2][0] += xv.z * w0; acc[2][1] += xv.z * w1; acc[2][2] += xv.z * w2; acc[2][3] += xv.z * w3;
      acc[3][0] += xv.w * w0; acc[3][1] += xv.w * w1; acc[3][2] += xv.w * w2; acc[3][3] += xv.w * w3;
    }
#pragma unroll
    for (int i = 0; i < 4; ++i)
#pragma unroll
      for (int j = 0; j < 4; ++j)
        Ts[(tx * 4 + i) * 65 + dy * 4 + j] = acc[i][j];
    __syncthreads();
    if (k < 3) {  // x part -> spatial d-major
      for (int idx = tid; idx < 4096; idx += 256) {
        int dz = idx >> 6, t = idx & 63;
        xsp[((s * 8 + b) * 192 + k * 64 + dz) * 4096 + n0 + t] = Ts[t * 65 + dz];
      }
    } else {      // z part -> token-major
      for (int idx = tid; idx < 4096; idx += 256) {
        int t = idx >> 6, dz = idx & 63;
        zbuf[(b * 8192 + s * 4096 + n0 + t) * 192 + (k - 3) * 64 + dz] = Ts[t * 65 + dz];
      }
    }
  }
}

// ---------------- depthwise 3x3 conv + BN(eval) + SiLU; spatial in, token-major out ----------------
__global__ __launch_bounds__(256) void k_conv(
    const float* __restrict__ xsp,
    const float* __restrict__ cwi, const float* __restrict__ cbi,
    const float* __restrict__ bgi, const float* __restrict__ bbi,
    const float* __restrict__ bmi, const float* __restrict__ bvi,
    const float* __restrict__ cwt, const float* __restrict__ cbt,
    const float* __restrict__ bgt, const float* __restrict__ bbt,
    const float* __restrict__ bmt, const float* __restrict__ bvt,
    float* __restrict__ xfor) {
  __shared__ float I[3 * 64 * 66];  // [row][d][w padded +1 both sides]
  __shared__ float O[64 * 65];      // [w][dloc]
  int bx = blockIdx.x;
  int h = bx & 63, b = (bx >> 6) & 7, s = bx >> 9;
  const float* cw = s ? cwt : cwi;
  const float* cb = s ? cbt : cbi;
  const float* bg = s ? bgt : bgi;
  const float* bb2 = s ? bbt : bbi;
  const float* bm = s ? bmt : bmi;
  const float* bv = s ? bvt : bvi;
  int tid = threadIdx.x;
  int w = tid & 63, dg = tid >> 6;
  for (int k = 0; k < 3; ++k) {
    __syncthreads();
    for (int idx = tid; idx < 384; idx += 256) {  // zero side pads
      int r = idx >> 7, rem = idx & 127;
      int d = rem >> 1, side = rem & 1;
      I[(r * 64 + d) * 66 + side * 65] = 0.f;
    }
    for (int idx = tid; idx < 3 * 64 * 64; idx += 256) {
      int r = idx >> 12, rem = idx & 4095;
      int d = rem >> 6, ww = rem & 63;
      int hh = h - 1 + r;
      float v = 0.f;
      if ((unsigned)hh < 64u)
        v = xsp[((s * 8 + b) * 192 + k * 64 + d) * 4096 + hh * 64 + ww];
      I[(r * 64 + d) * 66 + ww + 1] = v;
    }
    __syncthreads();
#pragma unroll 4
    for (int dd = 0; dd < 16; ++dd) {
      int dl = dg * 16 + dd;
      int d = k * 64 + dl;
      const float* cwr = cw + d * 9;
      float inv = rsqrtf(bv[d] + EPSV);
      float sc = bg[d] * inv;
      float eb = (cb[d] - bm[d]) * sc + bb2[d];
      const float* r0 = &I[(0 * 64 + dl) * 66 + w];
      const float* r1 = &I[(1 * 64 + dl) * 66 + w];
      const float* r2 = &I[(2 * 64 + dl) * 66 + w];
      float a = r0[0] * cwr[0] + r0[1] * cwr[1] + r0[2] * cwr[2]
              + r1[0] * cwr[3] + r1[1] * cwr[4] + r1[2] * cwr[5]
              + r2[0] * cwr[6] + r2[1] * cwr[7] + r2[2] * cwr[8];
      O[w * 65 + dl] = siluf(a * sc + eb);
    }
    __syncthreads();
    for (int idx = tid; idx < 4096; idx += 256) {
      int t = idx >> 6, dz = idx & 63;
      xfor[(b * 8192 + s * 4096 + h * 64 + t) * 192 + k * 64 + dz] = O[t * 65 + dz];
    }
  }
}

// ---------------- x_proj: per-token 192 -> 14 (dt,B,C) ----------------
__global__ __launch_bounds__(256) void k_xproj(const float* __restrict__ xfor,
                                               const float* __restrict__ xpw,
                                               float* __restrict__ dtBC) {
  __shared__ __align__(16) float Xs[64 * 196];  // [t][c] padded to 196
  __shared__ __align__(16) float Wp[16 * 192];  // rows 14,15 zero
  __shared__ float Od[64 * 17];
  int t0 = blockIdx.x * 64;
  int tid = threadIdx.x;
  for (int idx = tid; idx < 64 * 192; idx += 256) {
    int t = idx / 192, cc = idx - t * 192;
    Xs[t * 196 + cc] = xfor[(t0 + t) * 192 + cc];
  }
  for (int idx = tid; idx < 16 * 192; idx += 256)
    Wp[idx] = (idx < 14 * 192) ? xpw[idx] : 0.f;
  __syncthreads();
  int t = tid & 63, og = tid >> 6;  // og 0..3, each owns outputs og*4 .. og*4+3
  float a0 = 0.f, a1 = 0.f, a2 = 0.f, a3 = 0.f;
#pragma unroll 4
  for (int c4 = 0; c4 < 48; ++c4) {
    float4 xv = *(const float4*)&Xs[t * 196 + c4 * 4];
    float4 w0 = *(const float4*)&Wp[(og * 4 + 0) * 192 + c4 * 4];
    float4 w1 = *(const float4*)&Wp[(og * 4 + 1) * 192 + c4 * 4];
    float4 w2 = *(const float4*)&Wp[(og * 4 + 2) * 192 + c4 * 4];
    float4 w3 = *(const float4*)&Wp[(og * 4 + 3) * 192 + c4 * 4];
    a0 += xv.x * w0.x + xv.y * w0.y + xv.z * w0.z + xv.w * w0.w;
    a1 += xv.x * w1.x + xv.y * w1.y + xv.z * w1.z + xv.w * w1.w;
    a2 += xv.x * w2.x + xv.y * w2.y + xv.z * w2.z + xv.w * w2.w;
    a3 += xv.x * w3.x + xv.y * w3.y + xv.z * w3.z + xv.w * w3.w;
  }
  Od[t * 17 + og * 4 + 0] = a0;
  Od[t * 17 + og * 4 + 1] = a1;
  Od[t * 17 + og * 4 + 2] = a2;
  Od[t * 17 + og * 4 + 3] = a3;
  __syncthreads();
  for (int idx = tid; idx < 1024; idx += 256) {
    int tt = idx >> 4, o = idx & 15;
    dtBC[(t0 + tt) * 16 + o] = Od[tt * 17 + o];
  }
}

// ---------------- chunked selective scan, pass 1: per-chunk P and h_end(from 0) ----------------
__global__ __launch_bounds__(192) void k_scan1(const float* __restrict__ xfor,
                                               const float* __restrict__ dtBC,
                                               const float* __restrict__ dtw,
                                               const float* __restrict__ dtbias,
                                               const float* __restrict__ Alog,
                                               float* __restrict__ hend,
                                               float* __restrict__ Pbuf) {
  __shared__ float SBC[128 * 16];
  __shared__ float Xt[64 * 192];
  int c = blockIdx.x & 63, b = blockIdx.x >> 6;
  int d = threadIdx.x;
  float w0 = dtw[d * 6 + 0], w1 = dtw[d * 6 + 1], w2 = dtw[d * 6 + 2];
  float w3 = dtw[d * 6 + 3], w4 = dtw[d * 6 + 4], w5 = dtw[d * 6 + 5];
  float bb = dtbias[d];
  float4 al = *(const float4*)&Alog[d * 4];
  float A0 = -__expf(al.x), A1 = -__expf(al.y), A2 = -__expf(al.z), A3 = -__expf(al.w);
  int base = b * 8192 + c * 128;
  for (int idx = d; idx < 2048; idx += 192) SBC[idx] = dtBC[base * 16 + idx];
  float h0 = 0.f, h1 = 0.f, h2 = 0.f, h3 = 0.f, sd = 0.f;
  for (int sub = 0; sub < 2; ++sub) {
    __syncthreads();
    for (int idx = d; idx < 64 * 192; idx += 192)
      Xt[idx] = xfor[(base + sub * 64) * 192 + idx];
    __syncthreads();
#pragma unroll 4
    for (int l2 = 0; l2 < 64; ++l2) {
      const float* sb = &SBC[(sub * 64 + l2) * 16];
      float pre = bb + w0 * sb[0] + w1 * sb[1] + w2 * sb[2] + w3 * sb[3] + w4 * sb[4] + w5 * sb[5];
      float delta = (pre > 20.f) ? pre : log1pf(__expf(pre));
      sd += delta;
      float dx = delta * Xt[l2 * 192 + d];
      h0 = __expf(delta * A0) * h0 + dx * sb[6];
      h1 = __expf(delta * A1) * h1 + dx * sb[7];
      h2 = __expf(delta * A2) * h2 + dx * sb[8];
      h3 = __expf(delta * A3) * h3 + dx * sb[9];
    }
  }
  int o = ((b * 64 + c) * 192 + d) * 4;
  *(float4*)&hend[o] = make_float4(h0, h1, h2, h3);
  *(float4*)&Pbuf[o] = make_float4(__expf(A0 * sd), __expf(A1 * sd), __expf(A2 * sd), __expf(A3 * sd));
}

// ---------------- scan pass 2: cross-chunk combine ----------------
__global__ __launch_bounds__(256) void k_scan2(const float* __restrict__ hend,
                                               const float* __restrict__ Pbuf,
                                               float* __restrict__ hinit) {
  int e = blockIdx.x * 256 + threadIdx.x;
  if (e >= 8 * 768) return;
  int b = e / 768, r = e - b * 768;
  float h = 0.f;
  for (int c = 0; c < 64; ++c) {
    int a = (b * 64 + c) * 768 + r;
    hinit[a] = h;
    h = Pbuf[a] * h + hend[a];
  }
}

// ---------------- scan pass 3: replay from h_init, emit y ----------------
__global__ __launch_bounds__(192) void k_scan3(const float* __restrict__ xfor,
                                               const float* __restrict__ dtBC,
                                               const float* __restrict__ dtw,
                                               const float* __restrict__ dtbias,
                                               const float* __restrict__ Alog,
                                               const float* __restrict__ Dskip,
                                               const float* __restrict__ hinit,
                                               float* __restrict__ ybuf) {
  __shared__ float SBC[128 * 16];
  __shared__ float Xt[64 * 192];
  int c = blockIdx.x & 63, b = blockIdx.x >> 6;
  int d = threadIdx.x;
  float w0 = dtw[d * 6 + 0], w1 = dtw[d * 6 + 1], w2 = dtw[d * 6 + 2];
  float w3 = dtw[d * 6 + 3], w4 = dtw[d * 6 + 4], w5 = dtw[d * 6 + 5];
  float bb = dtbias[d];
  float4 al = *(const float4*)&Alog[d * 4];
  float A0 = -__expf(al.x), A1 = -__expf(al.y), A2 = -__expf(al.z), A3 = -__expf(al.w);
  float Dv = Dskip[d];
  int base = b * 8192 + c * 128;
  for (int idx = d; idx < 2048; idx += 192) SBC[idx] = dtBC[base * 16 + idx];
  int o = ((b * 64 + c) * 192 + d) * 4;
  float4 hv = *(const float4*)&hinit[o];
  float h0 = hv.x, h1 = hv.y, h2 = hv.z, h3 = hv.w;
  for (int sub = 0; sub < 2; ++sub) {
    __syncthreads();
    for (int idx = d; idx < 64 * 192; idx += 192)
      Xt[idx] = xfor[(base + sub * 64) * 192 + idx];
    __syncthreads();
#pragma unroll 4
    for (int l2 = 0; l2 < 64; ++l2) {
      const float* sb = &SBC[(sub * 64 + l2) * 16];
      float pre = bb + w0 * sb[0] + w1 * sb[1] + w2 * sb[2] + w3 * sb[3] + w4 * sb[4] + w5 * sb[5];
      float delta = (pre > 20.f) ? pre : log1pf(__expf(pre));
      float xv = Xt[l2 * 192 + d];
      float dx = delta * xv;
      h0 = __expf(delta * A0) * h0 + dx * sb[6];
      h1 = __expf(delta * A1) * h1 + dx * sb[7];
      h2 = __expf(delta * A2) * h2 + dx * sb[8];
      h3 = __expf(delta * A3) * h3 + dx * sb[9];
      float y = h0 * sb[10] + h1 * sb[11] + h2 * sb[12] + h3 * sb[13] + Dv * xv;
      ybuf[(base + sub * 64 + l2) * 192 + d] = y;
    }
  }
}

// ---------------- LayerNorm(d_inner) + z-gate ----------------
__global__ __launch_bounds__(256) void k_lngate(const float* __restrict__ ybuf,
                                                const float* __restrict__ zbuf,
                                                const float* __restrict__ lng,
                                                const float* __restrict__ lnb,
                                                float* __restrict__ gbuf) {
  int lane = threadIdx.x & 63;
  int wv = threadIdx.x >> 6;
  for (int t = blockIdx.x * 4 + wv; t < 65536; t += gridDim.x * 4) {
    const float* yr = ybuf + t * 192;
    float y0 = yr[lane], y1 = yr[lane + 64], y2 = yr[lane + 128];
    float s = y0 + y1 + y2;
    float q = y0 * y0 + y1 * y1 + y2 * y2;
    for (int off = 32; off; off >>= 1) {
      s += __shfl_xor(s, off);
      q += __shfl_xor(q, off);
    }
    float mu = s * (1.f / 192.f);
    float var = q * (1.f / 192.f) - mu * mu;
    float rstd = rsqrtf(var + EPSV);
    const float* zr = zbuf + t * 192;
    float* gr = gbuf + t * 192;
#pragma unroll
    for (int kk = 0; kk < 3; ++kk) {
      int dd = lane + kk * 64;
      float yv = (kk == 0) ? y0 : (kk == 1) ? y1 : y2;
      float g = (yv - mu) * rstd * lng[dd] + lnb[dd];
      float z = zr[dd];
      gr[dd] = g * siluf(z);
    }
  }
}

// ---------------- fused out-proj + stream-fusion: out[b,c,h,w] ----------------
__global__ __launch_bounds__(384) void k_outfuse(const float* __restrict__ gbuf,
                                                 const float* __restrict__ Mg,
                                                 float* __restrict__ out) {
  __shared__ float Xc[192 * 66];                // [c][t] padded
  __shared__ __align__(16) float Wc[192 * 96];  // [c][o]
  __shared__ float Ts[96 * 66];                 // [o][t]
  int tile = blockIdx.x & 63, b = blockIdx.x >> 6;
  int n0 = tile * 64;
  int tid = threadIdx.x;
  int tx = tid & 15, cg = tid >> 4;  // cg 0..23
  float acc[4][4] = {};
  for (int kc = 0; kc < 2; ++kc) {
    __syncthreads();
    for (int idx = tid; idx < 64 * 192; idx += 384) {
      int t = idx / 192, cc = idx - t * 192;
      Xc[cc * 66 + t] = gbuf[(b * 8192 + kc * 4096 + n0 + t) * 192 + cc];
    }
    for (int idx = tid; idx < 192 * 96; idx += 384)
      Wc[idx] = Mg[kc * 192 * 96 + idx];
    __syncthreads();
#pragma unroll 2
    for (int cc = 0; cc < 192; ++cc) {
      float x0 = Xc[cc * 66 + tx * 4 + 0];
      float x1 = Xc[cc * 66 + tx * 4 + 1];
      float x2 = Xc[cc * 66 + tx * 4 + 2];
      float x3 = Xc[cc * 66 + tx * 4 + 3];
      float4 wv = *(const float4*)&Wc[cc * 96 + cg * 4];
      acc[0][0] += x0 * wv.x; acc[0][1] += x0 * wv.y; acc[0][2] += x0 * wv.z; acc[0][3] += x0 * wv.w;
      acc[1][0] += x1 * wv.x; acc[1][1] += x1 * wv.y; acc[1][2] += x1 * wv.z; acc[1][3] += x1 * wv.w;
      acc[2][0] += x2 * wv.x; acc[2][1] += x2 * wv.y; acc[2][2] += x2 * wv.z; acc[2][3] += x2 * wv.w;
      acc[3][0] += x3 * wv.x; acc[3][1] += x3 * wv.y; acc[3][2] += x3 * wv.z; acc[3][3] += x3 * wv.w;
    }
  }
#pragma unroll
  for (int i = 0; i < 4; ++i)
#pragma unroll
    for (int j = 0; j < 4; ++j)
      Ts[(cg * 4 + j) * 66 + tx * 4 + i] = acc[i][j];
  __syncthreads();
  for (int idx = tid; idx < 96 * 64; idx += 384) {
    int co = idx >> 6, t = idx & 63;
    out[(b * 96 + co) * 4096 + n0 + t] = Ts[co * 66 + t];
  }
}

extern "C" void kernel_launch(void* const* d_in, const int* in_sizes, int n_in,
                              void* d_out, int out_size, void* d_ws, size_t ws_size,
                              hipStream_t stream) {
  (void)in_sizes; (void)n_in; (void)out_size; (void)ws_size;
  const float* img  = (const float*)d_in[0];
  const float* text = (const float*)d_in[1];
  const float* Wii  = (const float*)d_in[2];
  const float* Wit  = (const float*)d_in[3];
  const float* cwi  = (const float*)d_in[4];
  const float* cbi  = (const float*)d_in[5];
  const float* bgi  = (const float*)d_in[6];
  const float* bbi  = (const float*)d_in[7];
  const float* bmi  = (const float*)d_in[8];
  const float* bvi  = (const float*)d_in[9];
  const float* cwt  = (const float*)d_in[10];
  const float* cbt  = (const float*)d_in[11];
  const float* bgt  = (const float*)d_in[12];
  const float* bbt  = (const float*)d_in[13];
  const float* bmt  = (const float*)d_in[14];
  const float* bvt  = (const float*)d_in[15];
  const float* xpw  = (const float*)d_in[16];
  const float* dtw  = (const float*)d_in[17];
  const float* dtb  = (const float*)d_in[18];
  const float* Alog = (const float*)d_in[19];
  const float* Dsk  = (const float*)d_in[20];
  const float* lng  = (const float*)d_in[21];
  const float* lnb  = (const float*)d_in[22];
  const float* Wout = (const float*)d_in[23];
  const float* Wfus = (const float*)d_in[24];

  float* ws    = (float*)d_ws;
  float* xsp   = ws;
  float* zbuf  = xsp + N_XSP;
  float* xfor  = zbuf + N_ZBUF;
  float* dtBC  = xfor + N_XFOR;
  float* hend  = dtBC + N_DTBC;
  float* Pbuf  = hend + N_STATE;
  float* hinit = Pbuf + N_STATE;
  float* Mg    = hinit + N_STATE;
  float* ybuf  = xsp;   // xsp dead after k_conv
  float* gbuf  = xfor;  // xfor dead after k_scan3
  float* out   = (float*)d_out;

  hipLaunchKernelGGL(k_prepM, dim3(144), dim3(256), 0, stream, Wout, Wfus, Mg);
  hipLaunchKernelGGL(k_inproj, dim3(1024), dim3(256), 0, stream, img, text, Wii, Wit, xsp, zbuf);
  hipLaunchKernelGGL(k_conv, dim3(1024), dim3(256), 0, stream, xsp,
                     cwi, cbi, bgi, bbi, bmi, bvi, cwt, cbt, bgt, bbt, bmt, bvt, xfor);
  hipLaunchKernelGGL(k_xproj, dim3(1024), dim3(256), 0, stream, xfor, xpw, dtBC);
  hipLaunchKernelGGL(k_scan1, dim3(512), dim3(192), 0, stream, xfor, dtBC, dtw, dtb, Alog, hend, Pbuf);
  hipLaunchKernelGGL(k_scan2, dim3(24), dim3(256), 0, stream, hend, Pbuf, hinit);
  hipLaunchKernelGGL(k_scan3, dim3(512), dim3(192), 0, stream, xfor, dtBC, dtw, dtb, Alog, Dsk, hinit, ybuf);
  hipLaunchKernelGGL(k_lngate, dim3(2048), dim3(256), 0, stream, ybuf, zbuf, lng, lnb, gbuf);
  hipLaunchKernelGGL(k_outfuse, dim3(512), dim3(384), 0, stream, gbuf, Mg, out);
}

// Round 2
// 428.441 us; speedup vs baseline: 1.2258x; 1.2258x over previous
//
#include <hip/hip_runtime.h>
#include <math.h>

#define EPSV 1e-5f

// ---------------- workspace layout (floats) ----------------
// xsp  : (2,8,192,4096) x-branch, d-major spatial (conv in)  | reused as gbuf
// zbuf : (8,8192,192)   z-branch, token-major
// xd   : (2,8,192,4096) conv output, d-major (scan/xproj in)
// dtBC : (65536,16)     per-token dt(6),B(4),C(4),pad(2)
// hend/Pbuf/hinit : (8,64,192,4) chunk-scan state
// Mg   : (384,96)  fused W_fusion@W_out; Wti/Wtt: (96,384) W_in^T; Wxt: (192,16) x_proj^T
#define N_XSP   12582912
#define N_ZBUF  12582912
#define N_XD    12582912
#define N_DTBC  1048576
#define N_STATE 393216

__device__ __forceinline__ float siluf(float v) {
  return v / (1.f + __expf(-v));
}

// ---------------- prep: Mg + weight transposes ----------------
__global__ __launch_bounds__(256) void k_prep(const float* __restrict__ Wout,
                                              const float* __restrict__ Wf,
                                              const float* __restrict__ Wii,
                                              const float* __restrict__ Wit,
                                              const float* __restrict__ xpw,
                                              float* __restrict__ Mg,
                                              float* __restrict__ Wti,
                                              float* __restrict__ Wtt,
                                              float* __restrict__ Wxt) {
  int e = blockIdx.x * 256 + threadIdx.x;
  if (e < 36864) {                     // Mg[k][o] = sum_j Wf[o][half*96+j]*Wout[j][k%192]
    int k = e / 96, o = e - k * 96;
    int half = (k >= 192) ? 1 : 0;
    int c = k - half * 192;
    const float* wfr = Wf + o * 192 + half * 96;
    float acc = 0.f;
#pragma unroll 4
    for (int j = 0; j < 96; ++j) acc += wfr[j] * Wout[j * 192 + c];
    Mg[e] = acc;
  } else if (e < 73728) {              // Wti[c][o] = Wii[o][c]
    int i = e - 36864;
    int o = i / 96, c = i - o * 96;
    Wti[c * 384 + o] = Wii[i];
  } else if (e < 110592) {
    int i = e - 73728;
    int o = i / 96, c = i - o * 96;
    Wtt[c * 384 + o] = Wit[i];
  } else if (e < 113664) {             // Wxt[c][o], o 14..15 zero
    int i = e - 110592;
    int c = i >> 4, o = i & 15;
    Wxt[i] = (o < 14) ? xpw[o * 192 + c] : 0.f;
  }
}

// ---------------- in_proj: 96 -> 384 per token; x -> d-major spatial, z -> token-major ----------------
__global__ __launch_bounds__(256) void k_inproj(const float* __restrict__ img,
                                                const float* __restrict__ text,
                                                const float* __restrict__ Wti,
                                                const float* __restrict__ Wtt,
                                                float* __restrict__ xsp,
                                                float* __restrict__ zbuf) {
  __shared__ __align__(16) float Xs[96 * 64];  // [c][t]
  int bx = blockIdx.x;
  int tile = bx & 63, b = (bx >> 6) & 7, s = bx >> 9;
  int n0 = tile * 64;
  const float* src = s ? text : img;
  const float* Wt = s ? Wtt : Wti;   // [96][384]
  int tid = threadIdx.x;
  for (int idx = tid; idx < 96 * 64; idx += 256) {
    int c = idx >> 6, t = idx & 63;
    Xs[idx] = src[((size_t)b * 96 + c) * 4096 + n0 + t];
  }
  __syncthreads();
  int tx = tid & 15, dy4 = (tid >> 4) * 4;
  for (int k = 0; k < 6; ++k) {
    float acc[4][4] = {};
    const float* wp = Wt + k * 64 + dy4;
#pragma unroll 2
    for (int c = 0; c < 96; ++c) {
      float4 xv = *(const float4*)&Xs[c * 64 + tx * 4];
      float4 wv = *(const float4*)&wp[c * 384];
      acc[0][0] += xv.x * wv.x; acc[0][1] += xv.x * wv.y; acc[0][2] += xv.x * wv.z; acc[0][3] += xv.x * wv.w;
      acc[1][0] += xv.y * wv.x; acc[1][1] += xv.y * wv.y; acc[1][2] += xv.y * wv.z; acc[1][3] += xv.y * wv.w;
      acc[2][0] += xv.z * wv.x; acc[2][1] += xv.z * wv.y; acc[2][2] += xv.z * wv.z; acc[2][3] += xv.z * wv.w;
      acc[3][0] += xv.w * wv.x; acc[3][1] += xv.w * wv.y; acc[3][2] += xv.w * wv.z; acc[3][3] += xv.w * wv.w;
    }
    if (k < 3) {   // x part: d-major spatial, tokens contiguous per channel
#pragma unroll
      for (int j = 0; j < 4; ++j) {
        float4 v = make_float4(acc[0][j], acc[1][j], acc[2][j], acc[3][j]);
        *(float4*)&xsp[(((size_t)s * 8 + b) * 192 + k * 64 + dy4 + j) * 4096 + n0 + tx * 4] = v;
      }
    } else {       // z part: token-major, channels contiguous per token
#pragma unroll
      for (int i = 0; i < 4; ++i) {
        float4 v = make_float4(acc[i][0], acc[i][1], acc[i][2], acc[i][3]);
        *(float4*)&zbuf[((size_t)b * 8192 + s * 4096 + n0 + tx * 4 + i) * 192 + (k - 3) * 64 + dy4] = v;
      }
    }
  }
}

// ---------------- depthwise 3x3 conv + BN + SiLU: register-marching, d-major in/out ----------------
__global__ __launch_bounds__(256) void k_conv(
    const float* __restrict__ xsp,
    const float* __restrict__ cwi, const float* __restrict__ cbi,
    const float* __restrict__ bgi, const float* __restrict__ bbi,
    const float* __restrict__ bmi, const float* __restrict__ bvi,
    const float* __restrict__ cwt, const float* __restrict__ cbt,
    const float* __restrict__ bgt, const float* __restrict__ bbt,
    const float* __restrict__ bmt, const float* __restrict__ bvt,
    float* __restrict__ xd) {
  // 1536 blocks x 4 waves: block -> (img, d-pair); wave -> (d, h-half)
  int bid = blockIdx.x;
  int img = bid / 96;                 // 0..15
  int d0 = (bid - img * 96) * 2;
  int widx = threadIdx.x >> 6;
  int lane = threadIdx.x & 63;
  int d = d0 + (widx >> 1);
  int half = widx & 1;
  int s = img >> 3;
  const float* cw = s ? cwt : cwi;
  const float* cb = s ? cbt : cbi;
  const float* bg = s ? bgt : bgi;
  const float* bb2 = s ? bbt : bbi;
  const float* bm = s ? bmt : bmi;
  const float* bv = s ? bvt : bvi;
  const float* src = xsp + ((size_t)img * 192 + d) * 4096;
  float* dst = xd + ((size_t)img * 192 + d) * 4096;
  float c0 = cw[d * 9 + 0], c1 = cw[d * 9 + 1], c2 = cw[d * 9 + 2];
  float c3 = cw[d * 9 + 3], c4 = cw[d * 9 + 4], c5 = cw[d * 9 + 5];
  float c6 = cw[d * 9 + 6], c7 = cw[d * 9 + 7], c8 = cw[d * 9 + 8];
  float sc = bg[d] * rsqrtf(bv[d] + EPSV);
  float eb = (cb[d] - bm[d]) * sc + bb2[d];
  int h0 = half * 32;
  float pc = (h0 > 0) ? src[(h0 - 1) * 64 + lane] : 0.f;
  float cc = src[h0 * 64 + lane];
  float nc = src[(h0 + 1) * 64 + lane];
  float t;
  t = __shfl_up(pc, 1);  float pl = (lane == 0) ? 0.f : t;
  t = __shfl_down(pc, 1); float pr = (lane == 63) ? 0.f : t;
  t = __shfl_up(cc, 1);  float cl = (lane == 0) ? 0.f : t;
  t = __shfl_down(cc, 1); float cr = (lane == 63) ? 0.f : t;
#pragma unroll 4
  for (int i = 0; i < 32; ++i) {
    int h = h0 + i;
    float fut = (h + 2 <= 63) ? src[(h + 2) * 64 + lane] : 0.f;
    t = __shfl_up(nc, 1);  float nl = (lane == 0) ? 0.f : t;
    t = __shfl_down(nc, 1); float nr = (lane == 63) ? 0.f : t;
    float a = pl * c0 + pc * c1 + pr * c2
            + cl * c3 + cc * c4 + cr * c5
            + nl * c6 + nc * c7 + nr * c8;
    a = a * sc + eb;
    dst[h * 64 + lane] = a / (1.f + __expf(-a));
    pl = cl; pc = cc; pr = cr;
    cl = nl; cc = nc; cr = nr;
    nc = fut;
  }
}

// ---------------- x_proj: per-token 192 -> 14, d-major input ----------------
__global__ __launch_bounds__(256) void k_xproj(const float* __restrict__ xd,
                                               const float* __restrict__ Wxt,
                                               float* __restrict__ dtBC) {
  __shared__ float Xs[192 * 65];  // [c][t] pad 65
  __shared__ float Od[64 * 17];
  int blk = blockIdx.x;
  int b = blk >> 7, rem = blk & 127, s = rem >> 6, n0 = (rem & 63) * 64;
  const float* xsrc = xd + ((size_t)s * 8 + b) * 192 * 4096 + n0;
  int tid = threadIdx.x;
  for (int idx = tid; idx < 192 * 64; idx += 256) {
    int c = idx >> 6, t2 = idx & 63;
    Xs[c * 65 + t2] = xsrc[(size_t)c * 4096 + t2];
  }
  __syncthreads();
  int t = tid & 63, og = tid >> 6;
  float a0 = 0.f, a1 = 0.f, a2 = 0.f, a3 = 0.f;
#pragma unroll 4
  for (int c = 0; c < 192; ++c) {
    float x = Xs[c * 65 + t];
    float4 wv = *(const float4*)&Wxt[c * 16 + og * 4];
    a0 += x * wv.x; a1 += x * wv.y; a2 += x * wv.z; a3 += x * wv.w;
  }
  Od[t * 17 + og * 4 + 0] = a0;
  Od[t * 17 + og * 4 + 1] = a1;
  Od[t * 17 + og * 4 + 2] = a2;
  Od[t * 17 + og * 4 + 3] = a3;
  __syncthreads();
  int t0g = b * 8192 + s * 4096 + n0;
  for (int idx = tid; idx < 1024; idx += 256) {
    int tt = idx >> 4, o = idx & 15;
    dtBC[(size_t)(t0g + tt) * 16 + o] = Od[tt * 17 + o];
  }
}

// ---------------- scan pass 1: per-chunk P and h_end(from 0) ----------------
__global__ __launch_bounds__(192) void k_scan1(const float* __restrict__ xd,
                                               const float* __restrict__ dtBC,
                                               const float* __restrict__ dtw,
                                               const float* __restrict__ dtbias,
                                               const float* __restrict__ Alog,
                                               float* __restrict__ hend,
                                               float* __restrict__ Pbuf) {
  __shared__ float SBC[128 * 16];
  __shared__ float Xt[192 * 65];  // [d][l] pad 65
  int c = blockIdx.x & 63, b = blockIdx.x >> 6;
  int s = c >> 5, cl = c & 31;
  int d = threadIdx.x;
  float w0 = dtw[d * 6 + 0], w1 = dtw[d * 6 + 1], w2 = dtw[d * 6 + 2];
  float w3 = dtw[d * 6 + 3], w4 = dtw[d * 6 + 4], w5 = dtw[d * 6 + 5];
  float bb = dtbias[d];
  float4 al = *(const float4*)&Alog[d * 4];
  float A0 = -__expf(al.x), A1 = -__expf(al.y), A2 = -__expf(al.z), A3 = -__expf(al.w);
  int base = b * 8192 + c * 128;
  const float* xsrc = xd + ((size_t)s * 8 + b) * 192 * 4096 + cl * 128;
  for (int idx = d; idx < 2048; idx += 192) SBC[idx] = dtBC[(size_t)base * 16 + idx];
  float h0 = 0.f, h1 = 0.f, h2 = 0.f, h3 = 0.f, sd = 0.f;
  for (int sub = 0; sub < 2; ++sub) {
    __syncthreads();
    for (int idx = d; idx < 192 * 64; idx += 192) {
      int dd = idx >> 6, l = idx & 63;
      Xt[dd * 65 + l] = xsrc[(size_t)dd * 4096 + sub * 64 + l];
    }
    __syncthreads();
#pragma unroll 4
    for (int l2 = 0; l2 < 64; ++l2) {
      const float* sb = &SBC[(sub * 64 + l2) * 16];
      float pre = bb + w0 * sb[0] + w1 * sb[1] + w2 * sb[2] + w3 * sb[3] + w4 * sb[4] + w5 * sb[5];
      float delta = (pre > 20.f) ? pre : log1pf(__expf(pre));
      sd += delta;
      float dx = delta * Xt[d * 65 + l2];
      h0 = __expf(delta * A0) * h0 + dx * sb[6];
      h1 = __expf(delta * A1) * h1 + dx * sb[7];
      h2 = __expf(delta * A2) * h2 + dx * sb[8];
      h3 = __expf(delta * A3) * h3 + dx * sb[9];
    }
  }
  int o = ((b * 64 + c) * 192 + d) * 4;
  *(float4*)&hend[o] = make_float4(h0, h1, h2, h3);
  *(float4*)&Pbuf[o] = make_float4(__expf(A0 * sd), __expf(A1 * sd), __expf(A2 * sd), __expf(A3 * sd));
}

// ---------------- scan pass 2: cross-chunk combine ----------------
__global__ __launch_bounds__(256) void k_scan2(const float* __restrict__ hend,
                                               const float* __restrict__ Pbuf,
                                               float* __restrict__ hinit) {
  int e = blockIdx.x * 256 + threadIdx.x;
  if (e >= 8 * 768) return;
  int b = e / 768, r = e - b * 768;
  float h = 0.f;
  for (int c = 0; c < 64; ++c) {
    int a = (b * 64 + c) * 768 + r;
    hinit[a] = h;
    h = Pbuf[a] * h + hend[a];
  }
}

// ---------------- scan pass 3 + LayerNorm + z-gate fused ----------------
__global__ __launch_bounds__(192) void k_scan3(const float* __restrict__ xd,
                                               const float* __restrict__ dtBC,
                                               const float* __restrict__ dtw,
                                               const float* __restrict__ dtbias,
                                               const float* __restrict__ Alog,
                                               const float* __restrict__ Dskip,
                                               const float* __restrict__ hinit,
                                               const float* __restrict__ zbuf,
                                               const float* __restrict__ lng,
                                               const float* __restrict__ lnb,
                                               float* __restrict__ gbuf) {
  __shared__ float SBC[128 * 16];
  __shared__ float Xt[192 * 65];  // x, overwritten in place by y
  __shared__ float Ps[192], Qs[192], Ms[64], Rs[64];
  int c = blockIdx.x & 63, b = blockIdx.x >> 6;
  int s = c >> 5, cl = c & 31;
  int d = threadIdx.x;
  float w0 = dtw[d * 6 + 0], w1 = dtw[d * 6 + 1], w2 = dtw[d * 6 + 2];
  float w3 = dtw[d * 6 + 3], w4 = dtw[d * 6 + 4], w5 = dtw[d * 6 + 5];
  float bb = dtbias[d];
  float4 al = *(const float4*)&Alog[d * 4];
  float A0 = -__expf(al.x), A1 = -__expf(al.y), A2 = -__expf(al.z), A3 = -__expf(al.w);
  float Dv = Dskip[d];
  float lg = lng[d], lb = lnb[d];
  int base = b * 8192 + c * 128;
  const float* xsrc = xd + ((size_t)s * 8 + b) * 192 * 4096 + cl * 128;
  for (int idx = d; idx < 2048; idx += 192) SBC[idx] = dtBC[(size_t)base * 16 + idx];
  int o = ((b * 64 + c) * 192 + d) * 4;
  float4 hv = *(const float4*)&hinit[o];
  float h0 = hv.x, h1 = hv.y, h2 = hv.z, h3 = hv.w;
  int l = d & 63, part = d >> 6;   // stats-phase mapping
  for (int sub = 0; sub < 2; ++sub) {
    __syncthreads();
    for (int idx = d; idx < 192 * 64; idx += 192) {
      int dd = idx >> 6, l0 = idx & 63;
      Xt[dd * 65 + l0] = xsrc[(size_t)dd * 4096 + sub * 64 + l0];
    }
    __syncthreads();
#pragma unroll 4
    for (int l2 = 0; l2 < 64; ++l2) {
      const float* sb = &SBC[(sub * 64 + l2) * 16];
      float pre = bb + w0 * sb[0] + w1 * sb[1] + w2 * sb[2] + w3 * sb[3] + w4 * sb[4] + w5 * sb[5];
      float delta = (pre > 20.f) ? pre : log1pf(__expf(pre));
      float xv = Xt[d * 65 + l2];
      float dx = delta * xv;
      h0 = __expf(delta * A0) * h0 + dx * sb[6];
      h1 = __expf(delta * A1) * h1 + dx * sb[7];
      h2 = __expf(delta * A2) * h2 + dx * sb[8];
      h3 = __expf(delta * A3) * h3 + dx * sb[9];
      Xt[d * 65 + l2] = h0 * sb[10] + h1 * sb[11] + h2 * sb[12] + h3 * sb[13] + Dv * xv;
    }
    __syncthreads();
    // per-token stats: thread -> (l, part), partial over 64 channels
    {
      float sm = 0.f, sq = 0.f;
      int dbase = part * 64;
#pragma unroll 4
      for (int dd = 0; dd < 64; ++dd) {
        float v = Xt[(dbase + dd) * 65 + l];
        sm += v; sq += v * v;
      }
      Ps[part * 64 + l] = sm; Qs[part * 64 + l] = sq;
    }
    __syncthreads();
    if (d < 64) {
      float sm = Ps[d] + Ps[64 + d] + Ps[128 + d];
      float sq = Qs[d] + Qs[64 + d] + Qs[128 + d];
      float mu = sm * (1.f / 192.f);
      float var = sq * (1.f / 192.f) - mu * mu;
      Ms[d] = mu; Rs[d] = rsqrtf(var + EPSV);
    }
    __syncthreads();
    for (int l2 = 0; l2 < 64; ++l2) {
      size_t tok = (size_t)(base + sub * 64 + l2);
      float y = Xt[d * 65 + l2];
      float g = (y - Ms[l2]) * Rs[l2] * lg + lb;
      float z = zbuf[tok * 192 + d];
      gbuf[tok * 192 + d] = g * siluf(z);
    }
  }
}

// ---------------- fused out-proj + stream-fusion ----------------
__global__ __launch_bounds__(384) void k_outfuse(const float* __restrict__ gbuf,
                                                 const float* __restrict__ Mg,
                                                 float* __restrict__ out) {
  __shared__ __align__(16) float Xc[192 * 68];  // [c][t] pad 68 (f4-aligned)
  int tile = blockIdx.x & 63, b = blockIdx.x >> 6;
  int n0 = tile * 64;
  int tid = threadIdx.x;
  int tx = tid & 15, cg = tid >> 4;  // cg 0..23
  float acc[4][4] = {};
  for (int kc = 0; kc < 2; ++kc) {
    __syncthreads();
    for (int idx = tid; idx < 64 * 192; idx += 384) {
      int t2 = idx / 192, cc = idx - t2 * 192;
      Xc[cc * 68 + t2] = gbuf[((size_t)b * 8192 + kc * 4096 + n0 + t2) * 192 + cc];
    }
    __syncthreads();
    const float* mp = Mg + kc * 18432 + cg * 4;
#pragma unroll 2
    for (int cc = 0; cc < 192; ++cc) {
      float4 xv = *(const float4*)&Xc[cc * 68 + tx * 4];
      float4 wv = *(const float4*)&mp[cc * 96];
      acc[0][0] += xv.x * wv.x; acc[0][1] += xv.x * wv.y; acc[0][2] += xv.x * wv.z; acc[0][3] += xv.x * wv.w;
      acc[1][0] += xv.y * wv.x; acc[1][1] += xv.y * wv.y; acc[1][2] += xv.y * wv.z; acc[1][3] += xv.y * wv.w;
      acc[2][0] += xv.z * wv.x; acc[2][1] += xv.z * wv.y; acc[2][2] += xv.z * wv.z; acc[2][3] += xv.z * wv.w;
      acc[3][0] += xv.w * wv.x; acc[3][1] += xv.w * wv.y; acc[3][2] += xv.w * wv.z; acc[3][3] += xv.w * wv.w;
    }
  }
#pragma unroll
  for (int j = 0; j < 4; ++j) {
    float4 v = make_float4(acc[0][j], acc[1][j], acc[2][j], acc[3][j]);
    *(float4*)&out[((size_t)b * 96 + cg * 4 + j) * 4096 + n0 + tx * 4] = v;
  }
}

extern "C" void kernel_launch(void* const* d_in, const int* in_sizes, int n_in,
                              void* d_out, int out_size, void* d_ws, size_t ws_size,
                              hipStream_t stream) {
  (void)in_sizes; (void)n_in; (void)out_size; (void)ws_size;
  const float* img  = (const float*)d_in[0];
  const float* text = (const float*)d_in[1];
  const float* Wii  = (const float*)d_in[2];
  const float* Wit  = (const float*)d_in[3];
  const float* cwi  = (const float*)d_in[4];
  const float* cbi  = (const float*)d_in[5];
  const float* bgi  = (const float*)d_in[6];
  const float* bbi  = (const float*)d_in[7];
  const float* bmi  = (const float*)d_in[8];
  const float* bvi  = (const float*)d_in[9];
  const float* cwt  = (const float*)d_in[10];
  const float* cbt  = (const float*)d_in[11];
  const float* bgt  = (const float*)d_in[12];
  const float* bbt  = (const float*)d_in[13];
  const float* bmt  = (const float*)d_in[14];
  const float* bvt  = (const float*)d_in[15];
  const float* xpw  = (const float*)d_in[16];
  const float* dtw  = (const float*)d_in[17];
  const float* dtb  = (const float*)d_in[18];
  const float* Alog = (const float*)d_in[19];
  const float* Dsk  = (const float*)d_in[20];
  const float* lng  = (const float*)d_in[21];
  const float* lnb  = (const float*)d_in[22];
  const float* Wout = (const float*)d_in[23];
  const float* Wfus = (const float*)d_in[24];

  float* ws    = (float*)d_ws;
  float* xsp   = ws;
  float* zbuf  = xsp + N_XSP;
  float* xd    = zbuf + N_ZBUF;
  float* dtBC  = xd + N_XD;
  float* hend  = dtBC + N_DTBC;
  float* Pbuf  = hend + N_STATE;
  float* hinit = Pbuf + N_STATE;
  float* Mg    = hinit + N_STATE;
  float* Wti   = Mg + 36864;
  float* Wtt   = Wti + 36864;
  float* Wxt   = Wtt + 36864;
  float* gbuf  = xsp;   // xsp dead after k_conv
  float* out   = (float*)d_out;

  hipLaunchKernelGGL(k_prep, dim3(444), dim3(256), 0, stream, Wout, Wfus, Wii, Wit, xpw, Mg, Wti, Wtt, Wxt);
  hipLaunchKernelGGL(k_inproj, dim3(1024), dim3(256), 0, stream, img, text, Wti, Wtt, xsp, zbuf);
  hipLaunchKernelGGL(k_conv, dim3(1536), dim3(256), 0, stream, xsp,
                     cwi, cbi, bgi, bbi, bmi, bvi, cwt, cbt, bgt, bbt, bmt, bvt, xd);
  hipLaunchKernelGGL(k_xproj, dim3(1024), dim3(256), 0, stream, xd, Wxt, dtBC);
  hipLaunchKernelGGL(k_scan1, dim3(512), dim3(192), 0, stream, xd, dtBC, dtw, dtb, Alog, hend, Pbuf);
  hipLaunchKernelGGL(k_scan2, dim3(24), dim3(256), 0, stream, hend, Pbuf, hinit);
  hipLaunchKernelGGL(k_scan3, dim3(512), dim3(192), 0, stream, xd, dtBC, dtw, dtb, Alog, Dsk, hinit,
                     zbuf, lng, lnb, gbuf);
  hipLaunchKernelGGL(k_outfuse, dim3(512), dim3(384), 0, stream, gbuf, Mg, out);
}

// Round 3
// 396.475 us; speedup vs baseline: 1.3247x; 1.0806x over previous
//
#include <hip/hip_runtime.h>
#include <math.h>

#define EPSV 1e-5f

// ---------------- workspace layout (floats) ----------------
// xsp  : (2,8,192,4096) x-branch, d-major spatial (conv in)  | reused as ybuf
// zbuf : (8,8192,192)   z-branch, token-major
// xd   : (2,8,192,4096) conv output, d-major (scan/xproj in)
// dtBC : (65536,16)     per-token dt(6),B(4),C(4),pad(2)
// hend/Pbuf/hinit : (8,128,192,4) chunk-scan state
// Mg   : (384,96)  fused W_fusion@W_out; Wti/Wtt: (96,384) W_in^T; Wxt: (192,16) x_proj^T
#define N_XSP   12582912
#define N_ZBUF  12582912
#define N_XD    12582912
#define N_DTBC  1048576
#define N_STATE 786432

__device__ __forceinline__ float siluf(float v) {
  return v / (1.f + __expf(-v));
}

// ---------------- prep: Mg + weight transposes ----------------
__global__ __launch_bounds__(256) void k_prep(const float* __restrict__ Wout,
                                              const float* __restrict__ Wf,
                                              const float* __restrict__ Wii,
                                              const float* __restrict__ Wit,
                                              const float* __restrict__ xpw,
                                              float* __restrict__ Mg,
                                              float* __restrict__ Wti,
                                              float* __restrict__ Wtt,
                                              float* __restrict__ Wxt) {
  int e = blockIdx.x * 256 + threadIdx.x;
  if (e < 36864) {                     // Mg[k][o] = sum_j Wf[o][half*96+j]*Wout[j][k%192]
    int k = e / 96, o = e - k * 96;
    int half = (k >= 192) ? 1 : 0;
    int c = k - half * 192;
    const float* wfr = Wf + o * 192 + half * 96;
    float acc = 0.f;
#pragma unroll 4
    for (int j = 0; j < 96; ++j) acc += wfr[j] * Wout[j * 192 + c];
    Mg[e] = acc;
  } else if (e < 73728) {              // Wti[c][o] = Wii[o][c]
    int i = e - 36864;
    int o = i / 96, c = i - o * 96;
    Wti[c * 384 + o] = Wii[i];
  } else if (e < 110592) {
    int i = e - 73728;
    int o = i / 96, c = i - o * 96;
    Wtt[c * 384 + o] = Wit[i];
  } else if (e < 113664) {             // Wxt[c][o], o 14..15 zero
    int i = e - 110592;
    int c = i >> 4, o = i & 15;
    Wxt[i] = (o < 14) ? xpw[o * 192 + c] : 0.f;
  }
}

// ---------------- in_proj: 96 -> 384 per token; x -> d-major spatial, z -> token-major ----------------
__global__ __launch_bounds__(256) void k_inproj(const float* __restrict__ img,
                                                const float* __restrict__ text,
                                                const float* __restrict__ Wti,
                                                const float* __restrict__ Wtt,
                                                float* __restrict__ xsp,
                                                float* __restrict__ zbuf) {
  __shared__ __align__(16) float Xs[96 * 64];  // [c][t]
  int bx = blockIdx.x;
  int tile = bx & 63, b = (bx >> 6) & 7, s = bx >> 9;
  int n0 = tile * 64;
  const float* src = s ? text : img;
  const float* Wt = s ? Wtt : Wti;   // [96][384]
  int tid = threadIdx.x;
  for (int idx = tid; idx < 96 * 64; idx += 256) {
    int c = idx >> 6, t = idx & 63;
    Xs[idx] = src[((size_t)b * 96 + c) * 4096 + n0 + t];
  }
  __syncthreads();
  int tx = tid & 15, dy4 = (tid >> 4) * 4;
  for (int k = 0; k < 6; ++k) {
    float acc[4][4] = {};
    const float* wp = Wt + k * 64 + dy4;
#pragma unroll 2
    for (int c = 0; c < 96; ++c) {
      float4 xv = *(const float4*)&Xs[c * 64 + tx * 4];
      float4 wv = *(const float4*)&wp[c * 384];
      acc[0][0] += xv.x * wv.x; acc[0][1] += xv.x * wv.y; acc[0][2] += xv.x * wv.z; acc[0][3] += xv.x * wv.w;
      acc[1][0] += xv.y * wv.x; acc[1][1] += xv.y * wv.y; acc[1][2] += xv.y * wv.z; acc[1][3] += xv.y * wv.w;
      acc[2][0] += xv.z * wv.x; acc[2][1] += xv.z * wv.y; acc[2][2] += xv.z * wv.z; acc[2][3] += xv.z * wv.w;
      acc[3][0] += xv.w * wv.x; acc[3][1] += xv.w * wv.y; acc[3][2] += xv.w * wv.z; acc[3][3] += xv.w * wv.w;
    }
    if (k < 3) {   // x part: d-major spatial
#pragma unroll
      for (int j = 0; j < 4; ++j) {
        float4 v = make_float4(acc[0][j], acc[1][j], acc[2][j], acc[3][j]);
        *(float4*)&xsp[(((size_t)s * 8 + b) * 192 + k * 64 + dy4 + j) * 4096 + n0 + tx * 4] = v;
      }
    } else {       // z part: token-major
#pragma unroll
      for (int i = 0; i < 4; ++i) {
        float4 v = make_float4(acc[i][0], acc[i][1], acc[i][2], acc[i][3]);
        *(float4*)&zbuf[((size_t)b * 8192 + s * 4096 + n0 + tx * 4 + i) * 192 + (k - 3) * 64 + dy4] = v;
      }
    }
  }
}

// ---------------- depthwise 3x3 conv + BN + SiLU: register-marching, d-major in/out ----------------
__global__ __launch_bounds__(256) void k_conv(
    const float* __restrict__ xsp,
    const float* __restrict__ cwi, const float* __restrict__ cbi,
    const float* __restrict__ bgi, const float* __restrict__ bbi,
    const float* __restrict__ bmi, const float* __restrict__ bvi,
    const float* __restrict__ cwt, const float* __restrict__ cbt,
    const float* __restrict__ bgt, const float* __restrict__ bbt,
    const float* __restrict__ bmt, const float* __restrict__ bvt,
    float* __restrict__ xd) {
  int bid = blockIdx.x;
  int img = bid / 96;                 // 0..15
  int d0 = (bid - img * 96) * 2;
  int widx = threadIdx.x >> 6;
  int lane = threadIdx.x & 63;
  int d = d0 + (widx >> 1);
  int half = widx & 1;
  int s = img >> 3;
  const float* cw = s ? cwt : cwi;
  const float* cb = s ? cbt : cbi;
  const float* bg = s ? bgt : bgi;
  const float* bb2 = s ? bbt : bbi;
  const float* bm = s ? bmt : bmi;
  const float* bv = s ? bvt : bvi;
  const float* src = xsp + ((size_t)img * 192 + d) * 4096;
  float* dst = xd + ((size_t)img * 192 + d) * 4096;
  float c0 = cw[d * 9 + 0], c1 = cw[d * 9 + 1], c2 = cw[d * 9 + 2];
  float c3 = cw[d * 9 + 3], c4 = cw[d * 9 + 4], c5 = cw[d * 9 + 5];
  float c6 = cw[d * 9 + 6], c7 = cw[d * 9 + 7], c8 = cw[d * 9 + 8];
  float sc = bg[d] * rsqrtf(bv[d] + EPSV);
  float eb = (cb[d] - bm[d]) * sc + bb2[d];
  int h0 = half * 32;
  float pc = (h0 > 0) ? src[(h0 - 1) * 64 + lane] : 0.f;
  float cc = src[h0 * 64 + lane];
  float nc = src[(h0 + 1) * 64 + lane];
  float t;
  t = __shfl_up(pc, 1);  float pl = (lane == 0) ? 0.f : t;
  t = __shfl_down(pc, 1); float pr = (lane == 63) ? 0.f : t;
  t = __shfl_up(cc, 1);  float cl = (lane == 0) ? 0.f : t;
  t = __shfl_down(cc, 1); float cr = (lane == 63) ? 0.f : t;
#pragma unroll 4
  for (int i = 0; i < 32; ++i) {
    int h = h0 + i;
    float fut = (h + 2 <= 63) ? src[(h + 2) * 64 + lane] : 0.f;
    t = __shfl_up(nc, 1);  float nl = (lane == 0) ? 0.f : t;
    t = __shfl_down(nc, 1); float nr = (lane == 63) ? 0.f : t;
    float a = pl * c0 + pc * c1 + pr * c2
            + cl * c3 + cc * c4 + cr * c5
            + nl * c6 + nc * c7 + nr * c8;
    a = a * sc + eb;
    dst[h * 64 + lane] = a / (1.f + __expf(-a));
    pl = cl; pc = cc; pr = cr;
    cl = nl; cc = nc; cr = nr;
    nc = fut;
  }
}

// ---------------- x_proj: per-token 192 -> 14, d-major input ----------------
__global__ __launch_bounds__(256) void k_xproj(const float* __restrict__ xd,
                                               const float* __restrict__ Wxt,
                                               float* __restrict__ dtBC) {
  __shared__ float Xs[192 * 65];
  __shared__ float Od[64 * 17];
  int blk = blockIdx.x;
  int b = blk >> 7, rem = blk & 127, s = rem >> 6, n0 = (rem & 63) * 64;
  const float* xsrc = xd + ((size_t)s * 8 + b) * 192 * 4096 + n0;
  int tid = threadIdx.x;
  for (int idx = tid; idx < 192 * 64; idx += 256) {
    int c = idx >> 6, t2 = idx & 63;
    Xs[c * 65 + t2] = xsrc[(size_t)c * 4096 + t2];
  }
  __syncthreads();
  int t = tid & 63, og = tid >> 6;
  float a0 = 0.f, a1 = 0.f, a2 = 0.f, a3 = 0.f;
#pragma unroll 4
  for (int c = 0; c < 192; ++c) {
    float x = Xs[c * 65 + t];
    float4 wv = *(const float4*)&Wxt[c * 16 + og * 4];
    a0 += x * wv.x; a1 += x * wv.y; a2 += x * wv.z; a3 += x * wv.w;
  }
  Od[t * 17 + og * 4 + 0] = a0;
  Od[t * 17 + og * 4 + 1] = a1;
  Od[t * 17 + og * 4 + 2] = a2;
  Od[t * 17 + og * 4 + 3] = a3;
  __syncthreads();
  int t0g = b * 8192 + s * 4096 + n0;
  for (int idx = tid; idx < 1024; idx += 256) {
    int tt = idx >> 4, o = idx & 15;
    dtBC[(size_t)(t0g + tt) * 16 + o] = Od[tt * 17 + o];
  }
}

// ---------------- scan pass 1: 64-token chunks, x in registers, 4KB LDS ----------------
__global__ __launch_bounds__(192) void k_scan1(const float* __restrict__ xd,
                                               const float* __restrict__ dtBC,
                                               const float* __restrict__ dtw,
                                               const float* __restrict__ dtbias,
                                               const float* __restrict__ Alog,
                                               float* __restrict__ hend,
                                               float* __restrict__ Pbuf) {
  __shared__ __align__(16) float SBC[64 * 16];
  int c = blockIdx.x & 127, b = blockIdx.x >> 7;
  int s = c >> 6, cl = c & 63;
  int d = threadIdx.x;
  float w0 = dtw[d * 6 + 0], w1 = dtw[d * 6 + 1], w2 = dtw[d * 6 + 2];
  float w3 = dtw[d * 6 + 3], w4 = dtw[d * 6 + 4], w5 = dtw[d * 6 + 5];
  float bb = dtbias[d];
  float4 al = *(const float4*)&Alog[d * 4];
  float A0 = -__expf(al.x), A1 = -__expf(al.y), A2 = -__expf(al.z), A3 = -__expf(al.w);
  int tokbase = b * 8192 + c * 64;
  for (int idx = d; idx < 1024; idx += 192) SBC[idx] = dtBC[(size_t)tokbase * 16 + idx];
  const float* xrow = xd + (((size_t)s * 8 + b) * 192 + d) * 4096 + cl * 64;
  float4 xr[16];
#pragma unroll
  for (int i = 0; i < 16; ++i) xr[i] = *(const float4*)&xrow[i * 4];
  __syncthreads();
  float h0 = 0.f, h1 = 0.f, h2 = 0.f, h3 = 0.f, sd = 0.f;
#pragma unroll
  for (int i = 0; i < 16; ++i) {
    float xv4[4] = {xr[i].x, xr[i].y, xr[i].z, xr[i].w};
#pragma unroll
    for (int j = 0; j < 4; ++j) {
      int l2 = i * 4 + j;
      float4 s0 = *(const float4*)&SBC[l2 * 16 + 0];
      float4 s1 = *(const float4*)&SBC[l2 * 16 + 4];
      float4 s2 = *(const float4*)&SBC[l2 * 16 + 8];
      float pre = bb + w0 * s0.x + w1 * s0.y + w2 * s0.z + w3 * s0.w + w4 * s1.x + w5 * s1.y;
      float ex = __expf(pre);
      float delta = (pre > 15.f) ? pre : __logf(1.f + ex);
      sd += delta;
      float dx = delta * xv4[j];
      h0 = __expf(delta * A0) * h0 + dx * s1.z;
      h1 = __expf(delta * A1) * h1 + dx * s1.w;
      h2 = __expf(delta * A2) * h2 + dx * s2.x;
      h3 = __expf(delta * A3) * h3 + dx * s2.y;
    }
  }
  size_t o = (((size_t)b * 128 + c) * 192 + d) * 4;
  *(float4*)&hend[o] = make_float4(h0, h1, h2, h3);
  *(float4*)&Pbuf[o] = make_float4(__expf(A0 * sd), __expf(A1 * sd), __expf(A2 * sd), __expf(A3 * sd));
}

// ---------------- scan pass 2: cross-chunk combine (128 chunks) ----------------
__global__ __launch_bounds__(256) void k_scan2(const float* __restrict__ hend,
                                               const float* __restrict__ Pbuf,
                                               float* __restrict__ hinit) {
  int e = blockIdx.x * 256 + threadIdx.x;
  if (e >= 8 * 768) return;
  int b = e / 768, r = e - b * 768;
  float h = 0.f;
#pragma unroll 4
  for (int c = 0; c < 128; ++c) {
    int a = (b * 128 + c) * 768 + r;
    hinit[a] = h;
    h = Pbuf[a] * h + hend[a];
  }
}

// ---------------- scan pass 3: replay with h_init, write y token-major ----------------
__global__ __launch_bounds__(192) void k_scan3(const float* __restrict__ xd,
                                               const float* __restrict__ dtBC,
                                               const float* __restrict__ dtw,
                                               const float* __restrict__ dtbias,
                                               const float* __restrict__ Alog,
                                               const float* __restrict__ Dskip,
                                               const float* __restrict__ hinit,
                                               float* __restrict__ ybuf) {
  __shared__ __align__(16) float SBC[64 * 16];
  int c = blockIdx.x & 127, b = blockIdx.x >> 7;
  int s = c >> 6, cl = c & 63;
  int d = threadIdx.x;
  float w0 = dtw[d * 6 + 0], w1 = dtw[d * 6 + 1], w2 = dtw[d * 6 + 2];
  float w3 = dtw[d * 6 + 3], w4 = dtw[d * 6 + 4], w5 = dtw[d * 6 + 5];
  float bb = dtbias[d];
  float4 al = *(const float4*)&Alog[d * 4];
  float A0 = -__expf(al.x), A1 = -__expf(al.y), A2 = -__expf(al.z), A3 = -__expf(al.w);
  float Dv = Dskip[d];
  int tokbase = b * 8192 + c * 64;
  for (int idx = d; idx < 1024; idx += 192) SBC[idx] = dtBC[(size_t)tokbase * 16 + idx];
  const float* xrow = xd + (((size_t)s * 8 + b) * 192 + d) * 4096 + cl * 64;
  float4 xr[16];
#pragma unroll
  for (int i = 0; i < 16; ++i) xr[i] = *(const float4*)&xrow[i * 4];
  size_t o = (((size_t)b * 128 + c) * 192 + d) * 4;
  float4 hv = *(const float4*)&hinit[o];
  float h0 = hv.x, h1 = hv.y, h2 = hv.z, h3 = hv.w;
  __syncthreads();
  float* yout = ybuf + (size_t)tokbase * 192 + d;
#pragma unroll
  for (int i = 0; i < 16; ++i) {
    float xv4[4] = {xr[i].x, xr[i].y, xr[i].z, xr[i].w};
#pragma unroll
    for (int j = 0; j < 4; ++j) {
      int l2 = i * 4 + j;
      float4 s0 = *(const float4*)&SBC[l2 * 16 + 0];
      float4 s1 = *(const float4*)&SBC[l2 * 16 + 4];
      float4 s2 = *(const float4*)&SBC[l2 * 16 + 8];
      float4 s3 = *(const float4*)&SBC[l2 * 16 + 12];
      float pre = bb + w0 * s0.x + w1 * s0.y + w2 * s0.z + w3 * s0.w + w4 * s1.x + w5 * s1.y;
      float ex = __expf(pre);
      float delta = (pre > 15.f) ? pre : __logf(1.f + ex);
      float xv = xv4[j];
      float dx = delta * xv;
      h0 = __expf(delta * A0) * h0 + dx * s1.z;
      h1 = __expf(delta * A1) * h1 + dx * s1.w;
      h2 = __expf(delta * A2) * h2 + dx * s2.x;
      h3 = __expf(delta * A3) * h3 + dx * s2.y;
      yout[(size_t)l2 * 192] = h0 * s2.z + h1 * s2.w + h2 * s3.x + h3 * s3.y + Dv * xv;
    }
  }
}

// ---------------- fused LayerNorm + z-gate + out-proj + stream-fusion ----------------
__global__ __launch_bounds__(384) void k_outfuse(const float* __restrict__ ybuf,
                                                 const float* __restrict__ zbuf,
                                                 const float* __restrict__ lng,
                                                 const float* __restrict__ lnb,
                                                 const float* __restrict__ Mg,
                                                 float* __restrict__ out) {
  __shared__ __align__(16) float Xc[192 * 68];  // [c][t]
  __shared__ float Ps[6 * 64], Qs[6 * 64], Ms[64], Rs[64];
  int tile = blockIdx.x & 63, b = blockIdx.x >> 6;
  int n0 = tile * 64;
  int tid = threadIdx.x;
  int tx = tid & 15, cg = tid >> 4;  // cg 0..23
  int part = tid / 64, l = tid & 63; // for stats
  float acc[4][4] = {};
  for (int kc = 0; kc < 2; ++kc) {
    size_t tokb = (size_t)b * 8192 + kc * 4096 + n0;
    __syncthreads();
    for (int idx = tid; idx < 64 * 192; idx += 384) {
      int t2 = idx / 192, cc = idx - t2 * 192;
      Xc[cc * 68 + t2] = ybuf[(tokb + t2) * 192 + cc];
    }
    __syncthreads();
    // per-token LN stats over 192 channels
    {
      float sm = 0.f, sq = 0.f;
      int cb = part * 32;
#pragma unroll 4
      for (int q = 0; q < 32; ++q) {
        float v = Xc[(cb + q) * 68 + l];
        sm += v; sq += v * v;
      }
      Ps[part * 64 + l] = sm; Qs[part * 64 + l] = sq;
    }
    __syncthreads();
    if (tid < 64) {
      float sm = Ps[tid] + Ps[64 + tid] + Ps[128 + tid] + Ps[192 + tid] + Ps[256 + tid] + Ps[320 + tid];
      float sq = Qs[tid] + Qs[64 + tid] + Qs[128 + tid] + Qs[192 + tid] + Qs[256 + tid] + Qs[320 + tid];
      float mu = sm * (1.f / 192.f);
      float var = sq * (1.f / 192.f) - mu * mu;
      Ms[tid] = mu; Rs[tid] = rsqrtf(var + EPSV);
    }
    __syncthreads();
    // normalize + gate in place
    for (int idx = tid; idx < 64 * 192; idx += 384) {
      int t2 = idx / 192, cc = idx - t2 * 192;
      float v = Xc[cc * 68 + t2];
      float g = (v - Ms[t2]) * Rs[t2] * lng[cc] + lnb[cc];
      float z = zbuf[(tokb + t2) * 192 + cc];
      Xc[cc * 68 + t2] = g * siluf(z);
    }
    __syncthreads();
    const float* mp = Mg + kc * 18432 + cg * 4;
#pragma unroll 2
    for (int cc = 0; cc < 192; ++cc) {
      float4 xv = *(const float4*)&Xc[cc * 68 + tx * 4];
      float4 wv = *(const float4*)&mp[cc * 96];
      acc[0][0] += xv.x * wv.x; acc[0][1] += xv.x * wv.y; acc[0][2] += xv.x * wv.z; acc[0][3] += xv.x * wv.w;
      acc[1][0] += xv.y * wv.x; acc[1][1] += xv.y * wv.y; acc[1][2] += xv.y * wv.z; acc[1][3] += xv.y * wv.w;
      acc[2][0] += xv.z * wv.x; acc[2][1] += xv.z * wv.y; acc[2][2] += xv.z * wv.z; acc[2][3] += xv.z * wv.w;
      acc[3][0] += xv.w * wv.x; acc[3][1] += xv.w * wv.y; acc[3][2] += xv.w * wv.z; acc[3][3] += xv.w * wv.w;
    }
  }
#pragma unroll
  for (int j = 0; j < 4; ++j) {
    float4 v = make_float4(acc[0][j], acc[1][j], acc[2][j], acc[3][j]);
    *(float4*)&out[((size_t)b * 96 + cg * 4 + j) * 4096 + n0 + tx * 4] = v;
  }
}

extern "C" void kernel_launch(void* const* d_in, const int* in_sizes, int n_in,
                              void* d_out, int out_size, void* d_ws, size_t ws_size,
                              hipStream_t stream) {
  (void)in_sizes; (void)n_in; (void)out_size; (void)ws_size;
  const float* img  = (const float*)d_in[0];
  const float* text = (const float*)d_in[1];
  const float* Wii  = (const float*)d_in[2];
  const float* Wit  = (const float*)d_in[3];
  const float* cwi  = (const float*)d_in[4];
  const float* cbi  = (const float*)d_in[5];
  const float* bgi  = (const float*)d_in[6];
  const float* bbi  = (const float*)d_in[7];
  const float* bmi  = (const float*)d_in[8];
  const float* bvi  = (const float*)d_in[9];
  const float* cwt  = (const float*)d_in[10];
  const float* cbt  = (const float*)d_in[11];
  const float* bgt  = (const float*)d_in[12];
  const float* bbt  = (const float*)d_in[13];
  const float* bmt  = (const float*)d_in[14];
  const float* bvt  = (const float*)d_in[15];
  const float* xpw  = (const float*)d_in[16];
  const float* dtw  = (const float*)d_in[17];
  const float* dtb  = (const float*)d_in[18];
  const float* Alog = (const float*)d_in[19];
  const float* Dsk  = (const float*)d_in[20];
  const float* lng  = (const float*)d_in[21];
  const float* lnb  = (const float*)d_in[22];
  const float* Wout = (const float*)d_in[23];
  const float* Wfus = (const float*)d_in[24];

  float* ws    = (float*)d_ws;
  float* xsp   = ws;
  float* zbuf  = xsp + N_XSP;
  float* xd    = zbuf + N_ZBUF;
  float* dtBC  = xd + N_XD;
  float* hend  = dtBC + N_DTBC;
  float* Pbuf  = hend + N_STATE;
  float* hinit = Pbuf + N_STATE;
  float* Mg    = hinit + N_STATE;
  float* Wti   = Mg + 36864;
  float* Wtt   = Wti + 36864;
  float* Wxt   = Wtt + 36864;
  float* ybuf  = xsp;   // xsp dead after k_conv
  float* out   = (float*)d_out;

  hipLaunchKernelGGL(k_prep, dim3(444), dim3(256), 0, stream, Wout, Wfus, Wii, Wit, xpw, Mg, Wti, Wtt, Wxt);
  hipLaunchKernelGGL(k_inproj, dim3(1024), dim3(256), 0, stream, img, text, Wii ? Wti : Wti, Wtt, xsp, zbuf);
  hipLaunchKernelGGL(k_conv, dim3(1536), dim3(256), 0, stream, xsp,
                     cwi, cbi, bgi, bbi, bmi, bvi, cwt, cbt, bgt, bbt, bmt, bvt, xd);
  hipLaunchKernelGGL(k_xproj, dim3(1024), dim3(256), 0, stream, xd, Wxt, dtBC);
  hipLaunchKernelGGL(k_scan1, dim3(1024), dim3(192), 0, stream, xd, dtBC, dtw, dtb, Alog, hend, Pbuf);
  hipLaunchKernelGGL(k_scan2, dim3(24), dim3(256), 0, stream, hend, Pbuf, hinit);
  hipLaunchKernelGGL(k_scan3, dim3(1024), dim3(192), 0, stream, xd, dtBC, dtw, dtb, Alog, Dsk, hinit, xsp);
  hipLaunchKernelGGL(k_outfuse, dim3(512), dim3(384), 0, stream, ybuf, zbuf, lng, lnb, Mg, out);
}

// Round 4
// 322.411 us; speedup vs baseline: 1.6289x; 1.2297x over previous
//
#include <hip/hip_runtime.h>
#include <math.h>

#define EPSV 1e-5f

// ---------------- workspace layout (floats) ----------------
// xsp  : (2,8,192,4096) x-branch, d-major spatial (conv in)  | reused as ybuf
// zbuf : (8,8192,192)   z-branch, token-major
// xd   : (2,8,192,4096) conv output, d-major (scan/xproj in)
// dtBC : (65536,16)     per-token dt(6),B(4),C(4),pad(2)
// hend/Pbuf/hinit : (8,128,192,4) chunk-scan state
// Mg   : (384,96)  fused W_fusion@W_out; Wti/Wtt: (96,384) W_in^T; Wxt: (192,16) x_proj^T
#define N_XSP   12582912
#define N_ZBUF  12582912
#define N_XD    12582912
#define N_DTBC  1048576
#define N_STATE 786432

__device__ __forceinline__ float siluf(float v) {
  return v / (1.f + __expf(-v));
}

// ---------------- prep: Mg + weight transposes ----------------
__global__ __launch_bounds__(256) void k_prep(const float* __restrict__ Wout,
                                              const float* __restrict__ Wf,
                                              const float* __restrict__ Wii,
                                              const float* __restrict__ Wit,
                                              const float* __restrict__ xpw,
                                              float* __restrict__ Mg,
                                              float* __restrict__ Wti,
                                              float* __restrict__ Wtt,
                                              float* __restrict__ Wxt) {
  int e = blockIdx.x * 256 + threadIdx.x;
  if (e < 36864) {                     // Mg[k][o] = sum_j Wf[o][half*96+j]*Wout[j][k%192]
    int k = e / 96, o = e - k * 96;
    int half = (k >= 192) ? 1 : 0;
    int c = k - half * 192;
    const float* wfr = Wf + o * 192 + half * 96;
    float acc = 0.f;
#pragma unroll 4
    for (int j = 0; j < 96; ++j) acc += wfr[j] * Wout[j * 192 + c];
    Mg[e] = acc;
  } else if (e < 73728) {              // Wti[c][o] = Wii[o][c]
    int i = e - 36864;
    int o = i / 96, c = i - o * 96;
    Wti[c * 384 + o] = Wii[i];
  } else if (e < 110592) {
    int i = e - 73728;
    int o = i / 96, c = i - o * 96;
    Wtt[c * 384 + o] = Wit[i];
  } else if (e < 113664) {             // Wxt[c][o], o 14..15 zero
    int i = e - 110592;
    int c = i >> 4, o = i & 15;
    Wxt[i] = (o < 14) ? xpw[o * 192 + c] : 0.f;
  }
}

// ---------------- in_proj: 96 -> 384 per token; x -> d-major spatial, z -> token-major ----------------
__global__ __launch_bounds__(256) void k_inproj(const float* __restrict__ img,
                                                const float* __restrict__ text,
                                                const float* __restrict__ Wti,
                                                const float* __restrict__ Wtt,
                                                float* __restrict__ xsp,
                                                float* __restrict__ zbuf) {
  __shared__ __align__(16) float Xs[96 * 64];  // [c][t]
  int bx = blockIdx.x;
  int tile = bx & 63, b = (bx >> 6) & 7, s = bx >> 9;
  int n0 = tile * 64;
  const float* src = s ? text : img;
  const float* Wt = s ? Wtt : Wti;   // [96][384]
  int tid = threadIdx.x;
  for (int idx = tid; idx < 96 * 64; idx += 256) {
    int c = idx >> 6, t = idx & 63;
    Xs[idx] = src[((size_t)b * 96 + c) * 4096 + n0 + t];
  }
  __syncthreads();
  int tx = tid & 15, dy4 = (tid >> 4) * 4;
  for (int k = 0; k < 6; ++k) {
    float acc[4][4] = {};
    const float* wp = Wt + k * 64 + dy4;
#pragma unroll 2
    for (int c = 0; c < 96; ++c) {
      float4 xv = *(const float4*)&Xs[c * 64 + tx * 4];
      float4 wv = *(const float4*)&wp[c * 384];
      acc[0][0] += xv.x * wv.x; acc[0][1] += xv.x * wv.y; acc[0][2] += xv.x * wv.z; acc[0][3] += xv.x * wv.w;
      acc[1][0] += xv.y * wv.x; acc[1][1] += xv.y * wv.y; acc[1][2] += xv.y * wv.z; acc[1][3] += xv.y * wv.w;
      acc[2][0] += xv.z * wv.x; acc[2][1] += xv.z * wv.y; acc[2][2] += xv.z * wv.z; acc[2][3] += xv.z * wv.w;
      acc[3][0] += xv.w * wv.x; acc[3][1] += xv.w * wv.y; acc[3][2] += xv.w * wv.z; acc[3][3] += xv.w * wv.w;
    }
    if (k < 3) {   // x part: d-major spatial
#pragma unroll
      for (int j = 0; j < 4; ++j) {
        float4 v = make_float4(acc[0][j], acc[1][j], acc[2][j], acc[3][j]);
        *(float4*)&xsp[(((size_t)s * 8 + b) * 192 + k * 64 + dy4 + j) * 4096 + n0 + tx * 4] = v;
      }
    } else {       // z part: token-major
#pragma unroll
      for (int i = 0; i < 4; ++i) {
        float4 v = make_float4(acc[i][0], acc[i][1], acc[i][2], acc[i][3]);
        *(float4*)&zbuf[((size_t)b * 8192 + s * 4096 + n0 + tx * 4 + i) * 192 + (k - 3) * 64 + dy4] = v;
      }
    }
  }
}

// ---------------- depthwise 3x3 conv + BN + SiLU: register-marching, d-major in/out ----------------
__global__ __launch_bounds__(256) void k_conv(
    const float* __restrict__ xsp,
    const float* __restrict__ cwi, const float* __restrict__ cbi,
    const float* __restrict__ bgi, const float* __restrict__ bbi,
    const float* __restrict__ bmi, const float* __restrict__ bvi,
    const float* __restrict__ cwt, const float* __restrict__ cbt,
    const float* __restrict__ bgt, const float* __restrict__ bbt,
    const float* __restrict__ bmt, const float* __restrict__ bvt,
    float* __restrict__ xd) {
  int bid = blockIdx.x;
  int img = bid / 96;                 // 0..15
  int d0 = (bid - img * 96) * 2;
  int widx = threadIdx.x >> 6;
  int lane = threadIdx.x & 63;
  int d = d0 + (widx >> 1);
  int half = widx & 1;
  int s = img >> 3;
  const float* cw = s ? cwt : cwi;
  const float* cb = s ? cbt : cbi;
  const float* bg = s ? bgt : bgi;
  const float* bb2 = s ? bbt : bbi;
  const float* bm = s ? bmt : bmi;
  const float* bv = s ? bvt : bvi;
  const float* src = xsp + ((size_t)img * 192 + d) * 4096;
  float* dst = xd + ((size_t)img * 192 + d) * 4096;
  float c0 = cw[d * 9 + 0], c1 = cw[d * 9 + 1], c2 = cw[d * 9 + 2];
  float c3 = cw[d * 9 + 3], c4 = cw[d * 9 + 4], c5 = cw[d * 9 + 5];
  float c6 = cw[d * 9 + 6], c7 = cw[d * 9 + 7], c8 = cw[d * 9 + 8];
  float sc = bg[d] * rsqrtf(bv[d] + EPSV);
  float eb = (cb[d] - bm[d]) * sc + bb2[d];
  int h0 = half * 32;
  float pc = (h0 > 0) ? src[(h0 - 1) * 64 + lane] : 0.f;
  float cc = src[h0 * 64 + lane];
  float nc = src[(h0 + 1) * 64 + lane];
  float t;
  t = __shfl_up(pc, 1);  float pl = (lane == 0) ? 0.f : t;
  t = __shfl_down(pc, 1); float pr = (lane == 63) ? 0.f : t;
  t = __shfl_up(cc, 1);  float cl = (lane == 0) ? 0.f : t;
  t = __shfl_down(cc, 1); float cr = (lane == 63) ? 0.f : t;
#pragma unroll 4
  for (int i = 0; i < 32; ++i) {
    int h = h0 + i;
    float fut = (h + 2 <= 63) ? src[(h + 2) * 64 + lane] : 0.f;
    t = __shfl_up(nc, 1);  float nl = (lane == 0) ? 0.f : t;
    t = __shfl_down(nc, 1); float nr = (lane == 63) ? 0.f : t;
    float a = pl * c0 + pc * c1 + pr * c2
            + cl * c3 + cc * c4 + cr * c5
            + nl * c6 + nc * c7 + nr * c8;
    a = a * sc + eb;
    dst[h * 64 + lane] = a / (1.f + __expf(-a));
    pl = cl; pc = cc; pr = cr;
    cl = nl; cc = nc; cr = nr;
    nc = fut;
  }
}

// ---------------- x_proj: per-token 192 -> 14, d-major input ----------------
__global__ __launch_bounds__(256) void k_xproj(const float* __restrict__ xd,
                                               const float* __restrict__ Wxt,
                                               float* __restrict__ dtBC) {
  __shared__ float Xs[192 * 65];
  __shared__ float Od[64 * 17];
  int blk = blockIdx.x;
  int b = blk >> 7, rem = blk & 127, s = rem >> 6, n0 = (rem & 63) * 64;
  const float* xsrc = xd + ((size_t)s * 8 + b) * 192 * 4096 + n0;
  int tid = threadIdx.x;
  for (int idx = tid; idx < 192 * 64; idx += 256) {
    int c = idx >> 6, t2 = idx & 63;
    Xs[c * 65 + t2] = xsrc[(size_t)c * 4096 + t2];
  }
  __syncthreads();
  int t = tid & 63, og = tid >> 6;
  float a0 = 0.f, a1 = 0.f, a2 = 0.f, a3 = 0.f;
#pragma unroll 4
  for (int c = 0; c < 192; ++c) {
    float x = Xs[c * 65 + t];
    float4 wv = *(const float4*)&Wxt[c * 16 + og * 4];
    a0 += x * wv.x; a1 += x * wv.y; a2 += x * wv.z; a3 += x * wv.w;
  }
  Od[t * 17 + og * 4 + 0] = a0;
  Od[t * 17 + og * 4 + 1] = a1;
  Od[t * 17 + og * 4 + 2] = a2;
  Od[t * 17 + og * 4 + 3] = a3;
  __syncthreads();
  int t0g = b * 8192 + s * 4096 + n0;
  for (int idx = tid; idx < 1024; idx += 256) {
    int tt = idx >> 4, o = idx & 15;
    dtBC[(size_t)(t0g + tt) * 16 + o] = Od[tt * 17 + o];
  }
}

// ---------------- scan pass 1: 64-token chunks, x in registers, 4KB LDS ----------------
__global__ __launch_bounds__(192) void k_scan1(const float* __restrict__ xd,
                                               const float* __restrict__ dtBC,
                                               const float* __restrict__ dtw,
                                               const float* __restrict__ dtbias,
                                               const float* __restrict__ Alog,
                                               float* __restrict__ hend,
                                               float* __restrict__ Pbuf) {
  __shared__ __align__(16) float SBC[64 * 16];
  int c = blockIdx.x & 127, b = blockIdx.x >> 7;
  int s = c >> 6, cl = c & 63;
  int d = threadIdx.x;
  float w0 = dtw[d * 6 + 0], w1 = dtw[d * 6 + 1], w2 = dtw[d * 6 + 2];
  float w3 = dtw[d * 6 + 3], w4 = dtw[d * 6 + 4], w5 = dtw[d * 6 + 5];
  float bb = dtbias[d];
  float4 al = *(const float4*)&Alog[d * 4];
  float A0 = -__expf(al.x), A1 = -__expf(al.y), A2 = -__expf(al.z), A3 = -__expf(al.w);
  int tokbase = b * 8192 + c * 64;
  for (int idx = d; idx < 1024; idx += 192) SBC[idx] = dtBC[(size_t)tokbase * 16 + idx];
  const float* xrow = xd + (((size_t)s * 8 + b) * 192 + d) * 4096 + cl * 64;
  float4 xr[16];
#pragma unroll
  for (int i = 0; i < 16; ++i) xr[i] = *(const float4*)&xrow[i * 4];
  __syncthreads();
  float h0 = 0.f, h1 = 0.f, h2 = 0.f, h3 = 0.f, sd = 0.f;
#pragma unroll
  for (int i = 0; i < 16; ++i) {
    float xv4[4] = {xr[i].x, xr[i].y, xr[i].z, xr[i].w};
#pragma unroll
    for (int j = 0; j < 4; ++j) {
      int l2 = i * 4 + j;
      float4 s0 = *(const float4*)&SBC[l2 * 16 + 0];
      float4 s1 = *(const float4*)&SBC[l2 * 16 + 4];
      float4 s2 = *(const float4*)&SBC[l2 * 16 + 8];
      float pre = bb + w0 * s0.x + w1 * s0.y + w2 * s0.z + w3 * s0.w + w4 * s1.x + w5 * s1.y;
      float ex = __expf(pre);
      float delta = (pre > 15.f) ? pre : __logf(1.f + ex);
      sd += delta;
      float dx = delta * xv4[j];
      h0 = __expf(delta * A0) * h0 + dx * s1.z;
      h1 = __expf(delta * A1) * h1 + dx * s1.w;
      h2 = __expf(delta * A2) * h2 + dx * s2.x;
      h3 = __expf(delta * A3) * h3 + dx * s2.y;
    }
  }
  size_t o = (((size_t)b * 128 + c) * 192 + d) * 4;
  *(float4*)&hend[o] = make_float4(h0, h1, h2, h3);
  *(float4*)&Pbuf[o] = make_float4(__expf(A0 * sd), __expf(A1 * sd), __expf(A2 * sd), __expf(A3 * sd));
}

// ---------------- scan pass 2: cross-chunk combine (128 chunks) ----------------
__global__ __launch_bounds__(256) void k_scan2(const float* __restrict__ hend,
                                               const float* __restrict__ Pbuf,
                                               float* __restrict__ hinit) {
  int e = blockIdx.x * 256 + threadIdx.x;
  if (e >= 8 * 768) return;
  int b = e / 768, r = e - b * 768;
  float h = 0.f;
#pragma unroll 4
  for (int c = 0; c < 128; ++c) {
    int a = (b * 128 + c) * 768 + r;
    hinit[a] = h;
    h = Pbuf[a] * h + hend[a];
  }
}

// ---------------- scan pass 3: replay with h_init, write y token-major ----------------
__global__ __launch_bounds__(192) void k_scan3(const float* __restrict__ xd,
                                               const float* __restrict__ dtBC,
                                               const float* __restrict__ dtw,
                                               const float* __restrict__ dtbias,
                                               const float* __restrict__ Alog,
                                               const float* __restrict__ Dskip,
                                               const float* __restrict__ hinit,
                                               float* __restrict__ ybuf) {
  __shared__ __align__(16) float SBC[64 * 16];
  int c = blockIdx.x & 127, b = blockIdx.x >> 7;
  int s = c >> 6, cl = c & 63;
  int d = threadIdx.x;
  float w0 = dtw[d * 6 + 0], w1 = dtw[d * 6 + 1], w2 = dtw[d * 6 + 2];
  float w3 = dtw[d * 6 + 3], w4 = dtw[d * 6 + 4], w5 = dtw[d * 6 + 5];
  float bb = dtbias[d];
  float4 al = *(const float4*)&Alog[d * 4];
  float A0 = -__expf(al.x), A1 = -__expf(al.y), A2 = -__expf(al.z), A3 = -__expf(al.w);
  float Dv = Dskip[d];
  int tokbase = b * 8192 + c * 64;
  for (int idx = d; idx < 1024; idx += 192) SBC[idx] = dtBC[(size_t)tokbase * 16 + idx];
  const float* xrow = xd + (((size_t)s * 8 + b) * 192 + d) * 4096 + cl * 64;
  float4 xr[16];
#pragma unroll
  for (int i = 0; i < 16; ++i) xr[i] = *(const float4*)&xrow[i * 4];
  size_t o = (((size_t)b * 128 + c) * 192 + d) * 4;
  float4 hv = *(const float4*)&hinit[o];
  float h0 = hv.x, h1 = hv.y, h2 = hv.z, h3 = hv.w;
  __syncthreads();
  float* yout = ybuf + (size_t)tokbase * 192 + d;
#pragma unroll
  for (int i = 0; i < 16; ++i) {
    float xv4[4] = {xr[i].x, xr[i].y, xr[i].z, xr[i].w};
#pragma unroll
    for (int j = 0; j < 4; ++j) {
      int l2 = i * 4 + j;
      float4 s0 = *(const float4*)&SBC[l2 * 16 + 0];
      float4 s1 = *(const float4*)&SBC[l2 * 16 + 4];
      float4 s2 = *(const float4*)&SBC[l2 * 16 + 8];
      float4 s3 = *(const float4*)&SBC[l2 * 16 + 12];
      float pre = bb + w0 * s0.x + w1 * s0.y + w2 * s0.z + w3 * s0.w + w4 * s1.x + w5 * s1.y;
      float ex = __expf(pre);
      float delta = (pre > 15.f) ? pre : __logf(1.f + ex);
      float xv = xv4[j];
      float dx = delta * xv;
      h0 = __expf(delta * A0) * h0 + dx * s1.z;
      h1 = __expf(delta * A1) * h1 + dx * s1.w;
      h2 = __expf(delta * A2) * h2 + dx * s2.x;
      h3 = __expf(delta * A3) * h3 + dx * s2.y;
      yout[(size_t)l2 * 192] = h0 * s2.z + h1 * s2.w + h2 * s3.x + h3 * s3.y + Dv * xv;
    }
  }
}

// ---------------- fused LayerNorm + z-gate + out-proj + stream-fusion ----------------
// wave-per-token LN/gate in registers -> conflict-free pad-65 [c][t] tile -> GEMM
__global__ __launch_bounds__(384) void k_outfuse(const float* __restrict__ ybuf,
                                                 const float* __restrict__ zbuf,
                                                 const float* __restrict__ lng,
                                                 const float* __restrict__ lnb,
                                                 const float* __restrict__ Mg,
                                                 float* __restrict__ out) {
  __shared__ float Xc[192 * 65];  // [c][t] pad 65: stride-65 col access & 4tx row access both conflict-free
  int tile = blockIdx.x & 63, b = blockIdx.x >> 6;
  int n0 = tile * 64;
  int tid = threadIdx.x;
  int wv = tid >> 6, lane = tid & 63;
  int tx = tid & 15, cg = tid >> 4;  // GEMM mapping: 16x24 -> 64 tokens x 96 outs
  float lg0 = lng[lane], lg1 = lng[lane + 64], lg2 = lng[lane + 128];
  float lb0 = lnb[lane], lb1 = lnb[lane + 64], lb2 = lnb[lane + 128];
  float acc[4][4] = {};
  for (int kc = 0; kc < 2; ++kc) {
    size_t tokb = (size_t)b * 8192 + (size_t)kc * 4096 + n0;
    // ---- wave-per-token LN + gate (registers + shfl), write gated to LDS ----
    for (int t = wv; t < 64; t += 6) {
      const float* yr = ybuf + (tokb + t) * 192;
      const float* zr = zbuf + (tokb + t) * 192;
      float y0 = yr[lane], y1 = yr[lane + 64], y2 = yr[lane + 128];
      float z0 = zr[lane], z1 = zr[lane + 64], z2 = zr[lane + 128];
      float sm = y0 + y1 + y2;
      float sq = y0 * y0 + y1 * y1 + y2 * y2;
#pragma unroll
      for (int off = 32; off; off >>= 1) {
        sm += __shfl_xor(sm, off);
        sq += __shfl_xor(sq, off);
      }
      float mu = sm * (1.f / 192.f);
      float var = sq * (1.f / 192.f) - mu * mu;
      float rstd = rsqrtf(var + EPSV);
      Xc[lane * 65 + t]         = ((y0 - mu) * rstd * lg0 + lb0) * siluf(z0);
      Xc[(lane + 64) * 65 + t]  = ((y1 - mu) * rstd * lg1 + lb1) * siluf(z1);
      Xc[(lane + 128) * 65 + t] = ((y2 - mu) * rstd * lg2 + lb2) * siluf(z2);
    }
    __syncthreads();
    // ---- GEMM: 192 -> 96 with fused weights ----
    const float* mp = Mg + kc * 18432 + cg * 4;
#pragma unroll 2
    for (int cc = 0; cc < 192; ++cc) {
      float x0 = Xc[cc * 65 + tx * 4 + 0];
      float x1 = Xc[cc * 65 + tx * 4 + 1];
      float x2 = Xc[cc * 65 + tx * 4 + 2];
      float x3 = Xc[cc * 65 + tx * 4 + 3];
      float4 wv4 = *(const float4*)&mp[cc * 96];
      acc[0][0] += x0 * wv4.x; acc[0][1] += x0 * wv4.y; acc[0][2] += x0 * wv4.z; acc[0][3] += x0 * wv4.w;
      acc[1][0] += x1 * wv4.x; acc[1][1] += x1 * wv4.y; acc[1][2] += x1 * wv4.z; acc[1][3] += x1 * wv4.w;
      acc[2][0] += x2 * wv4.x; acc[2][1] += x2 * wv4.y; acc[2][2] += x2 * wv4.z; acc[2][3] += x2 * wv4.w;
      acc[3][0] += x3 * wv4.x; acc[3][1] += x3 * wv4.y; acc[3][2] += x3 * wv4.z; acc[3][3] += x3 * wv4.w;
    }
    __syncthreads();
  }
#pragma unroll
  for (int j = 0; j < 4; ++j) {
    float4 v = make_float4(acc[0][j], acc[1][j], acc[2][j], acc[3][j]);
    *(float4*)&out[((size_t)b * 96 + cg * 4 + j) * 4096 + n0 + tx * 4] = v;
  }
}

extern "C" void kernel_launch(void* const* d_in, const int* in_sizes, int n_in,
                              void* d_out, int out_size, void* d_ws, size_t ws_size,
                              hipStream_t stream) {
  (void)in_sizes; (void)n_in; (void)out_size; (void)ws_size;
  const float* img  = (const float*)d_in[0];
  const float* text = (const float*)d_in[1];
  const float* Wii  = (const float*)d_in[2];
  const float* Wit  = (const float*)d_in[3];
  const float* cwi  = (const float*)d_in[4];
  const float* cbi  = (const float*)d_in[5];
  const float* bgi  = (const float*)d_in[6];
  const float* bbi  = (const float*)d_in[7];
  const float* bmi  = (const float*)d_in[8];
  const float* bvi  = (const float*)d_in[9];
  const float* cwt  = (const float*)d_in[10];
  const float* cbt  = (const float*)d_in[11];
  const float* bgt  = (const float*)d_in[12];
  const float* bbt  = (const float*)d_in[13];
  const float* bmt  = (const float*)d_in[14];
  const float* bvt  = (const float*)d_in[15];
  const float* xpw  = (const float*)d_in[16];
  const float* dtw  = (const float*)d_in[17];
  const float* dtb  = (const float*)d_in[18];
  const float* Alog = (const float*)d_in[19];
  const float* Dsk  = (const float*)d_in[20];
  const float* lng  = (const float*)d_in[21];
  const float* lnb  = (const float*)d_in[22];
  const float* Wout = (const float*)d_in[23];
  const float* Wfus = (const float*)d_in[24];

  float* ws    = (float*)d_ws;
  float* xsp   = ws;
  float* zbuf  = xsp + N_XSP;
  float* xd    = zbuf + N_ZBUF;
  float* dtBC  = xd + N_XD;
  float* hend  = dtBC + N_DTBC;
  float* Pbuf  = hend + N_STATE;
  float* hinit = Pbuf + N_STATE;
  float* Mg    = hinit + N_STATE;
  float* Wti   = Mg + 36864;
  float* Wtt   = Wti + 36864;
  float* Wxt   = Wtt + 36864;
  float* ybuf  = xsp;   // xsp dead after k_conv
  float* out   = (float*)d_out;

  hipLaunchKernelGGL(k_prep, dim3(444), dim3(256), 0, stream, Wout, Wfus, Wii, Wit, xpw, Mg, Wti, Wtt, Wxt);
  hipLaunchKernelGGL(k_inproj, dim3(1024), dim3(256), 0, stream, img, text, Wti, Wtt, xsp, zbuf);
  hipLaunchKernelGGL(k_conv, dim3(1536), dim3(256), 0, stream, xsp,
                     cwi, cbi, bgi, bbi, bmi, bvi, cwt, cbt, bgt, bbt, bmt, bvt, xd);
  hipLaunchKernelGGL(k_xproj, dim3(1024), dim3(256), 0, stream, xd, Wxt, dtBC);
  hipLaunchKernelGGL(k_scan1, dim3(1024), dim3(192), 0, stream, xd, dtBC, dtw, dtb, Alog, hend, Pbuf);
  hipLaunchKernelGGL(k_scan2, dim3(24), dim3(256), 0, stream, hend, Pbuf, hinit);
  hipLaunchKernelGGL(k_scan3, dim3(1024), dim3(192), 0, stream, xd, dtBC, dtw, dtb, Alog, Dsk, hinit, xsp);
  hipLaunchKernelGGL(k_outfuse, dim3(512), dim3(384), 0, stream, ybuf, zbuf, lng, lnb, Mg, out);
}

// Round 5
// 247.940 us; speedup vs baseline: 2.1182x; 1.3004x over previous
//
#include <hip/hip_runtime.h>
#include <math.h>

#define EPSV 1e-5f

typedef __attribute__((ext_vector_type(8))) short short8_t;   // 8 bf16 (4 VGPRs)
typedef __attribute__((ext_vector_type(4))) float f32x4;      // MFMA acc

// ---------------- workspace layout (floats) ----------------
// xsp  : (2,8,192,4096) x-branch, d-major spatial (conv in)  | reused as ybuf
// zbuf : (8,8192,192)   z-branch, token-major
// xd   : (2,8,192,4096) conv output, d-major (scan/xproj in)
// dtBC : (65536,16)     per-token dt(6),B(4),C(4),pad(2)
// hend/Pbuf/hinit : (8,128,192,4) chunk-scan state
// Mg   : (384,96) fused W_fusion@W_out; Wxt: (192,16) x_proj^T; wbi/wbt: bf16 W_in [384][96]
#define N_XSP   12582912
#define N_ZBUF  12582912
#define N_XD    12582912
#define N_DTBC  1048576
#define N_STATE 786432

__device__ __forceinline__ float siluf(float v) {
  return v / (1.f + __expf(-v));
}

__device__ __forceinline__ unsigned short f2bf(float f) {  // RTNE fp32->bf16
  unsigned int u = __float_as_uint(f);
  u += 0x7fffu + ((u >> 16) & 1u);
  return (unsigned short)(u >> 16);
}

// ---------------- prep: Mg + bf16 weight conversion + x_proj^T ----------------
__global__ __launch_bounds__(256) void k_prep(const float* __restrict__ Wout,
                                              const float* __restrict__ Wf,
                                              const float* __restrict__ Wii,
                                              const float* __restrict__ Wit,
                                              const float* __restrict__ xpw,
                                              float* __restrict__ Mg,
                                              unsigned short* __restrict__ wbi,
                                              unsigned short* __restrict__ wbt,
                                              float* __restrict__ Wxt) {
  int e = blockIdx.x * 256 + threadIdx.x;
  if (e < 36864) {                     // Mg[k][o] = sum_j Wf[o][half*96+j]*Wout[j][k%192]
    int k = e / 96, o = e - k * 96;
    int half = (k >= 192) ? 1 : 0;
    int c = k - half * 192;
    const float* wfr = Wf + o * 192 + half * 96;
    float acc = 0.f;
#pragma unroll 4
    for (int j = 0; j < 96; ++j) acc += wfr[j] * Wout[j * 192 + c];
    Mg[e] = acc;
  } else if (e < 73728) {              // bf16 W_in image, [out][in] row-major kept
    int i = e - 36864;
    wbi[i] = f2bf(Wii[i]);
  } else if (e < 110592) {
    int i = e - 73728;
    wbt[i] = f2bf(Wit[i]);
  } else if (e < 113664) {             // Wxt[c][o], o 14..15 zero
    int i = e - 110592;
    int c = i >> 4, o = i & 15;
    Wxt[i] = (o < 14) ? xpw[o * 192 + c] : 0.f;
  }
}

// ---------------- in_proj via bf16 MFMA: 64 tokens x 384 outs, K=96 ----------------
// M=tokens (A=X), N=outs (B=W^T view), fp32 accumulate.
__global__ __launch_bounds__(256, 2) void k_inproj(const float* __restrict__ img,
                                                   const float* __restrict__ text,
                                                   const unsigned short* __restrict__ wbi,
                                                   const unsigned short* __restrict__ wbt,
                                                   float* __restrict__ xsp,
                                                   float* __restrict__ zbuf) {
  __shared__ __align__(16) unsigned short Xbf[64 * 104];  // [t][k] pad 104 (208B rows, 16B aligned)
  int bx = blockIdx.x;
  int tile = bx & 63, b = (bx >> 6) & 7, s = bx >> 9;
  int n0 = tile * 64;
  int tid = threadIdx.x;
  int w = tid >> 6, lane = tid & 63;
  const float* src = s ? text : img;
  const unsigned short* wsel = s ? wbt : wbi;

  // B-fragments: wave w owns outs w*96 .. w*96+95; lane holds out (lane&15) of each
  // 16-wide n-tile, k-slice (lane>>4)*8 within each K=32 step. Resident in registers.
  const unsigned short* wbase = wsel + ((size_t)(w * 96 + (lane & 15))) * 96 + ((lane >> 4) * 8);
  short8_t bfr[18];
#pragma unroll
  for (int nt = 0; nt < 6; ++nt)
#pragma unroll
    for (int ks = 0; ks < 3; ++ks)
      bfr[nt * 3 + ks] = *(const short8_t*)(wbase + nt * 16 * 96 + ks * 32);

  // stage X tile -> bf16 LDS (coalesced global reads)
  for (int idx = tid; idx < 6144; idx += 256) {
    int c = idx >> 6, t = idx & 63;
    Xbf[t * 104 + c] = f2bf(src[((size_t)b * 96 + c) * 4096 + n0 + t]);
  }
  __syncthreads();

  f32x4 acc[4][6];
  f32x4 zz = {0.f, 0.f, 0.f, 0.f};
#pragma unroll
  for (int mt = 0; mt < 4; ++mt)
#pragma unroll
    for (int nt = 0; nt < 6; ++nt) acc[mt][nt] = zz;

  int arow = lane & 15;
  int acol = (lane >> 4) * 8;
#pragma unroll
  for (int mt = 0; mt < 4; ++mt) {
    const unsigned short* ap = &Xbf[(mt * 16 + arow) * 104 + acol];
    short8_t a0 = *(const short8_t*)(ap);
    short8_t a1 = *(const short8_t*)(ap + 32);
    short8_t a2 = *(const short8_t*)(ap + 64);
#pragma unroll
    for (int nt = 0; nt < 6; ++nt) {
      acc[mt][nt] = __builtin_amdgcn_mfma_f32_16x16x32_bf16(a0, bfr[nt * 3 + 0], acc[mt][nt], 0, 0, 0);
      acc[mt][nt] = __builtin_amdgcn_mfma_f32_16x16x32_bf16(a1, bfr[nt * 3 + 1], acc[mt][nt], 0, 0, 0);
      acc[mt][nt] = __builtin_amdgcn_mfma_f32_16x16x32_bf16(a2, bfr[nt * 3 + 2], acc[mt][nt], 0, 0, 0);
    }
  }

  // C layout: col(out) = lane&15, row(token) = (lane>>4)*4 + reg  [m89]
  int rowoff = (lane >> 4) * 4;
  if (w < 2) {   // x half -> d-major spatial; 4 consecutive tokens per lane -> float4
#pragma unroll
    for (int nt = 0; nt < 6; ++nt) {
      int d = w * 96 + nt * 16 + (lane & 15);
      float* xp = xsp + (((size_t)s * 8 + b) * 192 + d) * 4096 + n0 + rowoff;
#pragma unroll
      for (int mt = 0; mt < 4; ++mt) {
        f32x4 a = acc[mt][nt];
        *(float4*)&xp[mt * 16] = make_float4(a[0], a[1], a[2], a[3]);
      }
    }
  } else {       // z half -> token-major
    size_t tokb = (size_t)b * 8192 + (size_t)s * 4096 + n0;
#pragma unroll
    for (int nt = 0; nt < 6; ++nt) {
      int ch = (w - 2) * 96 + nt * 16 + (lane & 15);
#pragma unroll
      for (int mt = 0; mt < 4; ++mt) {
        f32x4 a = acc[mt][nt];
        float* zp = zbuf + (tokb + mt * 16 + rowoff) * 192 + ch;
        zp[0] = a[0]; zp[192] = a[1]; zp[384] = a[2]; zp[576] = a[3];
      }
    }
  }
}

// ---------------- depthwise 3x3 conv + BN + SiLU: register-marching, d-major in/out ----------------
__global__ __launch_bounds__(256) void k_conv(
    const float* __restrict__ xsp,
    const float* __restrict__ cwi, const float* __restrict__ cbi,
    const float* __restrict__ bgi, const float* __restrict__ bbi,
    const float* __restrict__ bmi, const float* __restrict__ bvi,
    const float* __restrict__ cwt, const float* __restrict__ cbt,
    const float* __restrict__ bgt, const float* __restrict__ bbt,
    const float* __restrict__ bmt, const float* __restrict__ bvt,
    float* __restrict__ xd) {
  int bid = blockIdx.x;
  int img = bid / 96;                 // 0..15
  int d0 = (bid - img * 96) * 2;
  int widx = threadIdx.x >> 6;
  int lane = threadIdx.x & 63;
  int d = d0 + (widx >> 1);
  int half = widx & 1;
  int s = img >> 3;
  const float* cw = s ? cwt : cwi;
  const float* cb = s ? cbt : cbi;
  const float* bg = s ? bgt : bgi;
  const float* bb2 = s ? bbt : bbi;
  const float* bm = s ? bmt : bmi;
  const float* bv = s ? bvt : bvi;
  const float* src = xsp + ((size_t)img * 192 + d) * 4096;
  float* dst = xd + ((size_t)img * 192 + d) * 4096;
  float c0 = cw[d * 9 + 0], c1 = cw[d * 9 + 1], c2 = cw[d * 9 + 2];
  float c3 = cw[d * 9 + 3], c4 = cw[d * 9 + 4], c5 = cw[d * 9 + 5];
  float c6 = cw[d * 9 + 6], c7 = cw[d * 9 + 7], c8 = cw[d * 9 + 8];
  float sc = bg[d] * rsqrtf(bv[d] + EPSV);
  float eb = (cb[d] - bm[d]) * sc + bb2[d];
  int h0 = half * 32;
  float pc = (h0 > 0) ? src[(h0 - 1) * 64 + lane] : 0.f;
  float cc = src[h0 * 64 + lane];
  float nc = src[(h0 + 1) * 64 + lane];
  float t;
  t = __shfl_up(pc, 1);  float pl = (lane == 0) ? 0.f : t;
  t = __shfl_down(pc, 1); float pr = (lane == 63) ? 0.f : t;
  t = __shfl_up(cc, 1);  float cl = (lane == 0) ? 0.f : t;
  t = __shfl_down(cc, 1); float cr = (lane == 63) ? 0.f : t;
#pragma unroll 4
  for (int i = 0; i < 32; ++i) {
    int h = h0 + i;
    float fut = (h + 2 <= 63) ? src[(h + 2) * 64 + lane] : 0.f;
    t = __shfl_up(nc, 1);  float nl = (lane == 0) ? 0.f : t;
    t = __shfl_down(nc, 1); float nr = (lane == 63) ? 0.f : t;
    float a = pl * c0 + pc * c1 + pr * c2
            + cl * c3 + cc * c4 + cr * c5
            + nl * c6 + nc * c7 + nr * c8;
    a = a * sc + eb;
    dst[h * 64 + lane] = a / (1.f + __expf(-a));
    pl = cl; pc = cc; pr = cr;
    cl = nl; cc = nc; cr = nr;
    nc = fut;
  }
}

// ---------------- x_proj: per-token 192 -> 14, d-major input ----------------
__global__ __launch_bounds__(256) void k_xproj(const float* __restrict__ xd,
                                               const float* __restrict__ Wxt,
                                               float* __restrict__ dtBC) {
  __shared__ float Xs[192 * 65];
  __shared__ float Od[64 * 17];
  int blk = blockIdx.x;
  int b = blk >> 7, rem = blk & 127, s = rem >> 6, n0 = (rem & 63) * 64;
  const float* xsrc = xd + ((size_t)s * 8 + b) * 192 * 4096 + n0;
  int tid = threadIdx.x;
  for (int idx = tid; idx < 192 * 64; idx += 256) {
    int c = idx >> 6, t2 = idx & 63;
    Xs[c * 65 + t2] = xsrc[(size_t)c * 4096 + t2];
  }
  __syncthreads();
  int t = tid & 63, og = tid >> 6;
  float a0 = 0.f, a1 = 0.f, a2 = 0.f, a3 = 0.f;
#pragma unroll 4
  for (int c = 0; c < 192; ++c) {
    float x = Xs[c * 65 + t];
    float4 wv = *(const float4*)&Wxt[c * 16 + og * 4];
    a0 += x * wv.x; a1 += x * wv.y; a2 += x * wv.z; a3 += x * wv.w;
  }
  Od[t * 17 + og * 4 + 0] = a0;
  Od[t * 17 + og * 4 + 1] = a1;
  Od[t * 17 + og * 4 + 2] = a2;
  Od[t * 17 + og * 4 + 3] = a3;
  __syncthreads();
  int t0g = b * 8192 + s * 4096 + n0;
  for (int idx = tid; idx < 1024; idx += 256) {
    int tt = idx >> 4, o = idx & 15;
    dtBC[(size_t)(t0g + tt) * 16 + o] = Od[tt * 17 + o];
  }
}

// ---------------- scan pass 1: 64-token chunks, x in registers, 4KB LDS ----------------
__global__ __launch_bounds__(192) void k_scan1(const float* __restrict__ xd,
                                               const float* __restrict__ dtBC,
                                               const float* __restrict__ dtw,
                                               const float* __restrict__ dtbias,
                                               const float* __restrict__ Alog,
                                               float* __restrict__ hend,
                                               float* __restrict__ Pbuf) {
  __shared__ __align__(16) float SBC[64 * 16];
  int c = blockIdx.x & 127, b = blockIdx.x >> 7;
  int s = c >> 6, cl = c & 63;
  int d = threadIdx.x;
  float w0 = dtw[d * 6 + 0], w1 = dtw[d * 6 + 1], w2 = dtw[d * 6 + 2];
  float w3 = dtw[d * 6 + 3], w4 = dtw[d * 6 + 4], w5 = dtw[d * 6 + 5];
  float bb = dtbias[d];
  float4 al = *(const float4*)&Alog[d * 4];
  float A0 = -__expf(al.x), A1 = -__expf(al.y), A2 = -__expf(al.z), A3 = -__expf(al.w);
  int tokbase = b * 8192 + c * 64;
  for (int idx = d; idx < 1024; idx += 192) SBC[idx] = dtBC[(size_t)tokbase * 16 + idx];
  const float* xrow = xd + (((size_t)s * 8 + b) * 192 + d) * 4096 + cl * 64;
  float4 xr[16];
#pragma unroll
  for (int i = 0; i < 16; ++i) xr[i] = *(const float4*)&xrow[i * 4];
  __syncthreads();
  float h0 = 0.f, h1 = 0.f, h2 = 0.f, h3 = 0.f, sd = 0.f;
#pragma unroll
  for (int i = 0; i < 16; ++i) {
    float xv4[4] = {xr[i].x, xr[i].y, xr[i].z, xr[i].w};
#pragma unroll
    for (int j = 0; j < 4; ++j) {
      int l2 = i * 4 + j;
      float4 s0 = *(const float4*)&SBC[l2 * 16 + 0];
      float4 s1 = *(const float4*)&SBC[l2 * 16 + 4];
      float4 s2 = *(const float4*)&SBC[l2 * 16 + 8];
      float pre = bb + w0 * s0.x + w1 * s0.y + w2 * s0.z + w3 * s0.w + w4 * s1.x + w5 * s1.y;
      float ex = __expf(pre);
      float delta = (pre > 15.f) ? pre : __logf(1.f + ex);
      sd += delta;
      float dx = delta * xv4[j];
      h0 = __expf(delta * A0) * h0 + dx * s1.z;
      h1 = __expf(delta * A1) * h1 + dx * s1.w;
      h2 = __expf(delta * A2) * h2 + dx * s2.x;
      h3 = __expf(delta * A3) * h3 + dx * s2.y;
    }
  }
  size_t o = (((size_t)b * 128 + c) * 192 + d) * 4;
  *(float4*)&hend[o] = make_float4(h0, h1, h2, h3);
  *(float4*)&Pbuf[o] = make_float4(__expf(A0 * sd), __expf(A1 * sd), __expf(A2 * sd), __expf(A3 * sd));
}

// ---------------- scan pass 2: cross-chunk combine (128 chunks) ----------------
__global__ __launch_bounds__(256) void k_scan2(const float* __restrict__ hend,
                                               const float* __restrict__ Pbuf,
                                               float* __restrict__ hinit) {
  int e = blockIdx.x * 256 + threadIdx.x;
  if (e >= 8 * 768) return;
  int b = e / 768, r = e - b * 768;
  float h = 0.f;
#pragma unroll 4
  for (int c = 0; c < 128; ++c) {
    int a = (b * 128 + c) * 768 + r;
    hinit[a] = h;
    h = Pbuf[a] * h + hend[a];
  }
}

// ---------------- scan pass 3: replay with h_init, write y token-major ----------------
__global__ __launch_bounds__(192) void k_scan3(const float* __restrict__ xd,
                                               const float* __restrict__ dtBC,
                                               const float* __restrict__ dtw,
                                               const float* __restrict__ dtbias,
                                               const float* __restrict__ Alog,
                                               const float* __restrict__ Dskip,
                                               const float* __restrict__ hinit,
                                               float* __restrict__ ybuf) {
  __shared__ __align__(16) float SBC[64 * 16];
  int c = blockIdx.x & 127, b = blockIdx.x >> 7;
  int s = c >> 6, cl = c & 63;
  int d = threadIdx.x;
  float w0 = dtw[d * 6 + 0], w1 = dtw[d * 6 + 1], w2 = dtw[d * 6 + 2];
  float w3 = dtw[d * 6 + 3], w4 = dtw[d * 6 + 4], w5 = dtw[d * 6 + 5];
  float bb = dtbias[d];
  float4 al = *(const float4*)&Alog[d * 4];
  float A0 = -__expf(al.x), A1 = -__expf(al.y), A2 = -__expf(al.z), A3 = -__expf(al.w);
  float Dv = Dskip[d];
  int tokbase = b * 8192 + c * 64;
  for (int idx = d; idx < 1024; idx += 192) SBC[idx] = dtBC[(size_t)tokbase * 16 + idx];
  const float* xrow = xd + (((size_t)s * 8 + b) * 192 + d) * 4096 + cl * 64;
  float4 xr[16];
#pragma unroll
  for (int i = 0; i < 16; ++i) xr[i] = *(const float4*)&xrow[i * 4];
  size_t o = (((size_t)b * 128 + c) * 192 + d) * 4;
  float4 hv = *(const float4*)&hinit[o];
  float h0 = hv.x, h1 = hv.y, h2 = hv.z, h3 = hv.w;
  __syncthreads();
  float* yout = ybuf + (size_t)tokbase * 192 + d;
#pragma unroll
  for (int i = 0; i < 16; ++i) {
    float xv4[4] = {xr[i].x, xr[i].y, xr[i].z, xr[i].w};
#pragma unroll
    for (int j = 0; j < 4; ++j) {
      int l2 = i * 4 + j;
      float4 s0 = *(const float4*)&SBC[l2 * 16 + 0];
      float4 s1 = *(const float4*)&SBC[l2 * 16 + 4];
      float4 s2 = *(const float4*)&SBC[l2 * 16 + 8];
      float4 s3 = *(const float4*)&SBC[l2 * 16 + 12];
      float pre = bb + w0 * s0.x + w1 * s0.y + w2 * s0.z + w3 * s0.w + w4 * s1.x + w5 * s1.y;
      float ex = __expf(pre);
      float delta = (pre > 15.f) ? pre : __logf(1.f + ex);
      float xv = xv4[j];
      float dx = delta * xv;
      h0 = __expf(delta * A0) * h0 + dx * s1.z;
      h1 = __expf(delta * A1) * h1 + dx * s1.w;
      h2 = __expf(delta * A2) * h2 + dx * s2.x;
      h3 = __expf(delta * A3) * h3 + dx * s2.y;
      yout[(size_t)l2 * 192] = h0 * s2.z + h1 * s2.w + h2 * s3.x + h3 * s3.y + Dv * xv;
    }
  }
}

// ---------------- fused LayerNorm + z-gate + out-proj + stream-fusion ----------------
__global__ __launch_bounds__(384) void k_outfuse(const float* __restrict__ ybuf,
                                                 const float* __restrict__ zbuf,
                                                 const float* __restrict__ lng,
                                                 const float* __restrict__ lnb,
                                                 const float* __restrict__ Mg,
                                                 float* __restrict__ out) {
  __shared__ float Xc[192 * 65];  // [c][t] pad 65
  int tile = blockIdx.x & 63, b = blockIdx.x >> 6;
  int n0 = tile * 64;
  int tid = threadIdx.x;
  int wv = tid >> 6, lane = tid & 63;
  int tx = tid & 15, cg = tid >> 4;
  float lg0 = lng[lane], lg1 = lng[lane + 64], lg2 = lng[lane + 128];
  float lb0 = lnb[lane], lb1 = lnb[lane + 64], lb2 = lnb[lane + 128];
  float acc[4][4] = {};
  for (int kc = 0; kc < 2; ++kc) {
    size_t tokb = (size_t)b * 8192 + (size_t)kc * 4096 + n0;
    for (int t = wv; t < 64; t += 6) {
      const float* yr = ybuf + (tokb + t) * 192;
      const float* zr = zbuf + (tokb + t) * 192;
      float y0 = yr[lane], y1 = yr[lane + 64], y2 = yr[lane + 128];
      float z0 = zr[lane], z1 = zr[lane + 64], z2 = zr[lane + 128];
      float sm = y0 + y1 + y2;
      float sq = y0 * y0 + y1 * y1 + y2 * y2;
#pragma unroll
      for (int off = 32; off; off >>= 1) {
        sm += __shfl_xor(sm, off);
        sq += __shfl_xor(sq, off);
      }
      float mu = sm * (1.f / 192.f);
      float var = sq * (1.f / 192.f) - mu * mu;
      float rstd = rsqrtf(var + EPSV);
      Xc[lane * 65 + t]         = ((y0 - mu) * rstd * lg0 + lb0) * siluf(z0);
      Xc[(lane + 64) * 65 + t]  = ((y1 - mu) * rstd * lg1 + lb1) * siluf(z1);
      Xc[(lane + 128) * 65 + t] = ((y2 - mu) * rstd * lg2 + lb2) * siluf(z2);
    }
    __syncthreads();
    const float* mp = Mg + kc * 18432 + cg * 4;
#pragma unroll 2
    for (int cc = 0; cc < 192; ++cc) {
      float x0 = Xc[cc * 65 + tx * 4 + 0];
      float x1 = Xc[cc * 65 + tx * 4 + 1];
      float x2 = Xc[cc * 65 + tx * 4 + 2];
      float x3 = Xc[cc * 65 + tx * 4 + 3];
      float4 wv4 = *(const float4*)&mp[cc * 96];
      acc[0][0] += x0 * wv4.x; acc[0][1] += x0 * wv4.y; acc[0][2] += x0 * wv4.z; acc[0][3] += x0 * wv4.w;
      acc[1][0] += x1 * wv4.x; acc[1][1] += x1 * wv4.y; acc[1][2] += x1 * wv4.z; acc[1][3] += x1 * wv4.w;
      acc[2][0] += x2 * wv4.x; acc[2][1] += x2 * wv4.y; acc[2][2] += x2 * wv4.z; acc[2][3] += x2 * wv4.w;
      acc[3][0] += x3 * wv4.x; acc[3][1] += x3 * wv4.y; acc[3][2] += x3 * wv4.z; acc[3][3] += x3 * wv4.w;
    }
    __syncthreads();
  }
#pragma unroll
  for (int j = 0; j < 4; ++j) {
    float4 v = make_float4(acc[0][j], acc[1][j], acc[2][j], acc[3][j]);
    *(float4*)&out[((size_t)b * 96 + cg * 4 + j) * 4096 + n0 + tx * 4] = v;
  }
}

extern "C" void kernel_launch(void* const* d_in, const int* in_sizes, int n_in,
                              void* d_out, int out_size, void* d_ws, size_t ws_size,
                              hipStream_t stream) {
  (void)in_sizes; (void)n_in; (void)out_size; (void)ws_size;
  const float* img  = (const float*)d_in[0];
  const float* text = (const float*)d_in[1];
  const float* Wii  = (const float*)d_in[2];
  const float* Wit  = (const float*)d_in[3];
  const float* cwi  = (const float*)d_in[4];
  const float* cbi  = (const float*)d_in[5];
  const float* bgi  = (const float*)d_in[6];
  const float* bbi  = (const float*)d_in[7];
  const float* bmi  = (const float*)d_in[8];
  const float* bvi  = (const float*)d_in[9];
  const float* cwt  = (const float*)d_in[10];
  const float* cbt  = (const float*)d_in[11];
  const float* bgt  = (const float*)d_in[12];
  const float* bbt  = (const float*)d_in[13];
  const float* bmt  = (const float*)d_in[14];
  const float* bvt  = (const float*)d_in[15];
  const float* xpw  = (const float*)d_in[16];
  const float* dtw  = (const float*)d_in[17];
  const float* dtb  = (const float*)d_in[18];
  const float* Alog = (const float*)d_in[19];
  const float* Dsk  = (const float*)d_in[20];
  const float* lng  = (const float*)d_in[21];
  const float* lnb  = (const float*)d_in[22];
  const float* Wout = (const float*)d_in[23];
  const float* Wfus = (const float*)d_in[24];

  float* ws    = (float*)d_ws;
  float* xsp   = ws;
  float* zbuf  = xsp + N_XSP;
  float* xd    = zbuf + N_ZBUF;
  float* dtBC  = xd + N_XD;
  float* hend  = dtBC + N_DTBC;
  float* Pbuf  = hend + N_STATE;
  float* hinit = Pbuf + N_STATE;
  float* Mg    = hinit + N_STATE;
  float* Wxt   = Mg + 36864;
  unsigned short* wbi = (unsigned short*)(Wxt + 3072);
  unsigned short* wbt = wbi + 36864;
  float* ybuf  = xsp;   // xsp dead after k_conv
  float* out   = (float*)d_out;

  hipLaunchKernelGGL(k_prep, dim3(444), dim3(256), 0, stream, Wout, Wfus, Wii, Wit, xpw, Mg, wbi, wbt, Wxt);
  hipLaunchKernelGGL(k_inproj, dim3(1024), dim3(256), 0, stream, img, text, wbi, wbt, xsp, zbuf);
  hipLaunchKernelGGL(k_conv, dim3(1536), dim3(256), 0, stream, xsp,
                     cwi, cbi, bgi, bbi, bmi, bvi, cwt, cbt, bgt, bbt, bmt, bvt, xd);
  hipLaunchKernelGGL(k_xproj, dim3(1024), dim3(256), 0, stream, xd, Wxt, dtBC);
  hipLaunchKernelGGL(k_scan1, dim3(1024), dim3(192), 0, stream, xd, dtBC, dtw, dtb, Alog, hend, Pbuf);
  hipLaunchKernelGGL(k_scan2, dim3(24), dim3(256), 0, stream, hend, Pbuf, hinit);
  hipLaunchKernelGGL(k_scan3, dim3(1024), dim3(192), 0, stream, xd, dtBC, dtw, dtb, Alog, Dsk, hinit, xsp);
  hipLaunchKernelGGL(k_outfuse, dim3(512), dim3(384), 0, stream, ybuf, zbuf, lng, lnb, Mg, out);
}

// Round 6
// 197.240 us; speedup vs baseline: 2.6627x; 1.2570x over previous
//
#include <hip/hip_runtime.h>
#include <math.h>

#define EPSV 1e-5f

typedef __attribute__((ext_vector_type(8))) short short8_t;   // 8 bf16 (4 VGPRs)
typedef __attribute__((ext_vector_type(4))) float f32x4;      // MFMA acc

// ---------------- workspace layout (floats) ----------------
// xsp  : (2,8,192,4096) x-branch, d-major spatial (conv in)  | reused as ybuf
// zbuf : (8,8192,192)   z-branch, token-major, BF16 (uses half the slot)
// xd   : (2,8,192,4096) conv output, d-major (scan/xproj in)
// dtBC : (65536,16)     per-token dt(6),B(4),C(4),pad(2)
// hend/Pbuf/hinit : (8,128,192,4) chunk-scan state
// Mgb  : bf16 [2*96][192] fused W_fusion@W_out (out-major); Wxt: (192,16); wbi/wbt: bf16 W_in
#define N_XSP   12582912
#define N_ZBUF  12582912
#define N_XD    12582912
#define N_DTBC  1048576
#define N_STATE 786432

__device__ __forceinline__ float siluf(float v) {
  return v / (1.f + __expf(-v));
}

__device__ __forceinline__ unsigned short f2bf(float f) {  // RTNE fp32->bf16
  unsigned int u = __float_as_uint(f);
  u += 0x7fffu + ((u >> 16) & 1u);
  return (unsigned short)(u >> 16);
}

__device__ __forceinline__ float bf2f(unsigned short h) {
  return __uint_as_float(((unsigned int)h) << 16);
}

// ---------------- prep: Mg(bf16) + bf16 W_in + x_proj^T ----------------
__global__ __launch_bounds__(256) void k_prep(const float* __restrict__ Wout,
                                              const float* __restrict__ Wf,
                                              const float* __restrict__ Wii,
                                              const float* __restrict__ Wit,
                                              const float* __restrict__ xpw,
                                              unsigned short* __restrict__ Mgb,
                                              unsigned short* __restrict__ wbi,
                                              unsigned short* __restrict__ wbt,
                                              float* __restrict__ Wxt) {
  int e = blockIdx.x * 256 + threadIdx.x;
  if (e < 36864) {                     // Mg[k][o] = sum_j Wf[o][half*96+j]*Wout[j][k%192]
    int k = e / 96, o = e - k * 96;
    int half = (k >= 192) ? 1 : 0;
    int c = k - half * 192;
    const float* wfr = Wf + o * 192 + half * 96;
    float acc = 0.f;
#pragma unroll 4
    for (int j = 0; j < 96; ++j) acc += wfr[j] * Wout[j * 192 + c];
    Mgb[(half * 96 + o) * 192 + c] = f2bf(acc);   // [kc][out][k] bf16
  } else if (e < 73728) {              // bf16 W_in image, [out][in] row-major kept
    int i = e - 36864;
    wbi[i] = f2bf(Wii[i]);
  } else if (e < 110592) {
    int i = e - 73728;
    wbt[i] = f2bf(Wit[i]);
  } else if (e < 113664) {             // Wxt[c][o], o 14..15 zero
    int i = e - 110592;
    int c = i >> 4, o = i & 15;
    Wxt[i] = (o < 14) ? xpw[o * 192 + c] : 0.f;
  }
}

// ---------------- in_proj via bf16 MFMA: 64 tokens x 384 outs, K=96 ----------------
__global__ __launch_bounds__(256, 2) void k_inproj(const float* __restrict__ img,
                                                   const float* __restrict__ text,
                                                   const unsigned short* __restrict__ wbi,
                                                   const unsigned short* __restrict__ wbt,
                                                   float* __restrict__ xsp,
                                                   unsigned short* __restrict__ zbufh) {
  __shared__ __align__(16) unsigned short Xbf[64 * 104];  // [t][k] pad 104
  int bx = blockIdx.x;
  int tile = bx & 63, b = (bx >> 6) & 7, s = bx >> 9;
  int n0 = tile * 64;
  int tid = threadIdx.x;
  int w = tid >> 6, lane = tid & 63;
  const float* src = s ? text : img;
  const unsigned short* wsel = s ? wbt : wbi;

  const unsigned short* wbase = wsel + ((size_t)(w * 96 + (lane & 15))) * 96 + ((lane >> 4) * 8);
  short8_t bfr[18];
#pragma unroll
  for (int nt = 0; nt < 6; ++nt)
#pragma unroll
    for (int ks = 0; ks < 3; ++ks)
      bfr[nt * 3 + ks] = *(const short8_t*)(wbase + nt * 16 * 96 + ks * 32);

  for (int idx = tid; idx < 6144; idx += 256) {
    int c = idx >> 6, t = idx & 63;
    Xbf[t * 104 + c] = f2bf(src[((size_t)b * 96 + c) * 4096 + n0 + t]);
  }
  __syncthreads();

  f32x4 acc[4][6];
  f32x4 zz = {0.f, 0.f, 0.f, 0.f};
#pragma unroll
  for (int mt = 0; mt < 4; ++mt)
#pragma unroll
    for (int nt = 0; nt < 6; ++nt) acc[mt][nt] = zz;

  int arow = lane & 15;
  int acol = (lane >> 4) * 8;
#pragma unroll
  for (int mt = 0; mt < 4; ++mt) {
    const unsigned short* ap = &Xbf[(mt * 16 + arow) * 104 + acol];
    short8_t a0 = *(const short8_t*)(ap);
    short8_t a1 = *(const short8_t*)(ap + 32);
    short8_t a2 = *(const short8_t*)(ap + 64);
#pragma unroll
    for (int nt = 0; nt < 6; ++nt) {
      acc[mt][nt] = __builtin_amdgcn_mfma_f32_16x16x32_bf16(a0, bfr[nt * 3 + 0], acc[mt][nt], 0, 0, 0);
      acc[mt][nt] = __builtin_amdgcn_mfma_f32_16x16x32_bf16(a1, bfr[nt * 3 + 1], acc[mt][nt], 0, 0, 0);
      acc[mt][nt] = __builtin_amdgcn_mfma_f32_16x16x32_bf16(a2, bfr[nt * 3 + 2], acc[mt][nt], 0, 0, 0);
    }
  }

  // C layout: col(out) = lane&15, row(token) = (lane>>4)*4 + reg
  int rowoff = (lane >> 4) * 4;
  if (w < 2) {   // x half -> d-major spatial (fp32)
#pragma unroll
    for (int nt = 0; nt < 6; ++nt) {
      int d = w * 96 + nt * 16 + (lane & 15);
      float* xp = xsp + (((size_t)s * 8 + b) * 192 + d) * 4096 + n0 + rowoff;
#pragma unroll
      for (int mt = 0; mt < 4; ++mt) {
        f32x4 a = acc[mt][nt];
        *(float4*)&xp[mt * 16] = make_float4(a[0], a[1], a[2], a[3]);
      }
    }
  } else {       // z half -> token-major bf16
    size_t tokb = (size_t)b * 8192 + (size_t)s * 4096 + n0;
#pragma unroll
    for (int nt = 0; nt < 6; ++nt) {
      int ch = (w - 2) * 96 + nt * 16 + (lane & 15);
#pragma unroll
      for (int mt = 0; mt < 4; ++mt) {
        f32x4 a = acc[mt][nt];
        unsigned short* zp = zbufh + (tokb + mt * 16 + rowoff) * 192 + ch;
        zp[0] = f2bf(a[0]); zp[192] = f2bf(a[1]); zp[384] = f2bf(a[2]); zp[576] = f2bf(a[3]);
      }
    }
  }
}

// ---------------- depthwise 3x3 conv + BN + SiLU: register-marching, d-major in/out ----------------
__global__ __launch_bounds__(256) void k_conv(
    const float* __restrict__ xsp,
    const float* __restrict__ cwi, const float* __restrict__ cbi,
    const float* __restrict__ bgi, const float* __restrict__ bbi,
    const float* __restrict__ bmi, const float* __restrict__ bvi,
    const float* __restrict__ cwt, const float* __restrict__ cbt,
    const float* __restrict__ bgt, const float* __restrict__ bbt,
    const float* __restrict__ bmt, const float* __restrict__ bvt,
    float* __restrict__ xd) {
  int bid = blockIdx.x;
  int img = bid / 96;                 // 0..15
  int d0 = (bid - img * 96) * 2;
  int widx = threadIdx.x >> 6;
  int lane = threadIdx.x & 63;
  int d = d0 + (widx >> 1);
  int half = widx & 1;
  int s = img >> 3;
  const float* cw = s ? cwt : cwi;
  const float* cb = s ? cbt : cbi;
  const float* bg = s ? bgt : bgi;
  const float* bb2 = s ? bbt : bbi;
  const float* bm = s ? bmt : bmi;
  const float* bv = s ? bvt : bvi;
  const float* src = xsp + ((size_t)img * 192 + d) * 4096;
  float* dst = xd + ((size_t)img * 192 + d) * 4096;
  float c0 = cw[d * 9 + 0], c1 = cw[d * 9 + 1], c2 = cw[d * 9 + 2];
  float c3 = cw[d * 9 + 3], c4 = cw[d * 9 + 4], c5 = cw[d * 9 + 5];
  float c6 = cw[d * 9 + 6], c7 = cw[d * 9 + 7], c8 = cw[d * 9 + 8];
  float sc = bg[d] * rsqrtf(bv[d] + EPSV);
  float eb = (cb[d] - bm[d]) * sc + bb2[d];
  int h0 = half * 32;
  float pc = (h0 > 0) ? src[(h0 - 1) * 64 + lane] : 0.f;
  float cc = src[h0 * 64 + lane];
  float nc = src[(h0 + 1) * 64 + lane];
  float t;
  t = __shfl_up(pc, 1);  float pl = (lane == 0) ? 0.f : t;
  t = __shfl_down(pc, 1); float pr = (lane == 63) ? 0.f : t;
  t = __shfl_up(cc, 1);  float cl = (lane == 0) ? 0.f : t;
  t = __shfl_down(cc, 1); float cr = (lane == 63) ? 0.f : t;
#pragma unroll 4
  for (int i = 0; i < 32; ++i) {
    int h = h0 + i;
    float fut = (h + 2 <= 63) ? src[(h + 2) * 64 + lane] : 0.f;
    t = __shfl_up(nc, 1);  float nl = (lane == 0) ? 0.f : t;
    t = __shfl_down(nc, 1); float nr = (lane == 63) ? 0.f : t;
    float a = pl * c0 + pc * c1 + pr * c2
            + cl * c3 + cc * c4 + cr * c5
            + nl * c6 + nc * c7 + nr * c8;
    a = a * sc + eb;
    dst[h * 64 + lane] = a / (1.f + __expf(-a));
    pl = cl; pc = cc; pr = cr;
    cl = nl; cc = nc; cr = nr;
    nc = fut;
  }
}

// ---------------- x_proj: per-token 192 -> 14, d-major input ----------------
__global__ __launch_bounds__(256) void k_xproj(const float* __restrict__ xd,
                                               const float* __restrict__ Wxt,
                                               float* __restrict__ dtBC) {
  __shared__ float Xs[192 * 65];
  __shared__ float Od[64 * 17];
  int blk = blockIdx.x;
  int b = blk >> 7, rem = blk & 127, s = rem >> 6, n0 = (rem & 63) * 64;
  const float* xsrc = xd + ((size_t)s * 8 + b) * 192 * 4096 + n0;
  int tid = threadIdx.x;
  for (int idx = tid; idx < 192 * 64; idx += 256) {
    int c = idx >> 6, t2 = idx & 63;
    Xs[c * 65 + t2] = xsrc[(size_t)c * 4096 + t2];
  }
  __syncthreads();
  int t = tid & 63, og = tid >> 6;
  float a0 = 0.f, a1 = 0.f, a2 = 0.f, a3 = 0.f;
#pragma unroll 4
  for (int c = 0; c < 192; ++c) {
    float x = Xs[c * 65 + t];
    float4 wv = *(const float4*)&Wxt[c * 16 + og * 4];
    a0 += x * wv.x; a1 += x * wv.y; a2 += x * wv.z; a3 += x * wv.w;
  }
  Od[t * 17 + og * 4 + 0] = a0;
  Od[t * 17 + og * 4 + 1] = a1;
  Od[t * 17 + og * 4 + 2] = a2;
  Od[t * 17 + og * 4 + 3] = a3;
  __syncthreads();
  int t0g = b * 8192 + s * 4096 + n0;
  for (int idx = tid; idx < 1024; idx += 256) {
    int tt = idx >> 4, o = idx & 15;
    dtBC[(size_t)(t0g + tt) * 16 + o] = Od[tt * 17 + o];
  }
}

// ---------------- scan pass 1: 64-token chunks, x in registers, 4KB LDS ----------------
__global__ __launch_bounds__(192) void k_scan1(const float* __restrict__ xd,
                                               const float* __restrict__ dtBC,
                                               const float* __restrict__ dtw,
                                               const float* __restrict__ dtbias,
                                               const float* __restrict__ Alog,
                                               float* __restrict__ hend,
                                               float* __restrict__ Pbuf) {
  __shared__ __align__(16) float SBC[64 * 16];
  int c = blockIdx.x & 127, b = blockIdx.x >> 7;
  int s = c >> 6, cl = c & 63;
  int d = threadIdx.x;
  float w0 = dtw[d * 6 + 0], w1 = dtw[d * 6 + 1], w2 = dtw[d * 6 + 2];
  float w3 = dtw[d * 6 + 3], w4 = dtw[d * 6 + 4], w5 = dtw[d * 6 + 5];
  float bb = dtbias[d];
  float4 al = *(const float4*)&Alog[d * 4];
  float A0 = -__expf(al.x), A1 = -__expf(al.y), A2 = -__expf(al.z), A3 = -__expf(al.w);
  int tokbase = b * 8192 + c * 64;
  for (int idx = d; idx < 1024; idx += 192) SBC[idx] = dtBC[(size_t)tokbase * 16 + idx];
  const float* xrow = xd + (((size_t)s * 8 + b) * 192 + d) * 4096 + cl * 64;
  float4 xr[16];
#pragma unroll
  for (int i = 0; i < 16; ++i) xr[i] = *(const float4*)&xrow[i * 4];
  __syncthreads();
  float h0 = 0.f, h1 = 0.f, h2 = 0.f, h3 = 0.f, sd = 0.f;
#pragma unroll
  for (int i = 0; i < 16; ++i) {
    float xv4[4] = {xr[i].x, xr[i].y, xr[i].z, xr[i].w};
#pragma unroll
    for (int j = 0; j < 4; ++j) {
      int l2 = i * 4 + j;
      float4 s0 = *(const float4*)&SBC[l2 * 16 + 0];
      float4 s1 = *(const float4*)&SBC[l2 * 16 + 4];
      float4 s2 = *(const float4*)&SBC[l2 * 16 + 8];
      float pre = bb + w0 * s0.x + w1 * s0.y + w2 * s0.z + w3 * s0.w + w4 * s1.x + w5 * s1.y;
      float ex = __expf(pre);
      float delta = (pre > 15.f) ? pre : __logf(1.f + ex);
      sd += delta;
      float dx = delta * xv4[j];
      h0 = __expf(delta * A0) * h0 + dx * s1.z;
      h1 = __expf(delta * A1) * h1 + dx * s1.w;
      h2 = __expf(delta * A2) * h2 + dx * s2.x;
      h3 = __expf(delta * A3) * h3 + dx * s2.y;
    }
  }
  size_t o = (((size_t)b * 128 + c) * 192 + d) * 4;
  *(float4*)&hend[o] = make_float4(h0, h1, h2, h3);
  *(float4*)&Pbuf[o] = make_float4(__expf(A0 * sd), __expf(A1 * sd), __expf(A2 * sd), __expf(A3 * sd));
}

// ---------------- scan pass 2: cross-chunk combine (128 chunks) ----------------
__global__ __launch_bounds__(256) void k_scan2(const float* __restrict__ hend,
                                               const float* __restrict__ Pbuf,
                                               float* __restrict__ hinit) {
  int e = blockIdx.x * 256 + threadIdx.x;
  if (e >= 8 * 768) return;
  int b = e / 768, r = e - b * 768;
  float h = 0.f;
#pragma unroll 4
  for (int c = 0; c < 128; ++c) {
    int a = (b * 128 + c) * 768 + r;
    hinit[a] = h;
    h = Pbuf[a] * h + hend[a];
  }
}

// ---------------- scan pass 3: replay with h_init, write y token-major ----------------
__global__ __launch_bounds__(192) void k_scan3(const float* __restrict__ xd,
                                               const float* __restrict__ dtBC,
                                               const float* __restrict__ dtw,
                                               const float* __restrict__ dtbias,
                                               const float* __restrict__ Alog,
                                               const float* __restrict__ Dskip,
                                               const float* __restrict__ hinit,
                                               float* __restrict__ ybuf) {
  __shared__ __align__(16) float SBC[64 * 16];
  int c = blockIdx.x & 127, b = blockIdx.x >> 7;
  int s = c >> 6, cl = c & 63;
  int d = threadIdx.x;
  float w0 = dtw[d * 6 + 0], w1 = dtw[d * 6 + 1], w2 = dtw[d * 6 + 2];
  float w3 = dtw[d * 6 + 3], w4 = dtw[d * 6 + 4], w5 = dtw[d * 6 + 5];
  float bb = dtbias[d];
  float4 al = *(const float4*)&Alog[d * 4];
  float A0 = -__expf(al.x), A1 = -__expf(al.y), A2 = -__expf(al.z), A3 = -__expf(al.w);
  float Dv = Dskip[d];
  int tokbase = b * 8192 + c * 64;
  for (int idx = d; idx < 1024; idx += 192) SBC[idx] = dtBC[(size_t)tokbase * 16 + idx];
  const float* xrow = xd + (((size_t)s * 8 + b) * 192 + d) * 4096 + cl * 64;
  float4 xr[16];
#pragma unroll
  for (int i = 0; i < 16; ++i) xr[i] = *(const float4*)&xrow[i * 4];
  size_t o = (((size_t)b * 128 + c) * 192 + d) * 4;
  float4 hv = *(const float4*)&hinit[o];
  float h0 = hv.x, h1 = hv.y, h2 = hv.z, h3 = hv.w;
  __syncthreads();
  float* yout = ybuf + (size_t)tokbase * 192 + d;
#pragma unroll
  for (int i = 0; i < 16; ++i) {
    float xv4[4] = {xr[i].x, xr[i].y, xr[i].z, xr[i].w};
#pragma unroll
    for (int j = 0; j < 4; ++j) {
      int l2 = i * 4 + j;
      float4 s0 = *(const float4*)&SBC[l2 * 16 + 0];
      float4 s1 = *(const float4*)&SBC[l2 * 16 + 4];
      float4 s2 = *(const float4*)&SBC[l2 * 16 + 8];
      float4 s3 = *(const float4*)&SBC[l2 * 16 + 12];
      float pre = bb + w0 * s0.x + w1 * s0.y + w2 * s0.z + w3 * s0.w + w4 * s1.x + w5 * s1.y;
      float ex = __expf(pre);
      float delta = (pre > 15.f) ? pre : __logf(1.f + ex);
      float xv = xv4[j];
      float dx = delta * xv;
      h0 = __expf(delta * A0) * h0 + dx * s1.z;
      h1 = __expf(delta * A1) * h1 + dx * s1.w;
      h2 = __expf(delta * A2) * h2 + dx * s2.x;
      h3 = __expf(delta * A3) * h3 + dx * s2.y;
      yout[(size_t)l2 * 192] = h0 * s2.z + h1 * s2.w + h2 * s3.x + h3 * s3.y + Dv * xv;
    }
  }
}

// ---------------- fused LayerNorm + z-gate + out-proj + stream-fusion (bf16 MFMA) ----------------
// 6 waves; wave w owns output channels w*16..w*16+15 (B-frags register-resident, K=192, 2 kc halves
// accumulate into the same C). LN/gate wave-per-token in registers -> bf16 LDS tile [64][200].
__global__ __launch_bounds__(384) void k_outfuse(const float* __restrict__ ybuf,
                                                 const unsigned short* __restrict__ zbufh,
                                                 const float* __restrict__ lng,
                                                 const float* __restrict__ lnb,
                                                 const unsigned short* __restrict__ Mgb,
                                                 float* __restrict__ out) {
  __shared__ __align__(16) unsigned short Xbf[64 * 200];  // [t][k] pad 200 (row stride 100 floats -> 4-bank step)
  int tile = blockIdx.x & 63, b = blockIdx.x >> 6;
  int n0 = tile * 64;
  int tid = threadIdx.x;
  int w = tid >> 6, lane = tid & 63;
  float lg0 = lng[lane], lg1 = lng[lane + 64], lg2 = lng[lane + 128];
  float lb0 = lnb[lane], lb1 = lnb[lane + 64], lb2 = lnb[lane + 128];

  // B-fragments: wave w -> outs w*16 + (lane&15); k-slice (lane>>4)*8
  const unsigned short* bb = Mgb + ((size_t)(w * 16 + (lane & 15))) * 192 + ((lane >> 4) * 8);
  short8_t bfr[2][6];
#pragma unroll
  for (int kc = 0; kc < 2; ++kc)
#pragma unroll
    for (int ks = 0; ks < 6; ++ks)
      bfr[kc][ks] = *(const short8_t*)(bb + kc * 96 * 192 + ks * 32);

  f32x4 acc[4];
  f32x4 zz = {0.f, 0.f, 0.f, 0.f};
#pragma unroll
  for (int mt = 0; mt < 4; ++mt) acc[mt] = zz;

  int arow = lane & 15, acol = (lane >> 4) * 8;
  for (int kc = 0; kc < 2; ++kc) {
    size_t tokb = (size_t)b * 8192 + (size_t)kc * 4096 + n0;
    if (kc) __syncthreads();   // Xbf reuse: wait for all MFMA reads of kc=0
    // ---- wave-per-token LN + gate -> bf16 LDS ----
    for (int t = w; t < 64; t += 6) {
      const float* yr = ybuf + (tokb + t) * 192;
      const unsigned short* zr = zbufh + (tokb + t) * 192;
      float y0 = yr[lane], y1 = yr[lane + 64], y2 = yr[lane + 128];
      float z0 = bf2f(zr[lane]), z1 = bf2f(zr[lane + 64]), z2 = bf2f(zr[lane + 128]);
      float sm = y0 + y1 + y2;
      float sq = y0 * y0 + y1 * y1 + y2 * y2;
#pragma unroll
      for (int off = 32; off; off >>= 1) {
        sm += __shfl_xor(sm, off);
        sq += __shfl_xor(sq, off);
      }
      float mu = sm * (1.f / 192.f);
      float var = sq * (1.f / 192.f) - mu * mu;
      float rstd = rsqrtf(var + EPSV);
      Xbf[t * 200 + lane]       = f2bf(((y0 - mu) * rstd * lg0 + lb0) * siluf(z0));
      Xbf[t * 200 + lane + 64]  = f2bf(((y1 - mu) * rstd * lg1 + lb1) * siluf(z1));
      Xbf[t * 200 + lane + 128] = f2bf(((y2 - mu) * rstd * lg2 + lb2) * siluf(z2));
    }
    __syncthreads();
    // ---- MFMA: 4 m-tiles x K=192 ----
#pragma unroll
    for (int mt = 0; mt < 4; ++mt) {
      const unsigned short* ap = &Xbf[(mt * 16 + arow) * 200 + acol];
#pragma unroll
      for (int ks = 0; ks < 6; ++ks) {
        short8_t a = *(const short8_t*)(ap + ks * 32);
        acc[mt] = __builtin_amdgcn_mfma_f32_16x16x32_bf16(a, bfr[kc][ks], acc[mt], 0, 0, 0);
      }
    }
  }
  // C layout: col(out)=lane&15, row(token)=(lane>>4)*4+reg -> float4 token-contiguous store
  int rowoff = (lane >> 4) * 4;
  float* op = out + ((size_t)b * 96 + w * 16 + (lane & 15)) * 4096 + n0 + rowoff;
#pragma unroll
  for (int mt = 0; mt < 4; ++mt) {
    f32x4 a = acc[mt];
    *(float4*)&op[mt * 16] = make_float4(a[0], a[1], a[2], a[3]);
  }
}

extern "C" void kernel_launch(void* const* d_in, const int* in_sizes, int n_in,
                              void* d_out, int out_size, void* d_ws, size_t ws_size,
                              hipStream_t stream) {
  (void)in_sizes; (void)n_in; (void)out_size; (void)ws_size;
  const float* img  = (const float*)d_in[0];
  const float* text = (const float*)d_in[1];
  const float* Wii  = (const float*)d_in[2];
  const float* Wit  = (const float*)d_in[3];
  const float* cwi  = (const float*)d_in[4];
  const float* cbi  = (const float*)d_in[5];
  const float* bgi  = (const float*)d_in[6];
  const float* bbi  = (const float*)d_in[7];
  const float* bmi  = (const float*)d_in[8];
  const float* bvi  = (const float*)d_in[9];
  const float* cwt  = (const float*)d_in[10];
  const float* cbt  = (const float*)d_in[11];
  const float* bgt  = (const float*)d_in[12];
  const float* bbt  = (const float*)d_in[13];
  const float* bmt  = (const float*)d_in[14];
  const float* bvt  = (const float*)d_in[15];
  const float* xpw  = (const float*)d_in[16];
  const float* dtw  = (const float*)d_in[17];
  const float* dtb  = (const float*)d_in[18];
  const float* Alog = (const float*)d_in[19];
  const float* Dsk  = (const float*)d_in[20];
  const float* lng  = (const float*)d_in[21];
  const float* lnb  = (const float*)d_in[22];
  const float* Wout = (const float*)d_in[23];
  const float* Wfus = (const float*)d_in[24];

  float* ws    = (float*)d_ws;
  float* xsp   = ws;
  float* zbuf  = xsp + N_XSP;
  float* xd    = zbuf + N_ZBUF;
  float* dtBC  = xd + N_XD;
  float* hend  = dtBC + N_DTBC;
  float* Pbuf  = hend + N_STATE;
  float* hinit = Pbuf + N_STATE;
  unsigned short* Mgb = (unsigned short*)(hinit + N_STATE);
  float* Wxt   = (float*)(Mgb + 36864);
  unsigned short* wbi = (unsigned short*)(Wxt + 3072);
  unsigned short* wbt = wbi + 36864;
  unsigned short* zbufh = (unsigned short*)zbuf;
  float* ybuf  = xsp;   // xsp dead after k_conv
  float* out   = (float*)d_out;

  hipLaunchKernelGGL(k_prep, dim3(444), dim3(256), 0, stream, Wout, Wfus, Wii, Wit, xpw, Mgb, wbi, wbt, Wxt);
  hipLaunchKernelGGL(k_inproj, dim3(1024), dim3(256), 0, stream, img, text, wbi, wbt, xsp, zbufh);
  hipLaunchKernelGGL(k_conv, dim3(1536), dim3(256), 0, stream, xsp,
                     cwi, cbi, bgi, bbi, bmi, bvi, cwt, cbt, bgt, bbt, bmt, bvt, xd);
  hipLaunchKernelGGL(k_xproj, dim3(1024), dim3(256), 0, stream, xd, Wxt, dtBC);
  hipLaunchKernelGGL(k_scan1, dim3(1024), dim3(192), 0, stream, xd, dtBC, dtw, dtb, Alog, hend, Pbuf);
  hipLaunchKernelGGL(k_scan2, dim3(24), dim3(256), 0, stream, hend, Pbuf, hinit);
  hipLaunchKernelGGL(k_scan3, dim3(1024), dim3(192), 0, stream, xd, dtBC, dtw, dtb, Alog, Dsk, hinit, xsp);
  hipLaunchKernelGGL(k_outfuse, dim3(512), dim3(384), 0, stream, ybuf, zbufh, lng, lnb, Mgb, out);
}

// Round 7
// 181.211 us; speedup vs baseline: 2.8982x; 1.0885x over previous
//
#include <hip/hip_runtime.h>
#include <math.h>

#define EPSV 1e-5f

typedef __attribute__((ext_vector_type(8))) short short8_t;   // 8 bf16 (4 VGPRs)
typedef __attribute__((ext_vector_type(4))) float f32x4;      // MFMA acc

// ---------------- workspace layout (floats) ----------------
// xsp  : (2,8,192,4096) fp32 x-branch, d-major (conv in)  | reused as bf16 ybuf
// zbuf : slot 12.58M floats; bf16 z (8,8192,192) uses half
// xd   : slot 12.58M floats; bf16 conv output (2,8,192,4096)
// dtBC : (65536,16) fp32 per-token dt(6),B(4),C(4),pad
// hend/Pbuf/hinit : (8,128,192,4) chunk-scan state
// Mgb: bf16 [2*96][192]; Wxt: fp32 (192,16); wbi/wbt: bf16 W_in [384][96]
#define N_XSP   12582912
#define N_ZBUF  12582912
#define N_XD    12582912
#define N_DTBC  1048576
#define N_STATE 786432

__device__ __forceinline__ float siluf(float v) {
  return v / (1.f + __expf(-v));
}

__device__ __forceinline__ unsigned short f2bf(float f) {  // RTNE fp32->bf16
  unsigned int u = __float_as_uint(f);
  u += 0x7fffu + ((u >> 16) & 1u);
  return (unsigned short)(u >> 16);
}

__device__ __forceinline__ float bf2f(unsigned short h) {
  return __uint_as_float(((unsigned int)h) << 16);
}

// ---------------- prep: Mg(bf16) + bf16 W_in + x_proj^T (fp32) ----------------
__global__ __launch_bounds__(256) void k_prep(const float* __restrict__ Wout,
                                              const float* __restrict__ Wf,
                                              const float* __restrict__ Wii,
                                              const float* __restrict__ Wit,
                                              const float* __restrict__ xpw,
                                              unsigned short* __restrict__ Mgb,
                                              unsigned short* __restrict__ wbi,
                                              unsigned short* __restrict__ wbt,
                                              float* __restrict__ Wxt) {
  int e = blockIdx.x * 256 + threadIdx.x;
  if (e < 36864) {                     // Mg[k][o] = sum_j Wf[o][half*96+j]*Wout[j][k%192]
    int k = e / 96, o = e - k * 96;
    int half = (k >= 192) ? 1 : 0;
    int c = k - half * 192;
    const float* wfr = Wf + o * 192 + half * 96;
    float acc = 0.f;
#pragma unroll 4
    for (int j = 0; j < 96; ++j) acc += wfr[j] * Wout[j * 192 + c];
    Mgb[(half * 96 + o) * 192 + c] = f2bf(acc);   // [kc][out][k] bf16
  } else if (e < 73728) {
    int i = e - 36864;
    wbi[i] = f2bf(Wii[i]);
  } else if (e < 110592) {
    int i = e - 73728;
    wbt[i] = f2bf(Wit[i]);
  } else if (e < 113664) {             // Wxt[c][o], o 14..15 zero
    int i = e - 110592;
    int c = i >> 4, o = i & 15;
    Wxt[i] = (o < 14) ? xpw[o * 192 + c] : 0.f;
  }
}

// ---------------- in_proj via bf16 MFMA: 64 tokens x 384 outs, K=96 ----------------
__global__ __launch_bounds__(256, 2) void k_inproj(const float* __restrict__ img,
                                                   const float* __restrict__ text,
                                                   const unsigned short* __restrict__ wbi,
                                                   const unsigned short* __restrict__ wbt,
                                                   float* __restrict__ xsp,
                                                   unsigned short* __restrict__ zbufh) {
  __shared__ __align__(16) unsigned short Xbf[64 * 104];  // [t][k] pad 104
  int bx = blockIdx.x;
  int tile = bx & 63, b = (bx >> 6) & 7, s = bx >> 9;
  int n0 = tile * 64;
  int tid = threadIdx.x;
  int w = tid >> 6, lane = tid & 63;
  const float* src = s ? text : img;
  const unsigned short* wsel = s ? wbt : wbi;

  const unsigned short* wbase = wsel + ((size_t)(w * 96 + (lane & 15))) * 96 + ((lane >> 4) * 8);
  short8_t bfr[18];
#pragma unroll
  for (int nt = 0; nt < 6; ++nt)
#pragma unroll
    for (int ks = 0; ks < 3; ++ks)
      bfr[nt * 3 + ks] = *(const short8_t*)(wbase + nt * 16 * 96 + ks * 32);

  for (int idx = tid; idx < 6144; idx += 256) {
    int c = idx >> 6, t = idx & 63;
    Xbf[t * 104 + c] = f2bf(src[((size_t)b * 96 + c) * 4096 + n0 + t]);
  }
  __syncthreads();

  f32x4 acc[4][6];
  f32x4 zz = {0.f, 0.f, 0.f, 0.f};
#pragma unroll
  for (int mt = 0; mt < 4; ++mt)
#pragma unroll
    for (int nt = 0; nt < 6; ++nt) acc[mt][nt] = zz;

  int arow = lane & 15;
  int acol = (lane >> 4) * 8;
#pragma unroll
  for (int mt = 0; mt < 4; ++mt) {
    const unsigned short* ap = &Xbf[(mt * 16 + arow) * 104 + acol];
    short8_t a0 = *(const short8_t*)(ap);
    short8_t a1 = *(const short8_t*)(ap + 32);
    short8_t a2 = *(const short8_t*)(ap + 64);
#pragma unroll
    for (int nt = 0; nt < 6; ++nt) {
      acc[mt][nt] = __builtin_amdgcn_mfma_f32_16x16x32_bf16(a0, bfr[nt * 3 + 0], acc[mt][nt], 0, 0, 0);
      acc[mt][nt] = __builtin_amdgcn_mfma_f32_16x16x32_bf16(a1, bfr[nt * 3 + 1], acc[mt][nt], 0, 0, 0);
      acc[mt][nt] = __builtin_amdgcn_mfma_f32_16x16x32_bf16(a2, bfr[nt * 3 + 2], acc[mt][nt], 0, 0, 0);
    }
  }

  int rowoff = (lane >> 4) * 4;
  if (w < 2) {   // x half -> d-major spatial (fp32)
#pragma unroll
    for (int nt = 0; nt < 6; ++nt) {
      int d = w * 96 + nt * 16 + (lane & 15);
      float* xp = xsp + (((size_t)s * 8 + b) * 192 + d) * 4096 + n0 + rowoff;
#pragma unroll
      for (int mt = 0; mt < 4; ++mt) {
        f32x4 a = acc[mt][nt];
        *(float4*)&xp[mt * 16] = make_float4(a[0], a[1], a[2], a[3]);
      }
    }
  } else {       // z half -> token-major bf16
    size_t tokb = (size_t)b * 8192 + (size_t)s * 4096 + n0;
#pragma unroll
    for (int nt = 0; nt < 6; ++nt) {
      int ch = (w - 2) * 96 + nt * 16 + (lane & 15);
#pragma unroll
      for (int mt = 0; mt < 4; ++mt) {
        f32x4 a = acc[mt][nt];
        unsigned short* zp = zbufh + (tokb + mt * 16 + rowoff) * 192 + ch;
        zp[0] = f2bf(a[0]); zp[192] = f2bf(a[1]); zp[384] = f2bf(a[2]); zp[576] = f2bf(a[3]);
      }
    }
  }
}

// ---------------- depthwise 3x3 conv + BN + SiLU: bf16 output ----------------
__global__ __launch_bounds__(256) void k_conv(
    const float* __restrict__ xsp,
    const float* __restrict__ cwi, const float* __restrict__ cbi,
    const float* __restrict__ bgi, const float* __restrict__ bbi,
    const float* __restrict__ bmi, const float* __restrict__ bvi,
    const float* __restrict__ cwt, const float* __restrict__ cbt,
    const float* __restrict__ bgt, const float* __restrict__ bbt,
    const float* __restrict__ bmt, const float* __restrict__ bvt,
    unsigned short* __restrict__ xdh) {
  int bid = blockIdx.x;
  int img = bid / 96;                 // 0..15
  int d0 = (bid - img * 96) * 2;
  int widx = threadIdx.x >> 6;
  int lane = threadIdx.x & 63;
  int d = d0 + (widx >> 1);
  int half = widx & 1;
  int s = img >> 3;
  const float* cw = s ? cwt : cwi;
  const float* cb = s ? cbt : cbi;
  const float* bg = s ? bgt : bgi;
  const float* bb2 = s ? bbt : bbi;
  const float* bm = s ? bmt : bmi;
  const float* bv = s ? bvt : bvi;
  const float* src = xsp + ((size_t)img * 192 + d) * 4096;
  unsigned short* dst = xdh + ((size_t)img * 192 + d) * 4096;
  float c0 = cw[d * 9 + 0], c1 = cw[d * 9 + 1], c2 = cw[d * 9 + 2];
  float c3 = cw[d * 9 + 3], c4 = cw[d * 9 + 4], c5 = cw[d * 9 + 5];
  float c6 = cw[d * 9 + 6], c7 = cw[d * 9 + 7], c8 = cw[d * 9 + 8];
  float sc = bg[d] * rsqrtf(bv[d] + EPSV);
  float eb = (cb[d] - bm[d]) * sc + bb2[d];
  int h0 = half * 32;
  float pc = (h0 > 0) ? src[(h0 - 1) * 64 + lane] : 0.f;
  float cc = src[h0 * 64 + lane];
  float nc = src[(h0 + 1) * 64 + lane];
  float t;
  t = __shfl_up(pc, 1);  float pl = (lane == 0) ? 0.f : t;
  t = __shfl_down(pc, 1); float pr = (lane == 63) ? 0.f : t;
  t = __shfl_up(cc, 1);  float cl = (lane == 0) ? 0.f : t;
  t = __shfl_down(cc, 1); float cr = (lane == 63) ? 0.f : t;
#pragma unroll 4
  for (int i = 0; i < 32; ++i) {
    int h = h0 + i;
    float fut = (h + 2 <= 63) ? src[(h + 2) * 64 + lane] : 0.f;
    t = __shfl_up(nc, 1);  float nl = (lane == 0) ? 0.f : t;
    t = __shfl_down(nc, 1); float nr = (lane == 63) ? 0.f : t;
    float a = pl * c0 + pc * c1 + pr * c2
            + cl * c3 + cc * c4 + cr * c5
            + nl * c6 + nc * c7 + nr * c8;
    a = a * sc + eb;
    dst[h * 64 + lane] = f2bf(a / (1.f + __expf(-a)));
    pl = cl; pc = cc; pr = cr;
    cl = nl; cc = nc; cr = nr;
    nc = fut;
  }
}

// ---------------- scan pass A: fused x_proj + chunk scan (hend, P, dtBC out) ----------------
__global__ __launch_bounds__(192) void k_scanA(const unsigned short* __restrict__ xdh,
                                               const float* __restrict__ Wxt,
                                               const float* __restrict__ dtw,
                                               const float* __restrict__ dtbias,
                                               const float* __restrict__ Alog,
                                               float* __restrict__ dtBC,
                                               float* __restrict__ hend,
                                               float* __restrict__ Pbuf) {
  __shared__ __align__(16) unsigned short Xt[192 * 66];  // [d][t] stride 66 -> 2-way banks
  __shared__ __align__(16) float SBC[64 * 16];
  __shared__ float Wp[192 * 16];
  int c = blockIdx.x & 127, b = blockIdx.x >> 7;
  int s = c >> 6, cl = c & 63;
  int d = threadIdx.x;
  int tokbase = b * 8192 + c * 64;

  // stage x row (64 bf16 = 128B) -> LDS
  const unsigned short* xrow = xdh + (((size_t)s * 8 + b) * 192 + d) * 4096 + cl * 64;
  {
    unsigned int* dstp = (unsigned int*)&Xt[(size_t)d * 66];
#pragma unroll
    for (int i = 0; i < 8; ++i) {
      uint4 v = *(const uint4*)(xrow + i * 8);
      dstp[i * 4 + 0] = v.x; dstp[i * 4 + 1] = v.y; dstp[i * 4 + 2] = v.z; dstp[i * 4 + 3] = v.w;
    }
  }
  for (int idx = d; idx < 3072; idx += 192) Wp[idx] = Wxt[idx];

  float w0 = dtw[d * 6 + 0], w1 = dtw[d * 6 + 1], w2 = dtw[d * 6 + 2];
  float w3 = dtw[d * 6 + 3], w4 = dtw[d * 6 + 4], w5 = dtw[d * 6 + 5];
  float bb = dtbias[d];
  float4 al = *(const float4*)&Alog[d * 4];
  float A0 = -__expf(al.x), A1 = -__expf(al.y), A2 = -__expf(al.z), A3 = -__expf(al.w);
  __syncthreads();

  // ---- fused x_proj: thread (t, og) -> outs og+3k ----
  {
    int t = d & 63, og = d >> 6;
    float a0 = 0.f, a1 = 0.f, a2 = 0.f, a3 = 0.f, a4 = 0.f;
#pragma unroll 4
    for (int cc2 = 0; cc2 < 192; ++cc2) {
      float x = bf2f(Xt[cc2 * 66 + t]);
      const float* wr = &Wp[cc2 * 16 + og];
      a0 += x * wr[0]; a1 += x * wr[3]; a2 += x * wr[6]; a3 += x * wr[9]; a4 += x * wr[12];
    }
    float* sb = &SBC[t * 16 + og];
    sb[0] = a0; sb[3] = a1; sb[6] = a2; sb[9] = a3; sb[12] = a4;
    float* db = &dtBC[(size_t)(tokbase + t) * 16 + og];
    db[0] = a0; db[3] = a1; db[6] = a2; db[9] = a3; db[12] = a4;
    if (og == 0) { SBC[t * 16 + 15] = 0.f; dtBC[(size_t)(tokbase + t) * 16 + 15] = 0.f; }
  }
  __syncthreads();

  // ---- chunk scan from zero state ----
  float h0 = 0.f, h1 = 0.f, h2 = 0.f, h3 = 0.f, sd = 0.f;
#pragma unroll 8
  for (int l2 = 0; l2 < 64; ++l2) {
    float4 s0 = *(const float4*)&SBC[l2 * 16 + 0];
    float4 s1 = *(const float4*)&SBC[l2 * 16 + 4];
    float4 s2 = *(const float4*)&SBC[l2 * 16 + 8];
    float pre = bb + w0 * s0.x + w1 * s0.y + w2 * s0.z + w3 * s0.w + w4 * s1.x + w5 * s1.y;
    float ex = __expf(pre);
    float delta = (pre > 15.f) ? pre : __logf(1.f + ex);
    sd += delta;
    float dx = delta * bf2f(Xt[d * 66 + l2]);
    h0 = __expf(delta * A0) * h0 + dx * s1.z;
    h1 = __expf(delta * A1) * h1 + dx * s1.w;
    h2 = __expf(delta * A2) * h2 + dx * s2.x;
    h3 = __expf(delta * A3) * h3 + dx * s2.y;
  }
  size_t o = (((size_t)b * 128 + c) * 192 + d) * 4;
  *(float4*)&hend[o] = make_float4(h0, h1, h2, h3);
  *(float4*)&Pbuf[o] = make_float4(__expf(A0 * sd), __expf(A1 * sd), __expf(A2 * sd), __expf(A3 * sd));
}

// ---------------- scan pass 2: cross-chunk combine (128 chunks) ----------------
__global__ __launch_bounds__(256) void k_scan2(const float* __restrict__ hend,
                                               const float* __restrict__ Pbuf,
                                               float* __restrict__ hinit) {
  int e = blockIdx.x * 256 + threadIdx.x;
  if (e >= 8 * 768) return;
  int b = e / 768, r = e - b * 768;
  float h = 0.f;
#pragma unroll 4
  for (int c = 0; c < 128; ++c) {
    int a = (b * 128 + c) * 768 + r;
    hinit[a] = h;
    h = Pbuf[a] * h + hend[a];
  }
}

// ---------------- scan pass B: replay with h_init, write y bf16 token-major ----------------
__global__ __launch_bounds__(192) void k_scanB(const unsigned short* __restrict__ xdh,
                                               const float* __restrict__ dtBC,
                                               const float* __restrict__ dtw,
                                               const float* __restrict__ dtbias,
                                               const float* __restrict__ Alog,
                                               const float* __restrict__ Dskip,
                                               const float* __restrict__ hinit,
                                               unsigned short* __restrict__ ybufh) {
  __shared__ __align__(16) float SBC[64 * 16];
  int c = blockIdx.x & 127, b = blockIdx.x >> 7;
  int s = c >> 6, cl = c & 63;
  int d = threadIdx.x;
  float w0 = dtw[d * 6 + 0], w1 = dtw[d * 6 + 1], w2 = dtw[d * 6 + 2];
  float w3 = dtw[d * 6 + 3], w4 = dtw[d * 6 + 4], w5 = dtw[d * 6 + 5];
  float bb = dtbias[d];
  float4 al = *(const float4*)&Alog[d * 4];
  float A0 = -__expf(al.x), A1 = -__expf(al.y), A2 = -__expf(al.z), A3 = -__expf(al.w);
  float Dv = Dskip[d];
  int tokbase = b * 8192 + c * 64;
  for (int idx = d; idx < 1024; idx += 192) SBC[idx] = dtBC[(size_t)tokbase * 16 + idx];
  const unsigned short* xrow = xdh + (((size_t)s * 8 + b) * 192 + d) * 4096 + cl * 64;
  short8_t xr8[8];
#pragma unroll
  for (int i = 0; i < 8; ++i) xr8[i] = *(const short8_t*)(xrow + i * 8);
  size_t o = (((size_t)b * 128 + c) * 192 + d) * 4;
  float4 hv = *(const float4*)&hinit[o];
  float h0 = hv.x, h1 = hv.y, h2 = hv.z, h3 = hv.w;
  __syncthreads();
  unsigned short* yout = ybufh + (size_t)tokbase * 192 + d;
#pragma unroll
  for (int i = 0; i < 8; ++i) {
#pragma unroll
    for (int j = 0; j < 8; ++j) {
      int l2 = i * 8 + j;
      float4 s0 = *(const float4*)&SBC[l2 * 16 + 0];
      float4 s1 = *(const float4*)&SBC[l2 * 16 + 4];
      float4 s2 = *(const float4*)&SBC[l2 * 16 + 8];
      float4 s3 = *(const float4*)&SBC[l2 * 16 + 12];
      float pre = bb + w0 * s0.x + w1 * s0.y + w2 * s0.z + w3 * s0.w + w4 * s1.x + w5 * s1.y;
      float ex = __expf(pre);
      float delta = (pre > 15.f) ? pre : __logf(1.f + ex);
      float xv = bf2f((unsigned short)xr8[i][j]);
      float dx = delta * xv;
      h0 = __expf(delta * A0) * h0 + dx * s1.z;
      h1 = __expf(delta * A1) * h1 + dx * s1.w;
      h2 = __expf(delta * A2) * h2 + dx * s2.x;
      h3 = __expf(delta * A3) * h3 + dx * s2.y;
      yout[(size_t)l2 * 192] = f2bf(h0 * s2.z + h1 * s2.w + h2 * s3.x + h3 * s3.y + Dv * xv);
    }
  }
}

// ---------------- fused LayerNorm + z-gate + out-proj + stream-fusion (bf16 MFMA) ----------------
__global__ __launch_bounds__(384) void k_outfuse(const unsigned short* __restrict__ ybufh,
                                                 const unsigned short* __restrict__ zbufh,
                                                 const float* __restrict__ lng,
                                                 const float* __restrict__ lnb,
                                                 const unsigned short* __restrict__ Mgb,
                                                 float* __restrict__ out) {
  __shared__ __align__(16) unsigned short Xbf[64 * 200];  // [t][k] pad 200
  int tile = blockIdx.x & 63, b = blockIdx.x >> 6;
  int n0 = tile * 64;
  int tid = threadIdx.x;
  int w = tid >> 6, lane = tid & 63;
  float lg0 = lng[lane], lg1 = lng[lane + 64], lg2 = lng[lane + 128];
  float lb0 = lnb[lane], lb1 = lnb[lane + 64], lb2 = lnb[lane + 128];

  const unsigned short* bb = Mgb + ((size_t)(w * 16 + (lane & 15))) * 192 + ((lane >> 4) * 8);
  short8_t bfr[2][6];
#pragma unroll
  for (int kc = 0; kc < 2; ++kc)
#pragma unroll
    for (int ks = 0; ks < 6; ++ks)
      bfr[kc][ks] = *(const short8_t*)(bb + kc * 96 * 192 + ks * 32);

  f32x4 acc[4];
  f32x4 zz = {0.f, 0.f, 0.f, 0.f};
#pragma unroll
  for (int mt = 0; mt < 4; ++mt) acc[mt] = zz;

  int arow = lane & 15, acol = (lane >> 4) * 8;
  for (int kc = 0; kc < 2; ++kc) {
    size_t tokb = (size_t)b * 8192 + (size_t)kc * 4096 + n0;
    if (kc) __syncthreads();
    for (int t = w; t < 64; t += 6) {
      const unsigned short* yr = ybufh + (tokb + t) * 192;
      const unsigned short* zr = zbufh + (tokb + t) * 192;
      float y0 = bf2f(yr[lane]), y1 = bf2f(yr[lane + 64]), y2 = bf2f(yr[lane + 128]);
      float z0 = bf2f(zr[lane]), z1 = bf2f(zr[lane + 64]), z2 = bf2f(zr[lane + 128]);
      float sm = y0 + y1 + y2;
      float sq = y0 * y0 + y1 * y1 + y2 * y2;
#pragma unroll
      for (int off = 32; off; off >>= 1) {
        sm += __shfl_xor(sm, off);
        sq += __shfl_xor(sq, off);
      }
      float mu = sm * (1.f / 192.f);
      float var = sq * (1.f / 192.f) - mu * mu;
      float rstd = rsqrtf(var + EPSV);
      Xbf[t * 200 + lane]       = f2bf(((y0 - mu) * rstd * lg0 + lb0) * siluf(z0));
      Xbf[t * 200 + lane + 64]  = f2bf(((y1 - mu) * rstd * lg1 + lb1) * siluf(z1));
      Xbf[t * 200 + lane + 128] = f2bf(((y2 - mu) * rstd * lg2 + lb2) * siluf(z2));
    }
    __syncthreads();
#pragma unroll
    for (int mt = 0; mt < 4; ++mt) {
      const unsigned short* ap = &Xbf[(mt * 16 + arow) * 200 + acol];
#pragma unroll
      for (int ks = 0; ks < 6; ++ks) {
        short8_t a = *(const short8_t*)(ap + ks * 32);
        acc[mt] = __builtin_amdgcn_mfma_f32_16x16x32_bf16(a, bfr[kc][ks], acc[mt], 0, 0, 0);
      }
    }
  }
  int rowoff = (lane >> 4) * 4;
  float* op = out + ((size_t)b * 96 + w * 16 + (lane & 15)) * 4096 + n0 + rowoff;
#pragma unroll
  for (int mt = 0; mt < 4; ++mt) {
    f32x4 a = acc[mt];
    *(float4*)&op[mt * 16] = make_float4(a[0], a[1], a[2], a[3]);
  }
}

extern "C" void kernel_launch(void* const* d_in, const int* in_sizes, int n_in,
                              void* d_out, int out_size, void* d_ws, size_t ws_size,
                              hipStream_t stream) {
  (void)in_sizes; (void)n_in; (void)out_size; (void)ws_size;
  const float* img  = (const float*)d_in[0];
  const float* text = (const float*)d_in[1];
  const float* Wii  = (const float*)d_in[2];
  const float* Wit  = (const float*)d_in[3];
  const float* cwi  = (const float*)d_in[4];
  const float* cbi  = (const float*)d_in[5];
  const float* bgi  = (const float*)d_in[6];
  const float* bbi  = (const float*)d_in[7];
  const float* bmi  = (const float*)d_in[8];
  const float* bvi  = (const float*)d_in[9];
  const float* cwt  = (const float*)d_in[10];
  const float* cbt  = (const float*)d_in[11];
  const float* bgt  = (const float*)d_in[12];
  const float* bbt  = (const float*)d_in[13];
  const float* bmt  = (const float*)d_in[14];
  const float* bvt  = (const float*)d_in[15];
  const float* xpw  = (const float*)d_in[16];
  const float* dtw  = (const float*)d_in[17];
  const float* dtb  = (const float*)d_in[18];
  const float* Alog = (const float*)d_in[19];
  const float* Dsk  = (const float*)d_in[20];
  const float* lng  = (const float*)d_in[21];
  const float* lnb  = (const float*)d_in[22];
  const float* Wout = (const float*)d_in[23];
  const float* Wfus = (const float*)d_in[24];

  float* ws    = (float*)d_ws;
  float* xsp   = ws;
  unsigned short* zbufh = (unsigned short*)(xsp + N_XSP);
  unsigned short* xdh   = (unsigned short*)(xsp + N_XSP + N_ZBUF);
  float* dtBC  = xsp + N_XSP + N_ZBUF + N_XD;
  float* hend  = dtBC + N_DTBC;
  float* Pbuf  = hend + N_STATE;
  float* hinit = Pbuf + N_STATE;
  unsigned short* Mgb = (unsigned short*)(hinit + N_STATE);
  float* Wxt   = (float*)(Mgb + 36864);
  unsigned short* wbi = (unsigned short*)(Wxt + 3072);
  unsigned short* wbt = wbi + 36864;
  unsigned short* ybufh = (unsigned short*)xsp;  // xsp dead after k_conv
  float* out   = (float*)d_out;

  hipLaunchKernelGGL(k_prep, dim3(444), dim3(256), 0, stream, Wout, Wfus, Wii, Wit, xpw, Mgb, wbi, wbt, Wxt);
  hipLaunchKernelGGL(k_inproj, dim3(1024), dim3(256), 0, stream, img, text, wbi, wbt, xsp, zbufh);
  hipLaunchKernelGGL(k_conv, dim3(1536), dim3(256), 0, stream, xsp,
                     cwi, cbi, bgi, bbi, bmi, bvi, cwt, cbt, bgt, bbt, bmt, bvt, xdh);
  hipLaunchKernelGGL(k_scanA, dim3(1024), dim3(192), 0, stream, xdh, Wxt, dtw, dtb, Alog, dtBC, hend, Pbuf);
  hipLaunchKernelGGL(k_scan2, dim3(24), dim3(256), 0, stream, hend, Pbuf, hinit);
  hipLaunchKernelGGL(k_scanB, dim3(1024), dim3(192), 0, stream, xdh, dtBC, dtw, dtb, Alog, Dsk, hinit, ybufh);
  hipLaunchKernelGGL(k_outfuse, dim3(512), dim3(384), 0, stream, ybufh, zbufh, lng, lnb, Mgb, out);
}

// Round 8
// 147.523 us; speedup vs baseline: 3.5601x; 1.2284x over previous
//
#include <hip/hip_runtime.h>
#include <math.h>

#define EPSV 1e-5f

typedef __attribute__((ext_vector_type(8))) short short8_t;   // 8 bf16 (4 VGPRs)
typedef __attribute__((ext_vector_type(4))) float f32x4;      // MFMA acc

// ---------------- workspace layout ----------------
// xsp slot : bf16 x-branch (2,8,192,4096) d-major (conv in) | reused as bf16 ybuf
// zbuf slot: bf16 z (8,8192,192) token-major
// xd  slot : bf16 conv output (2,8,192,4096) d-major
// dtBC : (65536,16) fp32; hend/Pbuf/hinit : (8,128,192,4)
// Mgb: bf16 [2*96][192]; Wxtb: bf16 [16][192]; wbi/wbt: bf16 W_in [384][96]
#define N_XSP   12582912
#define N_ZBUF  12582912
#define N_XD    12582912
#define N_DTBC  1048576
#define N_STATE 786432

__device__ __forceinline__ float siluf(float v) {
  return v / (1.f + __expf(-v));
}

__device__ __forceinline__ unsigned short f2bf(float f) {  // RTNE fp32->bf16
  unsigned int u = __float_as_uint(f);
  u += 0x7fffu + ((u >> 16) & 1u);
  return (unsigned short)(u >> 16);
}

__device__ __forceinline__ float bf2f(unsigned short h) {
  return __uint_as_float(((unsigned int)h) << 16);
}

// ---------------- prep: Mg(bf16) + bf16 W_in + bf16 x_proj ----------------
__global__ __launch_bounds__(256) void k_prep(const float* __restrict__ Wout,
                                              const float* __restrict__ Wf,
                                              const float* __restrict__ Wii,
                                              const float* __restrict__ Wit,
                                              const float* __restrict__ xpw,
                                              unsigned short* __restrict__ Mgb,
                                              unsigned short* __restrict__ wbi,
                                              unsigned short* __restrict__ wbt,
                                              unsigned short* __restrict__ Wxtb) {
  int e = blockIdx.x * 256 + threadIdx.x;
  if (e < 36864) {                     // Mg[k][o] = sum_j Wf[o][half*96+j]*Wout[j][k%192]
    int k = e / 96, o = e - k * 96;
    int half = (k >= 192) ? 1 : 0;
    int c = k - half * 192;
    const float* wfr = Wf + o * 192 + half * 96;
    float acc = 0.f;
#pragma unroll 4
    for (int j = 0; j < 96; ++j) acc += wfr[j] * Wout[j * 192 + c];
    Mgb[(half * 96 + o) * 192 + c] = f2bf(acc);
  } else if (e < 73728) {
    int i = e - 36864;
    wbi[i] = f2bf(Wii[i]);
  } else if (e < 110592) {
    int i = e - 73728;
    wbt[i] = f2bf(Wit[i]);
  } else if (e < 113664) {             // Wxtb[o][c] bf16, rows 14,15 zero
    int i = e - 110592;
    int o = i / 192;
    Wxtb[i] = (o < 14) ? f2bf(xpw[i]) : (unsigned short)0;
  }
}

// ---------------- in_proj via bf16 MFMA: x half -> bf16 d-major, z half -> bf16 token-major ----------------
__global__ __launch_bounds__(256, 2) void k_inproj(const float* __restrict__ img,
                                                   const float* __restrict__ text,
                                                   const unsigned short* __restrict__ wbi,
                                                   const unsigned short* __restrict__ wbt,
                                                   unsigned short* __restrict__ xsph,
                                                   unsigned short* __restrict__ zbufh) {
  __shared__ __align__(16) unsigned short Xbf[64 * 104];  // [t][k] pad 104
  int bx = blockIdx.x;
  int tile = bx & 63, b = (bx >> 6) & 7, s = bx >> 9;
  int n0 = tile * 64;
  int tid = threadIdx.x;
  int w = tid >> 6, lane = tid & 63;
  const float* src = s ? text : img;
  const unsigned short* wsel = s ? wbt : wbi;

  const unsigned short* wbase = wsel + ((size_t)(w * 96 + (lane & 15))) * 96 + ((lane >> 4) * 8);
  short8_t bfr[18];
#pragma unroll
  for (int nt = 0; nt < 6; ++nt)
#pragma unroll
    for (int ks = 0; ks < 3; ++ks)
      bfr[nt * 3 + ks] = *(const short8_t*)(wbase + nt * 16 * 96 + ks * 32);

  for (int idx = tid; idx < 6144; idx += 256) {
    int c = idx >> 6, t = idx & 63;
    Xbf[t * 104 + c] = f2bf(src[((size_t)b * 96 + c) * 4096 + n0 + t]);
  }
  __syncthreads();

  f32x4 acc[4][6];
  f32x4 zz = {0.f, 0.f, 0.f, 0.f};
#pragma unroll
  for (int mt = 0; mt < 4; ++mt)
#pragma unroll
    for (int nt = 0; nt < 6; ++nt) acc[mt][nt] = zz;

  int arow = lane & 15;
  int acol = (lane >> 4) * 8;
#pragma unroll
  for (int mt = 0; mt < 4; ++mt) {
    const unsigned short* ap = &Xbf[(mt * 16 + arow) * 104 + acol];
    short8_t a0 = *(const short8_t*)(ap);
    short8_t a1 = *(const short8_t*)(ap + 32);
    short8_t a2 = *(const short8_t*)(ap + 64);
#pragma unroll
    for (int nt = 0; nt < 6; ++nt) {
      acc[mt][nt] = __builtin_amdgcn_mfma_f32_16x16x32_bf16(a0, bfr[nt * 3 + 0], acc[mt][nt], 0, 0, 0);
      acc[mt][nt] = __builtin_amdgcn_mfma_f32_16x16x32_bf16(a1, bfr[nt * 3 + 1], acc[mt][nt], 0, 0, 0);
      acc[mt][nt] = __builtin_amdgcn_mfma_f32_16x16x32_bf16(a2, bfr[nt * 3 + 2], acc[mt][nt], 0, 0, 0);
    }
  }

  int rowoff = (lane >> 4) * 4;
  if (w < 2) {   // x half -> d-major bf16 (4 tokens packed as 8B)
#pragma unroll
    for (int nt = 0; nt < 6; ++nt) {
      int d = w * 96 + nt * 16 + (lane & 15);
      unsigned short* xp = xsph + (((size_t)s * 8 + b) * 192 + d) * 4096 + n0 + rowoff;
#pragma unroll
      for (int mt = 0; mt < 4; ++mt) {
        f32x4 a = acc[mt][nt];
        uint2 pk;
        pk.x = (unsigned int)f2bf(a[0]) | ((unsigned int)f2bf(a[1]) << 16);
        pk.y = (unsigned int)f2bf(a[2]) | ((unsigned int)f2bf(a[3]) << 16);
        *(uint2*)&xp[mt * 16] = pk;
      }
    }
  } else {       // z half -> token-major bf16
    size_t tokb = (size_t)b * 8192 + (size_t)s * 4096 + n0;
#pragma unroll
    for (int nt = 0; nt < 6; ++nt) {
      int ch = (w - 2) * 96 + nt * 16 + (lane & 15);
#pragma unroll
      for (int mt = 0; mt < 4; ++mt) {
        f32x4 a = acc[mt][nt];
        unsigned short* zp = zbufh + (tokb + mt * 16 + rowoff) * 192 + ch;
        zp[0] = f2bf(a[0]); zp[192] = f2bf(a[1]); zp[384] = f2bf(a[2]); zp[576] = f2bf(a[3]);
      }
    }
  }
}

// ---------------- depthwise 3x3 conv + BN + SiLU: bf16 in/out ----------------
__global__ __launch_bounds__(256) void k_conv(
    const unsigned short* __restrict__ xsph,
    const float* __restrict__ cwi, const float* __restrict__ cbi,
    const float* __restrict__ bgi, const float* __restrict__ bbi,
    const float* __restrict__ bmi, const float* __restrict__ bvi,
    const float* __restrict__ cwt, const float* __restrict__ cbt,
    const float* __restrict__ bgt, const float* __restrict__ bbt,
    const float* __restrict__ bmt, const float* __restrict__ bvt,
    unsigned short* __restrict__ xdh) {
  int bid = blockIdx.x;
  int img = bid / 96;                 // 0..15
  int d0 = (bid - img * 96) * 2;
  int widx = threadIdx.x >> 6;
  int lane = threadIdx.x & 63;
  int d = d0 + (widx >> 1);
  int half = widx & 1;
  int s = img >> 3;
  const float* cw = s ? cwt : cwi;
  const float* cb = s ? cbt : cbi;
  const float* bg = s ? bgt : bgi;
  const float* bb2 = s ? bbt : bbi;
  const float* bm = s ? bmt : bmi;
  const float* bv = s ? bvt : bvi;
  const unsigned short* src = xsph + ((size_t)img * 192 + d) * 4096;
  unsigned short* dst = xdh + ((size_t)img * 192 + d) * 4096;
  float c0 = cw[d * 9 + 0], c1 = cw[d * 9 + 1], c2 = cw[d * 9 + 2];
  float c3 = cw[d * 9 + 3], c4 = cw[d * 9 + 4], c5 = cw[d * 9 + 5];
  float c6 = cw[d * 9 + 6], c7 = cw[d * 9 + 7], c8 = cw[d * 9 + 8];
  float sc = bg[d] * rsqrtf(bv[d] + EPSV);
  float eb = (cb[d] - bm[d]) * sc + bb2[d];
  int h0 = half * 32;
  float pc = (h0 > 0) ? bf2f(src[(h0 - 1) * 64 + lane]) : 0.f;
  float cc = bf2f(src[h0 * 64 + lane]);
  float nc = bf2f(src[(h0 + 1) * 64 + lane]);
  float t;
  t = __shfl_up(pc, 1);  float pl = (lane == 0) ? 0.f : t;
  t = __shfl_down(pc, 1); float pr = (lane == 63) ? 0.f : t;
  t = __shfl_up(cc, 1);  float cl = (lane == 0) ? 0.f : t;
  t = __shfl_down(cc, 1); float cr = (lane == 63) ? 0.f : t;
#pragma unroll 4
  for (int i = 0; i < 32; ++i) {
    int h = h0 + i;
    float fut = (h + 2 <= 63) ? bf2f(src[(h + 2) * 64 + lane]) : 0.f;
    t = __shfl_up(nc, 1);  float nl = (lane == 0) ? 0.f : t;
    t = __shfl_down(nc, 1); float nr = (lane == 63) ? 0.f : t;
    float a = pl * c0 + pc * c1 + pr * c2
            + cl * c3 + cc * c4 + cr * c5
            + nl * c6 + nc * c7 + nr * c8;
    a = a * sc + eb;
    dst[h * 64 + lane] = f2bf(a / (1.f + __expf(-a)));
    pl = cl; pc = cc; pr = cr;
    cl = nl; cc = nc; cr = nr;
    nc = fut;
  }
}

// ---------------- scan pass A: MFMA x_proj + chunk scan ----------------
__global__ __launch_bounds__(192) void k_scanA(const unsigned short* __restrict__ xdh,
                                               const unsigned short* __restrict__ Wxtb,
                                               const float* __restrict__ dtw,
                                               const float* __restrict__ dtbias,
                                               const float* __restrict__ Alog,
                                               float* __restrict__ dtBC,
                                               float* __restrict__ hend,
                                               float* __restrict__ Pbuf) {
  __shared__ __align__(16) unsigned short Xt[64 * 200];  // [t][k] pad 200
  __shared__ __align__(16) float SBC[64 * 16];
  int c = blockIdx.x & 127, b = blockIdx.x >> 7;
  int s = c >> 6, cl = c & 63;
  int d = threadIdx.x;
  int w = d >> 6, lane = d & 63;
  int tokbase = b * 8192 + c * 64;

  // x row -> registers
  const unsigned short* xrow = xdh + (((size_t)s * 8 + b) * 192 + d) * 4096 + cl * 64;
  short8_t xr8[8];
#pragma unroll
  for (int i = 0; i < 8; ++i) xr8[i] = *(const short8_t*)(xrow + i * 8);
  // transpose -> LDS [t][k]
#pragma unroll
  for (int i = 0; i < 8; ++i)
#pragma unroll
    for (int j = 0; j < 8; ++j)
      Xt[(i * 8 + j) * 200 + d] = (unsigned short)xr8[i][j];

  // B-fragments for x_proj (16 outs, rows 14/15 zero)
  const unsigned short* wb = Wxtb + (size_t)(lane & 15) * 192 + ((lane >> 4) * 8);
  short8_t bfx[6];
#pragma unroll
  for (int ks = 0; ks < 6; ++ks) bfx[ks] = *(const short8_t*)(wb + ks * 32);

  float w0 = dtw[d * 6 + 0], w1 = dtw[d * 6 + 1], w2 = dtw[d * 6 + 2];
  float w3 = dtw[d * 6 + 3], w4 = dtw[d * 6 + 4], w5 = dtw[d * 6 + 5];
  float bb = dtbias[d];
  float4 al = *(const float4*)&Alog[d * 4];
  float A0 = -__expf(al.x), A1 = -__expf(al.y), A2 = -__expf(al.z), A3 = -__expf(al.w);
  __syncthreads();

  // ---- x_proj MFMA: wave w -> m-tile w; wave 0 also m-tile 3 ----
  int arow = lane & 15, acol = (lane >> 4) * 8;
#pragma unroll
  for (int q = 0; q < 2; ++q) {
    if (q == 1 && w != 0) break;
    int mt = (q == 0) ? w : 3;
    f32x4 a4 = {0.f, 0.f, 0.f, 0.f};
#pragma unroll
    for (int ks = 0; ks < 6; ++ks) {
      short8_t a = *(const short8_t*)&Xt[(mt * 16 + arow) * 200 + acol + ks * 32];
      a4 = __builtin_amdgcn_mfma_f32_16x16x32_bf16(a, bfx[ks], a4, 0, 0, 0);
    }
    int tt = mt * 16 + (lane >> 4) * 4, o = lane & 15;
#pragma unroll
    for (int r = 0; r < 4; ++r) {
      SBC[(tt + r) * 16 + o] = a4[r];
      dtBC[(size_t)(tokbase + tt + r) * 16 + o] = a4[r];
    }
  }
  __syncthreads();

  // ---- chunk scan from zero state ----
  bool fastp = fabsf(A0 + 1.f) < 1e-4f && fabsf(A1 + 2.f) < 2e-4f &&
               fabsf(A2 + 3.f) < 3e-4f && fabsf(A3 + 4.f) < 4e-4f;
  float h0 = 0.f, h1 = 0.f, h2 = 0.f, h3 = 0.f, sd = 0.f;
  if (fastp) {
#pragma unroll
    for (int i = 0; i < 8; ++i)
#pragma unroll
      for (int j = 0; j < 8; ++j) {
        int l2 = i * 8 + j;
        float4 s0 = *(const float4*)&SBC[l2 * 16 + 0];
        float4 s1 = *(const float4*)&SBC[l2 * 16 + 4];
        float4 s2 = *(const float4*)&SBC[l2 * 16 + 8];
        float pre = bb + w0 * s0.x + w1 * s0.y + w2 * s0.z + w3 * s0.w + w4 * s1.x + w5 * s1.y;
        float ex = __expf(pre);
        float opx = 1.f + ex;
        float e1 = __builtin_amdgcn_rcpf(opx);          // exp(-delta) exactly
        float delta = (pre > 15.f) ? pre : __logf(opx);
        sd += delta;
        float e2 = e1 * e1, e3 = e2 * e1, e4 = e2 * e2;
        float dx = delta * bf2f((unsigned short)xr8[i][j]);
        h0 = e1 * h0 + dx * s1.z;
        h1 = e2 * h1 + dx * s1.w;
        h2 = e3 * h2 + dx * s2.x;
        h3 = e4 * h3 + dx * s2.y;
      }
  } else {
#pragma unroll
    for (int i = 0; i < 8; ++i)
#pragma unroll
      for (int j = 0; j < 8; ++j) {
        int l2 = i * 8 + j;
        float4 s0 = *(const float4*)&SBC[l2 * 16 + 0];
        float4 s1 = *(const float4*)&SBC[l2 * 16 + 4];
        float4 s2 = *(const float4*)&SBC[l2 * 16 + 8];
        float pre = bb + w0 * s0.x + w1 * s0.y + w2 * s0.z + w3 * s0.w + w4 * s1.x + w5 * s1.y;
        float ex = __expf(pre);
        float delta = (pre > 15.f) ? pre : __logf(1.f + ex);
        sd += delta;
        float dx = delta * bf2f((unsigned short)xr8[i][j]);
        h0 = __expf(delta * A0) * h0 + dx * s1.z;
        h1 = __expf(delta * A1) * h1 + dx * s1.w;
        h2 = __expf(delta * A2) * h2 + dx * s2.x;
        h3 = __expf(delta * A3) * h3 + dx * s2.y;
      }
  }
  size_t o = (((size_t)b * 128 + c) * 192 + d) * 4;
  *(float4*)&hend[o] = make_float4(h0, h1, h2, h3);
  if (fastp) {
    float p1 = __expf(-sd);
    float p2 = p1 * p1;
    *(float4*)&Pbuf[o] = make_float4(p1, p2, p2 * p1, p2 * p2);
  } else {
    *(float4*)&Pbuf[o] = make_float4(__expf(A0 * sd), __expf(A1 * sd), __expf(A2 * sd), __expf(A3 * sd));
  }
}

// ---------------- scan pass 2: cross-chunk combine (128 chunks) ----------------
__global__ __launch_bounds__(256) void k_scan2(const float* __restrict__ hend,
                                               const float* __restrict__ Pbuf,
                                               float* __restrict__ hinit) {
  int e = blockIdx.x * 256 + threadIdx.x;
  if (e >= 8 * 768) return;
  int b = e / 768, r = e - b * 768;
  float h = 0.f;
#pragma unroll 4
  for (int c = 0; c < 128; ++c) {
    int a = (b * 128 + c) * 768 + r;
    hinit[a] = h;
    h = Pbuf[a] * h + hend[a];
  }
}

// ---------------- scan pass B: replay with h_init, write y bf16 token-major ----------------
__global__ __launch_bounds__(192) void k_scanB(const unsigned short* __restrict__ xdh,
                                               const float* __restrict__ dtBC,
                                               const float* __restrict__ dtw,
                                               const float* __restrict__ dtbias,
                                               const float* __restrict__ Alog,
                                               const float* __restrict__ Dskip,
                                               const float* __restrict__ hinit,
                                               unsigned short* __restrict__ ybufh) {
  __shared__ __align__(16) float SBC[64 * 16];
  int c = blockIdx.x & 127, b = blockIdx.x >> 7;
  int s = c >> 6, cl = c & 63;
  int d = threadIdx.x;
  float w0 = dtw[d * 6 + 0], w1 = dtw[d * 6 + 1], w2 = dtw[d * 6 + 2];
  float w3 = dtw[d * 6 + 3], w4 = dtw[d * 6 + 4], w5 = dtw[d * 6 + 5];
  float bb = dtbias[d];
  float4 al = *(const float4*)&Alog[d * 4];
  float A0 = -__expf(al.x), A1 = -__expf(al.y), A2 = -__expf(al.z), A3 = -__expf(al.w);
  float Dv = Dskip[d];
  int tokbase = b * 8192 + c * 64;
  for (int idx = d; idx < 1024; idx += 192) SBC[idx] = dtBC[(size_t)tokbase * 16 + idx];
  const unsigned short* xrow = xdh + (((size_t)s * 8 + b) * 192 + d) * 4096 + cl * 64;
  short8_t xr8[8];
#pragma unroll
  for (int i = 0; i < 8; ++i) xr8[i] = *(const short8_t*)(xrow + i * 8);
  size_t o = (((size_t)b * 128 + c) * 192 + d) * 4;
  float4 hv = *(const float4*)&hinit[o];
  float h0 = hv.x, h1 = hv.y, h2 = hv.z, h3 = hv.w;
  bool fastp = fabsf(A0 + 1.f) < 1e-4f && fabsf(A1 + 2.f) < 2e-4f &&
               fabsf(A2 + 3.f) < 3e-4f && fabsf(A3 + 4.f) < 4e-4f;
  __syncthreads();
  unsigned short* yout = ybufh + (size_t)tokbase * 192 + d;
  if (fastp) {
#pragma unroll
    for (int i = 0; i < 8; ++i)
#pragma unroll
      for (int j = 0; j < 8; ++j) {
        int l2 = i * 8 + j;
        float4 s0 = *(const float4*)&SBC[l2 * 16 + 0];
        float4 s1 = *(const float4*)&SBC[l2 * 16 + 4];
        float4 s2 = *(const float4*)&SBC[l2 * 16 + 8];
        float4 s3 = *(const float4*)&SBC[l2 * 16 + 12];
        float pre = bb + w0 * s0.x + w1 * s0.y + w2 * s0.z + w3 * s0.w + w4 * s1.x + w5 * s1.y;
        float ex = __expf(pre);
        float opx = 1.f + ex;
        float e1 = __builtin_amdgcn_rcpf(opx);
        float delta = (pre > 15.f) ? pre : __logf(opx);
        float e2 = e1 * e1, e3 = e2 * e1, e4 = e2 * e2;
        float xv = bf2f((unsigned short)xr8[i][j]);
        float dx = delta * xv;
        h0 = e1 * h0 + dx * s1.z;
        h1 = e2 * h1 + dx * s1.w;
        h2 = e3 * h2 + dx * s2.x;
        h3 = e4 * h3 + dx * s2.y;
        yout[(size_t)l2 * 192] = f2bf(h0 * s2.z + h1 * s2.w + h2 * s3.x + h3 * s3.y + Dv * xv);
      }
  } else {
#pragma unroll
    for (int i = 0; i < 8; ++i)
#pragma unroll
      for (int j = 0; j < 8; ++j) {
        int l2 = i * 8 + j;
        float4 s0 = *(const float4*)&SBC[l2 * 16 + 0];
        float4 s1 = *(const float4*)&SBC[l2 * 16 + 4];
        float4 s2 = *(const float4*)&SBC[l2 * 16 + 8];
        float4 s3 = *(const float4*)&SBC[l2 * 16 + 12];
        float pre = bb + w0 * s0.x + w1 * s0.y + w2 * s0.z + w3 * s0.w + w4 * s1.x + w5 * s1.y;
        float ex = __expf(pre);
        float delta = (pre > 15.f) ? pre : __logf(1.f + ex);
        float xv = bf2f((unsigned short)xr8[i][j]);
        float dx = delta * xv;
        h0 = __expf(delta * A0) * h0 + dx * s1.z;
        h1 = __expf(delta * A1) * h1 + dx * s1.w;
        h2 = __expf(delta * A2) * h2 + dx * s2.x;
        h3 = __expf(delta * A3) * h3 + dx * s2.y;
        yout[(size_t)l2 * 192] = f2bf(h0 * s2.z + h1 * s2.w + h2 * s3.x + h3 * s3.y + Dv * xv);
      }
  }
}

// ---------------- fused LayerNorm + z-gate + out-proj + stream-fusion (bf16 MFMA) ----------------
__global__ __launch_bounds__(384) void k_outfuse(const unsigned short* __restrict__ ybufh,
                                                 const unsigned short* __restrict__ zbufh,
                                                 const float* __restrict__ lng,
                                                 const float* __restrict__ lnb,
                                                 const unsigned short* __restrict__ Mgb,
                                                 float* __restrict__ out) {
  __shared__ __align__(16) unsigned short Xbf[64 * 200];  // [t][k] pad 200
  int tile = blockIdx.x & 63, b = blockIdx.x >> 6;
  int n0 = tile * 64;
  int tid = threadIdx.x;
  int w = tid >> 6, lane = tid & 63;
  float lg0 = lng[lane], lg1 = lng[lane + 64], lg2 = lng[lane + 128];
  float lb0 = lnb[lane], lb1 = lnb[lane + 64], lb2 = lnb[lane + 128];

  const unsigned short* bb = Mgb + ((size_t)(w * 16 + (lane & 15))) * 192 + ((lane >> 4) * 8);
  short8_t bfr[2][6];
#pragma unroll
  for (int kc = 0; kc < 2; ++kc)
#pragma unroll
    for (int ks = 0; ks < 6; ++ks)
      bfr[kc][ks] = *(const short8_t*)(bb + kc * 96 * 192 + ks * 32);

  f32x4 acc[4];
  f32x4 zz = {0.f, 0.f, 0.f, 0.f};
#pragma unroll
  for (int mt = 0; mt < 4; ++mt) acc[mt] = zz;

  int arow = lane & 15, acol = (lane >> 4) * 8;
  for (int kc = 0; kc < 2; ++kc) {
    size_t tokb = (size_t)b * 8192 + (size_t)kc * 4096 + n0;
    if (kc) __syncthreads();
    for (int t = w; t < 64; t += 6) {
      const unsigned short* yr = ybufh + (tokb + t) * 192;
      const unsigned short* zr = zbufh + (tokb + t) * 192;
      float y0 = bf2f(yr[lane]), y1 = bf2f(yr[lane + 64]), y2 = bf2f(yr[lane + 128]);
      float z0 = bf2f(zr[lane]), z1 = bf2f(zr[lane + 64]), z2 = bf2f(zr[lane + 128]);
      float sm = y0 + y1 + y2;
      float sq = y0 * y0 + y1 * y1 + y2 * y2;
#pragma unroll
      for (int off = 32; off; off >>= 1) {
        sm += __shfl_xor(sm, off);
        sq += __shfl_xor(sq, off);
      }
      float mu = sm * (1.f / 192.f);
      float var = sq * (1.f / 192.f) - mu * mu;
      float rstd = rsqrtf(var + EPSV);
      Xbf[t * 200 + lane]       = f2bf(((y0 - mu) * rstd * lg0 + lb0) * siluf(z0));
      Xbf[t * 200 + lane + 64]  = f2bf(((y1 - mu) * rstd * lg1 + lb1) * siluf(z1));
      Xbf[t * 200 + lane + 128] = f2bf(((y2 - mu) * rstd * lg2 + lb2) * siluf(z2));
    }
    __syncthreads();
#pragma unroll
    for (int mt = 0; mt < 4; ++mt) {
      const unsigned short* ap = &Xbf[(mt * 16 + arow) * 200 + acol];
#pragma unroll
      for (int ks = 0; ks < 6; ++ks) {
        short8_t a = *(const short8_t*)(ap + ks * 32);
        acc[mt] = __builtin_amdgcn_mfma_f32_16x16x32_bf16(a, bfr[kc][ks], acc[mt], 0, 0, 0);
      }
    }
  }
  int rowoff = (lane >> 4) * 4;
  float* op = out + ((size_t)b * 96 + w * 16 + (lane & 15)) * 4096 + n0 + rowoff;
#pragma unroll
  for (int mt = 0; mt < 4; ++mt) {
    f32x4 a = acc[mt];
    *(float4*)&op[mt * 16] = make_float4(a[0], a[1], a[2], a[3]);
  }
}

extern "C" void kernel_launch(void* const* d_in, const int* in_sizes, int n_in,
                              void* d_out, int out_size, void* d_ws, size_t ws_size,
                              hipStream_t stream) {
  (void)in_sizes; (void)n_in; (void)out_size; (void)ws_size;
  const float* img  = (const float*)d_in[0];
  const float* text = (const float*)d_in[1];
  const float* Wii  = (const float*)d_in[2];
  const float* Wit  = (const float*)d_in[3];
  const float* cwi  = (const float*)d_in[4];
  const float* cbi  = (const float*)d_in[5];
  const float* bgi  = (const float*)d_in[6];
  const float* bbi  = (const float*)d_in[7];
  const float* bmi  = (const float*)d_in[8];
  const float* bvi  = (const float*)d_in[9];
  const float* cwt  = (const float*)d_in[10];
  const float* cbt  = (const float*)d_in[11];
  const float* bgt  = (const float*)d_in[12];
  const float* bbt  = (const float*)d_in[13];
  const float* bmt  = (const float*)d_in[14];
  const float* bvt  = (const float*)d_in[15];
  const float* xpw  = (const float*)d_in[16];
  const float* dtw  = (const float*)d_in[17];
  const float* dtb  = (const float*)d_in[18];
  const float* Alog = (const float*)d_in[19];
  const float* Dsk  = (const float*)d_in[20];
  const float* lng  = (const float*)d_in[21];
  const float* lnb  = (const float*)d_in[22];
  const float* Wout = (const float*)d_in[23];
  const float* Wfus = (const float*)d_in[24];

  float* ws    = (float*)d_ws;
  unsigned short* xsph  = (unsigned short*)ws;
  unsigned short* zbufh = (unsigned short*)(ws + N_XSP);
  unsigned short* xdh   = (unsigned short*)(ws + N_XSP + N_ZBUF);
  float* dtBC  = ws + N_XSP + N_ZBUF + N_XD;
  float* hend  = dtBC + N_DTBC;
  float* Pbuf  = hend + N_STATE;
  float* hinit = Pbuf + N_STATE;
  unsigned short* Mgb  = (unsigned short*)(hinit + N_STATE);
  unsigned short* Wxtb = Mgb + 36864;
  unsigned short* wbi  = Wxtb + 3072;
  unsigned short* wbt  = wbi + 36864;
  unsigned short* ybufh = xsph;  // xsph dead after k_conv
  float* out   = (float*)d_out;

  hipLaunchKernelGGL(k_prep, dim3(444), dim3(256), 0, stream, Wout, Wfus, Wii, Wit, xpw, Mgb, wbi, wbt, Wxtb);
  hipLaunchKernelGGL(k_inproj, dim3(1024), dim3(256), 0, stream, img, text, wbi, wbt, xsph, zbufh);
  hipLaunchKernelGGL(k_conv, dim3(1536), dim3(256), 0, stream, xsph,
                     cwi, cbi, bgi, bbi, bmi, bvi, cwt, cbt, bgt, bbt, bmt, bvt, xdh);
  hipLaunchKernelGGL(k_scanA, dim3(1024), dim3(192), 0, stream, xdh, Wxtb, dtw, dtb, Alog, dtBC, hend, Pbuf);
  hipLaunchKernelGGL(k_scan2, dim3(24), dim3(256), 0, stream, hend, Pbuf, hinit);
  hipLaunchKernelGGL(k_scanB, dim3(1024), dim3(192), 0, stream, xdh, dtBC, dtw, dtb, Alog, Dsk, hinit, ybufh);
  hipLaunchKernelGGL(k_outfuse, dim3(512), dim3(384), 0, stream, ybufh, zbufh, lng, lnb, Mgb, out);
}

// Round 10
// 146.987 us; speedup vs baseline: 3.5730x; 1.0036x over previous
//
#include <hip/hip_runtime.h>
#include <hip/hip_cooperative_groups.h>
#include <math.h>

namespace cg = cooperative_groups;

#define EPSV 1e-5f

typedef __attribute__((ext_vector_type(8))) short short8_t;   // 8 bf16 (4 VGPRs)
typedef __attribute__((ext_vector_type(4))) float f32x4;      // MFMA acc

// ---------------- workspace layout ----------------
// xsp slot : bf16 x-branch (2,8,192,4096) d-major (conv in) | reused as bf16 ybuf
// zbuf slot: bf16 z (8,8192,192) token-major
// xd  slot : bf16 conv output (2,8,192,4096) d-major
// dtBC : (65536,16) fp32 (fallback path only); hend/Pbuf/hinit : (8,128,192,4)
// Mgb: bf16 [2*96][192]; Wxtb: bf16 [16][192]; wbi/wbt: bf16 W_in [384][96]
#define N_XSP   12582912
#define N_ZBUF  12582912
#define N_XD    12582912
#define N_DTBC  1048576
#define N_STATE 786432

__device__ __forceinline__ float siluf(float v) {
  return v / (1.f + __expf(-v));
}

__device__ __forceinline__ unsigned short f2bf(float f) {  // RTNE fp32->bf16
  unsigned int u = __float_as_uint(f);
  u += 0x7fffu + ((u >> 16) & 1u);
  return (unsigned short)(u >> 16);
}

__device__ __forceinline__ float bf2f(unsigned short h) {
  return __uint_as_float(((unsigned int)h) << 16);
}

// ---------------- prep: Mg(bf16) + bf16 W_in + bf16 x_proj ----------------
__global__ __launch_bounds__(256) void k_prep(const float* __restrict__ Wout,
                                              const float* __restrict__ Wf,
                                              const float* __restrict__ Wii,
                                              const float* __restrict__ Wit,
                                              const float* __restrict__ xpw,
                                              unsigned short* __restrict__ Mgb,
                                              unsigned short* __restrict__ wbi,
                                              unsigned short* __restrict__ wbt,
                                              unsigned short* __restrict__ Wxtb) {
  int e = blockIdx.x * 256 + threadIdx.x;
  if (e < 36864) {                     // Mg[k][o] = sum_j Wf[o][half*96+j]*Wout[j][k%192]
    int k = e / 96, o = e - k * 96;
    int half = (k >= 192) ? 1 : 0;
    int c = k - half * 192;
    const float* wfr = Wf + o * 192 + half * 96;
    float acc = 0.f;
#pragma unroll 4
    for (int j = 0; j < 96; ++j) acc += wfr[j] * Wout[j * 192 + c];
    Mgb[(half * 96 + o) * 192 + c] = f2bf(acc);
  } else if (e < 73728) {
    int i = e - 36864;
    wbi[i] = f2bf(Wii[i]);
  } else if (e < 110592) {
    int i = e - 73728;
    wbt[i] = f2bf(Wit[i]);
  } else if (e < 113664) {             // Wxtb[o][c] bf16, rows 14,15 zero
    int i = e - 110592;
    int o = i / 192;
    Wxtb[i] = (o < 14) ? f2bf(xpw[i]) : (unsigned short)0;
  }
}

// ---------------- in_proj via bf16 MFMA ----------------
__global__ __launch_bounds__(256, 2) void k_inproj(const float* __restrict__ img,
                                                   const float* __restrict__ text,
                                                   const unsigned short* __restrict__ wbi,
                                                   const unsigned short* __restrict__ wbt,
                                                   unsigned short* __restrict__ xsph,
                                                   unsigned short* __restrict__ zbufh) {
  __shared__ __align__(16) unsigned short Xbf[64 * 104];  // [t][k] pad 104
  int bx = blockIdx.x;
  int tile = bx & 63, b = (bx >> 6) & 7, s = bx >> 9;
  int n0 = tile * 64;
  int tid = threadIdx.x;
  int w = tid >> 6, lane = tid & 63;
  const float* src = s ? text : img;
  const unsigned short* wsel = s ? wbt : wbi;

  const unsigned short* wbase = wsel + ((size_t)(w * 96 + (lane & 15))) * 96 + ((lane >> 4) * 8);
  short8_t bfr[18];
#pragma unroll
  for (int nt = 0; nt < 6; ++nt)
#pragma unroll
    for (int ks = 0; ks < 3; ++ks)
      bfr[nt * 3 + ks] = *(const short8_t*)(wbase + nt * 16 * 96 + ks * 32);

  for (int idx = tid; idx < 6144; idx += 256) {
    int c = idx >> 6, t = idx & 63;
    Xbf[t * 104 + c] = f2bf(src[((size_t)b * 96 + c) * 4096 + n0 + t]);
  }
  __syncthreads();

  f32x4 acc[4][6];
  f32x4 zz = {0.f, 0.f, 0.f, 0.f};
#pragma unroll
  for (int mt = 0; mt < 4; ++mt)
#pragma unroll
    for (int nt = 0; nt < 6; ++nt) acc[mt][nt] = zz;

  int arow = lane & 15;
  int acol = (lane >> 4) * 8;
#pragma unroll
  for (int mt = 0; mt < 4; ++mt) {
    const unsigned short* ap = &Xbf[(mt * 16 + arow) * 104 + acol];
    short8_t a0 = *(const short8_t*)(ap);
    short8_t a1 = *(const short8_t*)(ap + 32);
    short8_t a2 = *(const short8_t*)(ap + 64);
#pragma unroll
    for (int nt = 0; nt < 6; ++nt) {
      acc[mt][nt] = __builtin_amdgcn_mfma_f32_16x16x32_bf16(a0, bfr[nt * 3 + 0], acc[mt][nt], 0, 0, 0);
      acc[mt][nt] = __builtin_amdgcn_mfma_f32_16x16x32_bf16(a1, bfr[nt * 3 + 1], acc[mt][nt], 0, 0, 0);
      acc[mt][nt] = __builtin_amdgcn_mfma_f32_16x16x32_bf16(a2, bfr[nt * 3 + 2], acc[mt][nt], 0, 0, 0);
    }
  }

  int rowoff = (lane >> 4) * 4;
  if (w < 2) {   // x half -> d-major bf16
#pragma unroll
    for (int nt = 0; nt < 6; ++nt) {
      int d = w * 96 + nt * 16 + (lane & 15);
      unsigned short* xp = xsph + (((size_t)s * 8 + b) * 192 + d) * 4096 + n0 + rowoff;
#pragma unroll
      for (int mt = 0; mt < 4; ++mt) {
        f32x4 a = acc[mt][nt];
        uint2 pk;
        pk.x = (unsigned int)f2bf(a[0]) | ((unsigned int)f2bf(a[1]) << 16);
        pk.y = (unsigned int)f2bf(a[2]) | ((unsigned int)f2bf(a[3]) << 16);
        *(uint2*)&xp[mt * 16] = pk;
      }
    }
  } else {       // z half -> token-major bf16
    size_t tokb = (size_t)b * 8192 + (size_t)s * 4096 + n0;
#pragma unroll
    for (int nt = 0; nt < 6; ++nt) {
      int ch = (w - 2) * 96 + nt * 16 + (lane & 15);
#pragma unroll
      for (int mt = 0; mt < 4; ++mt) {
        f32x4 a = acc[mt][nt];
        unsigned short* zp = zbufh + (tokb + mt * 16 + rowoff) * 192 + ch;
        zp[0] = f2bf(a[0]); zp[192] = f2bf(a[1]); zp[384] = f2bf(a[2]); zp[576] = f2bf(a[3]);
      }
    }
  }
}

// ---------------- depthwise 3x3 conv + BN + SiLU: bf16 in/out ----------------
__global__ __launch_bounds__(256) void k_conv(
    const unsigned short* __restrict__ xsph,
    const float* __restrict__ cwi, const float* __restrict__ cbi,
    const float* __restrict__ bgi, const float* __restrict__ bbi,
    const float* __restrict__ bmi, const float* __restrict__ bvi,
    const float* __restrict__ cwt, const float* __restrict__ cbt,
    const float* __restrict__ bgt, const float* __restrict__ bbt,
    const float* __restrict__ bmt, const float* __restrict__ bvt,
    unsigned short* __restrict__ xdh) {
  int bid = blockIdx.x;
  int img = bid / 96;                 // 0..15
  int d0 = (bid - img * 96) * 2;
  int widx = threadIdx.x >> 6;
  int lane = threadIdx.x & 63;
  int d = d0 + (widx >> 1);
  int half = widx & 1;
  int s = img >> 3;
  const float* cw = s ? cwt : cwi;
  const float* cb = s ? cbt : cbi;
  const float* bg = s ? bgt : bgi;
  const float* bb2 = s ? bbt : bbi;
  const float* bm = s ? bmt : bmi;
  const float* bv = s ? bvt : bvi;
  const unsigned short* src = xsph + ((size_t)img * 192 + d) * 4096;
  unsigned short* dst = xdh + ((size_t)img * 192 + d) * 4096;
  float c0 = cw[d * 9 + 0], c1 = cw[d * 9 + 1], c2 = cw[d * 9 + 2];
  float c3 = cw[d * 9 + 3], c4 = cw[d * 9 + 4], c5 = cw[d * 9 + 5];
  float c6 = cw[d * 9 + 6], c7 = cw[d * 9 + 7], c8 = cw[d * 9 + 8];
  float sc = bg[d] * rsqrtf(bv[d] + EPSV);
  float eb = (cb[d] - bm[d]) * sc + bb2[d];
  int h0 = half * 32;
  float pc = (h0 > 0) ? bf2f(src[(h0 - 1) * 64 + lane]) : 0.f;
  float cc = bf2f(src[h0 * 64 + lane]);
  float nc = bf2f(src[(h0 + 1) * 64 + lane]);
  float t;
  t = __shfl_up(pc, 1);  float pl = (lane == 0) ? 0.f : t;
  t = __shfl_down(pc, 1); float pr = (lane == 63) ? 0.f : t;
  t = __shfl_up(cc, 1);  float cl = (lane == 0) ? 0.f : t;
  t = __shfl_down(cc, 1); float cr = (lane == 63) ? 0.f : t;
#pragma unroll 4
  for (int i = 0; i < 32; ++i) {
    int h = h0 + i;
    float fut = (h + 2 <= 63) ? bf2f(src[(h + 2) * 64 + lane]) : 0.f;
    t = __shfl_up(nc, 1);  float nl = (lane == 0) ? 0.f : t;
    t = __shfl_down(nc, 1); float nr = (lane == 63) ? 0.f : t;
    float a = pl * c0 + pc * c1 + pr * c2
            + cl * c3 + cc * c4 + cr * c5
            + nl * c6 + nc * c7 + nr * c8;
    a = a * sc + eb;
    dst[h * 64 + lane] = f2bf(a / (1.f + __expf(-a)));
    pl = cl; pc = cc; pr = cr;
    cl = nl; cc = nc; cr = nr;
    nc = fut;
  }
}

// ================= FUSED COOPERATIVE SCAN (preferred path) =================
// 512 blocks x 192 thr; block -> (b, chunk-pair). Needs only 2 blocks/CU co-resident.
__global__ __launch_bounds__(192, 3) void k_scanfused2(
    const unsigned short* __restrict__ xdh,
    const unsigned short* __restrict__ Wxtb,
    const float* __restrict__ dtw,
    const float* __restrict__ dtbias,
    const float* __restrict__ Alog,
    const float* __restrict__ Dskip,
    float* __restrict__ hend,
    float* __restrict__ Pbuf,
    float* __restrict__ hinit,
    unsigned short* __restrict__ ybufh) {
  cg::grid_group grid = cg::this_grid();
  __shared__ __align__(16) unsigned short Xt[64 * 200];   // staging, reused per sub-chunk
  __shared__ __align__(16) float SBC2[2][64 * 16];        // dt/B/C per sub-chunk (persists to P3)
  int bid = blockIdx.x;
  int cp = bid & 63, b = bid >> 6;
  int d = threadIdx.x;
  int w = d >> 6, lane = d & 63;

  const unsigned short* wb = Wxtb + (size_t)(lane & 15) * 192 + ((lane >> 4) * 8);
  short8_t bfx[6];
#pragma unroll
  for (int ks = 0; ks < 6; ++ks) bfx[ks] = *(const short8_t*)(wb + ks * 32);

  float w0 = dtw[d * 6 + 0], w1 = dtw[d * 6 + 1], w2 = dtw[d * 6 + 2];
  float w3 = dtw[d * 6 + 3], w4 = dtw[d * 6 + 4], w5 = dtw[d * 6 + 5];
  float bb = dtbias[d];
  float4 al = *(const float4*)&Alog[d * 4];
  float A0 = -__expf(al.x), A1 = -__expf(al.y), A2 = -__expf(al.z), A3 = -__expf(al.w);
  float Dv = Dskip[d];
  bool fastp = fabsf(A0 + 1.f) < 1e-4f && fabsf(A1 + 2.f) < 2e-4f &&
               fabsf(A2 + 3.f) < 3e-4f && fabsf(A3 + 4.f) < 4e-4f;
  int arow = lane & 15, acol = (lane >> 4) * 8;

  // ---- P0+P1: per sub-chunk x_proj MFMA + chunk scan from zero ----
  for (int sub = 0; sub < 2; ++sub) {
    int c = cp * 2 + sub;
    int s = c >> 6, cl = c & 63;
    const unsigned short* xrow = xdh + (((size_t)s * 8 + b) * 192 + d) * 4096 + cl * 64;
    short8_t xr8[8];
#pragma unroll
    for (int i = 0; i < 8; ++i) xr8[i] = *(const short8_t*)(xrow + i * 8);
    __syncthreads();   // previous sub's MFMA reads of Xt complete
#pragma unroll
    for (int i = 0; i < 8; ++i)
#pragma unroll
      for (int j = 0; j < 8; ++j)
        Xt[(i * 8 + j) * 200 + d] = (unsigned short)xr8[i][j];
    __syncthreads();
    float* SBC = &SBC2[sub][0];
#pragma unroll
    for (int q = 0; q < 2; ++q) {
      if (q == 1 && w != 0) break;
      int mt = (q == 0) ? w : 3;
      f32x4 a4 = {0.f, 0.f, 0.f, 0.f};
#pragma unroll
      for (int ks = 0; ks < 6; ++ks) {
        short8_t a = *(const short8_t*)&Xt[(mt * 16 + arow) * 200 + acol + ks * 32];
        a4 = __builtin_amdgcn_mfma_f32_16x16x32_bf16(a, bfx[ks], a4, 0, 0, 0);
      }
      int tt = mt * 16 + (lane >> 4) * 4, o = lane & 15;
#pragma unroll
      for (int r = 0; r < 4; ++r)
        SBC[(tt + r) * 16 + o] = a4[r];
    }
    __syncthreads();

    float h0 = 0.f, h1 = 0.f, h2 = 0.f, h3 = 0.f, sd = 0.f;
    if (fastp) {
#pragma unroll
      for (int i = 0; i < 8; ++i)
#pragma unroll
        for (int j = 0; j < 8; ++j) {
          int l2 = i * 8 + j;
          float4 s0 = *(const float4*)&SBC[l2 * 16 + 0];
          float4 s1 = *(const float4*)&SBC[l2 * 16 + 4];
          float4 s2 = *(const float4*)&SBC[l2 * 16 + 8];
          float pre = bb + w0 * s0.x + w1 * s0.y + w2 * s0.z + w3 * s0.w + w4 * s1.x + w5 * s1.y;
          float ex = __expf(pre);
          float opx = 1.f + ex;
          float e1 = __builtin_amdgcn_rcpf(opx);
          float delta = (pre > 15.f) ? pre : __logf(opx);
          sd += delta;
          float e2 = e1 * e1, e3 = e2 * e1, e4 = e2 * e2;
          float dx = delta * bf2f((unsigned short)xr8[i][j]);
          h0 = e1 * h0 + dx * s1.z;
          h1 = e2 * h1 + dx * s1.w;
          h2 = e3 * h2 + dx * s2.x;
          h3 = e4 * h3 + dx * s2.y;
        }
    } else {
#pragma unroll
      for (int i = 0; i < 8; ++i)
#pragma unroll
        for (int j = 0; j < 8; ++j) {
          int l2 = i * 8 + j;
          float4 s0 = *(const float4*)&SBC[l2 * 16 + 0];
          float4 s1 = *(const float4*)&SBC[l2 * 16 + 4];
          float4 s2 = *(const float4*)&SBC[l2 * 16 + 8];
          float pre = bb + w0 * s0.x + w1 * s0.y + w2 * s0.z + w3 * s0.w + w4 * s1.x + w5 * s1.y;
          float ex = __expf(pre);
          float delta = (pre > 15.f) ? pre : __logf(1.f + ex);
          sd += delta;
          float dx = delta * bf2f((unsigned short)xr8[i][j]);
          h0 = __expf(delta * A0) * h0 + dx * s1.z;
          h1 = __expf(delta * A1) * h1 + dx * s1.w;
          h2 = __expf(delta * A2) * h2 + dx * s2.x;
          h3 = __expf(delta * A3) * h3 + dx * s2.y;
        }
    }
    size_t o = (((size_t)b * 128 + c) * 192 + d) * 4;
    *(float4*)&hend[o] = make_float4(h0, h1, h2, h3);
    if (fastp) {
      float p1 = __expf(-sd);
      float p2 = p1 * p1;
      *(float4*)&Pbuf[o] = make_float4(p1, p2, p2 * p1, p2 * p2);
    } else {
      *(float4*)&Pbuf[o] = make_float4(__expf(A0 * sd), __expf(A1 * sd), __expf(A2 * sd), __expf(A3 * sd));
    }
  }
  __threadfence();
  grid.sync();

  // ---- P2: cross-chunk combine (6144 sequences on blocks 0..31) ----
  {
    int e = bid * 192 + d;
    if (e < 6144) {
      int b2 = e / 768, r = e - b2 * 768;
      float h = 0.f;
#pragma unroll 4
      for (int cc = 0; cc < 128; ++cc) {
        int a = (b2 * 128 + cc) * 768 + r;
        hinit[a] = h;
        h = Pbuf[a] * h + hend[a];
      }
    }
  }
  __threadfence();
  grid.sync();

  // ---- P3: replay with h_init (SBC resident; x reloaded L2-warm) ----
  for (int sub = 0; sub < 2; ++sub) {
    int c = cp * 2 + sub;
    int s = c >> 6, cl = c & 63;
    int tokbase = b * 8192 + c * 64;
    const unsigned short* xrow = xdh + (((size_t)s * 8 + b) * 192 + d) * 4096 + cl * 64;
    short8_t xr8[8];
#pragma unroll
    for (int i = 0; i < 8; ++i) xr8[i] = *(const short8_t*)(xrow + i * 8);
    const float* SBC = &SBC2[sub][0];
    size_t o = (((size_t)b * 128 + c) * 192 + d) * 4;
    float4 hv = *(const float4*)&hinit[o];
    float h0 = hv.x, h1 = hv.y, h2 = hv.z, h3 = hv.w;
    unsigned short* yout = ybufh + (size_t)tokbase * 192 + d;
    if (fastp) {
#pragma unroll
      for (int i = 0; i < 8; ++i)
#pragma unroll
        for (int j = 0; j < 8; ++j) {
          int l2 = i * 8 + j;
          float4 s0 = *(const float4*)&SBC[l2 * 16 + 0];
          float4 s1 = *(const float4*)&SBC[l2 * 16 + 4];
          float4 s2 = *(const float4*)&SBC[l2 * 16 + 8];
          float4 s3 = *(const float4*)&SBC[l2 * 16 + 12];
          float pre = bb + w0 * s0.x + w1 * s0.y + w2 * s0.z + w3 * s0.w + w4 * s1.x + w5 * s1.y;
          float ex = __expf(pre);
          float opx = 1.f + ex;
          float e1 = __builtin_amdgcn_rcpf(opx);
          float delta = (pre > 15.f) ? pre : __logf(opx);
          float e2 = e1 * e1, e3 = e2 * e1, e4 = e2 * e2;
          float xv = bf2f((unsigned short)xr8[i][j]);
          float dx = delta * xv;
          h0 = e1 * h0 + dx * s1.z;
          h1 = e2 * h1 + dx * s1.w;
          h2 = e3 * h2 + dx * s2.x;
          h3 = e4 * h3 + dx * s2.y;
          yout[(size_t)l2 * 192] = f2bf(h0 * s2.z + h1 * s2.w + h2 * s3.x + h3 * s3.y + Dv * xv);
        }
    } else {
#pragma unroll
      for (int i = 0; i < 8; ++i)
#pragma unroll
        for (int j = 0; j < 8; ++j) {
          int l2 = i * 8 + j;
          float4 s0 = *(const float4*)&SBC[l2 * 16 + 0];
          float4 s1 = *(const float4*)&SBC[l2 * 16 + 4];
          float4 s2 = *(const float4*)&SBC[l2 * 16 + 8];
          float4 s3 = *(const float4*)&SBC[l2 * 16 + 12];
          float pre = bb + w0 * s0.x + w1 * s0.y + w2 * s0.z + w3 * s0.w + w4 * s1.x + w5 * s1.y;
          float ex = __expf(pre);
          float delta = (pre > 15.f) ? pre : __logf(1.f + ex);
          float xv = bf2f((unsigned short)xr8[i][j]);
          float dx = delta * xv;
          h0 = __expf(delta * A0) * h0 + dx * s1.z;
          h1 = __expf(delta * A1) * h1 + dx * s1.w;
          h2 = __expf(delta * A2) * h2 + dx * s2.x;
          h3 = __expf(delta * A3) * h3 + dx * s2.y;
          yout[(size_t)l2 * 192] = f2bf(h0 * s2.z + h1 * s2.w + h2 * s3.x + h3 * s3.y + Dv * xv);
        }
    }
  }
}

// ================= FALLBACK scan trio (round-8 known-good) =================
__global__ __launch_bounds__(192) void k_scanA(const unsigned short* __restrict__ xdh,
                                               const unsigned short* __restrict__ Wxtb,
                                               const float* __restrict__ dtw,
                                               const float* __restrict__ dtbias,
                                               const float* __restrict__ Alog,
                                               float* __restrict__ dtBC,
                                               float* __restrict__ hend,
                                               float* __restrict__ Pbuf) {
  __shared__ __align__(16) unsigned short Xt[64 * 200];
  __shared__ __align__(16) float SBC[64 * 16];
  int c = blockIdx.x & 127, b = blockIdx.x >> 7;
  int s = c >> 6, cl = c & 63;
  int d = threadIdx.x;
  int w = d >> 6, lane = d & 63;
  int tokbase = b * 8192 + c * 64;

  const unsigned short* xrow = xdh + (((size_t)s * 8 + b) * 192 + d) * 4096 + cl * 64;
  short8_t xr8[8];
#pragma unroll
  for (int i = 0; i < 8; ++i) xr8[i] = *(const short8_t*)(xrow + i * 8);
#pragma unroll
  for (int i = 0; i < 8; ++i)
#pragma unroll
    for (int j = 0; j < 8; ++j)
      Xt[(i * 8 + j) * 200 + d] = (unsigned short)xr8[i][j];

  const unsigned short* wb = Wxtb + (size_t)(lane & 15) * 192 + ((lane >> 4) * 8);
  short8_t bfx[6];
#pragma unroll
  for (int ks = 0; ks < 6; ++ks) bfx[ks] = *(const short8_t*)(wb + ks * 32);

  float w0 = dtw[d * 6 + 0], w1 = dtw[d * 6 + 1], w2 = dtw[d * 6 + 2];
  float w3 = dtw[d * 6 + 3], w4 = dtw[d * 6 + 4], w5 = dtw[d * 6 + 5];
  float bb = dtbias[d];
  float4 al = *(const float4*)&Alog[d * 4];
  float A0 = -__expf(al.x), A1 = -__expf(al.y), A2 = -__expf(al.z), A3 = -__expf(al.w);
  __syncthreads();

  int arow = lane & 15, acol = (lane >> 4) * 8;
#pragma unroll
  for (int q = 0; q < 2; ++q) {
    if (q == 1 && w != 0) break;
    int mt = (q == 0) ? w : 3;
    f32x4 a4 = {0.f, 0.f, 0.f, 0.f};
#pragma unroll
    for (int ks = 0; ks < 6; ++ks) {
      short8_t a = *(const short8_t*)&Xt[(mt * 16 + arow) * 200 + acol + ks * 32];
      a4 = __builtin_amdgcn_mfma_f32_16x16x32_bf16(a, bfx[ks], a4, 0, 0, 0);
    }
    int tt = mt * 16 + (lane >> 4) * 4, o = lane & 15;
#pragma unroll
    for (int r = 0; r < 4; ++r) {
      SBC[(tt + r) * 16 + o] = a4[r];
      dtBC[(size_t)(tokbase + tt + r) * 16 + o] = a4[r];
    }
  }
  __syncthreads();

  bool fastp = fabsf(A0 + 1.f) < 1e-4f && fabsf(A1 + 2.f) < 2e-4f &&
               fabsf(A2 + 3.f) < 3e-4f && fabsf(A3 + 4.f) < 4e-4f;
  float h0 = 0.f, h1 = 0.f, h2 = 0.f, h3 = 0.f, sd = 0.f;
  if (fastp) {
#pragma unroll
    for (int i = 0; i < 8; ++i)
#pragma unroll
      for (int j = 0; j < 8; ++j) {
        int l2 = i * 8 + j;
        float4 s0 = *(const float4*)&SBC[l2 * 16 + 0];
        float4 s1 = *(const float4*)&SBC[l2 * 16 + 4];
        float4 s2 = *(const float4*)&SBC[l2 * 16 + 8];
        float pre = bb + w0 * s0.x + w1 * s0.y + w2 * s0.z + w3 * s0.w + w4 * s1.x + w5 * s1.y;
        float ex = __expf(pre);
        float opx = 1.f + ex;
        float e1 = __builtin_amdgcn_rcpf(opx);
        float delta = (pre > 15.f) ? pre : __logf(opx);
        sd += delta;
        float e2 = e1 * e1, e3 = e2 * e1, e4 = e2 * e2;
        float dx = delta * bf2f((unsigned short)xr8[i][j]);
        h0 = e1 * h0 + dx * s1.z;
        h1 = e2 * h1 + dx * s1.w;
        h2 = e3 * h2 + dx * s2.x;
        h3 = e4 * h3 + dx * s2.y;
      }
  } else {
#pragma unroll
    for (int i = 0; i < 8; ++i)
#pragma unroll
      for (int j = 0; j < 8; ++j) {
        int l2 = i * 8 + j;
        float4 s0 = *(const float4*)&SBC[l2 * 16 + 0];
        float4 s1 = *(const float4*)&SBC[l2 * 16 + 4];
        float4 s2 = *(const float4*)&SBC[l2 * 16 + 8];
        float pre = bb + w0 * s0.x + w1 * s0.y + w2 * s0.z + w3 * s0.w + w4 * s1.x + w5 * s1.y;
        float ex = __expf(pre);
        float delta = (pre > 15.f) ? pre : __logf(1.f + ex);
        sd += delta;
        float dx = delta * bf2f((unsigned short)xr8[i][j]);
        h0 = __expf(delta * A0) * h0 + dx * s1.z;
        h1 = __expf(delta * A1) * h1 + dx * s1.w;
        h2 = __expf(delta * A2) * h2 + dx * s2.x;
        h3 = __expf(delta * A3) * h3 + dx * s2.y;
      }
  }
  size_t o = (((size_t)b * 128 + c) * 192 + d) * 4;
  *(float4*)&hend[o] = make_float4(h0, h1, h2, h3);
  if (fastp) {
    float p1 = __expf(-sd);
    float p2 = p1 * p1;
    *(float4*)&Pbuf[o] = make_float4(p1, p2, p2 * p1, p2 * p2);
  } else {
    *(float4*)&Pbuf[o] = make_float4(__expf(A0 * sd), __expf(A1 * sd), __expf(A2 * sd), __expf(A3 * sd));
  }
}

__global__ __launch_bounds__(256) void k_scan2(const float* __restrict__ hend,
                                               const float* __restrict__ Pbuf,
                                               float* __restrict__ hinit) {
  int e = blockIdx.x * 256 + threadIdx.x;
  if (e >= 8 * 768) return;
  int b = e / 768, r = e - b * 768;
  float h = 0.f;
#pragma unroll 4
  for (int c = 0; c < 128; ++c) {
    int a = (b * 128 + c) * 768 + r;
    hinit[a] = h;
    h = Pbuf[a] * h + hend[a];
  }
}

__global__ __launch_bounds__(192) void k_scanB(const unsigned short* __restrict__ xdh,
                                               const float* __restrict__ dtBC,
                                               const float* __restrict__ dtw,
                                               const float* __restrict__ dtbias,
                                               const float* __restrict__ Alog,
                                               const float* __restrict__ Dskip,
                                               const float* __restrict__ hinit,
                                               unsigned short* __restrict__ ybufh) {
  __shared__ __align__(16) float SBC[64 * 16];
  int c = blockIdx.x & 127, b = blockIdx.x >> 7;
  int s = c >> 6, cl = c & 63;
  int d = threadIdx.x;
  float w0 = dtw[d * 6 + 0], w1 = dtw[d * 6 + 1], w2 = dtw[d * 6 + 2];
  float w3 = dtw[d * 6 + 3], w4 = dtw[d * 6 + 4], w5 = dtw[d * 6 + 5];
  float bb = dtbias[d];
  float4 al = *(const float4*)&Alog[d * 4];
  float A0 = -__expf(al.x), A1 = -__expf(al.y), A2 = -__expf(al.z), A3 = -__expf(al.w);
  float Dv = Dskip[d];
  int tokbase = b * 8192 + c * 64;
  for (int idx = d; idx < 1024; idx += 192) SBC[idx] = dtBC[(size_t)tokbase * 16 + idx];
  const unsigned short* xrow = xdh + (((size_t)s * 8 + b) * 192 + d) * 4096 + cl * 64;
  short8_t xr8[8];
#pragma unroll
  for (int i = 0; i < 8; ++i) xr8[i] = *(const short8_t*)(xrow + i * 8);
  size_t o = (((size_t)b * 128 + c) * 192 + d) * 4;
  float4 hv = *(const float4*)&hinit[o];
  float h0 = hv.x, h1 = hv.y, h2 = hv.z, h3 = hv.w;
  bool fastp = fabsf(A0 + 1.f) < 1e-4f && fabsf(A1 + 2.f) < 2e-4f &&
               fabsf(A2 + 3.f) < 3e-4f && fabsf(A3 + 4.f) < 4e-4f;
  __syncthreads();
  unsigned short* yout = ybufh + (size_t)tokbase * 192 + d;
  if (fastp) {
#pragma unroll
    for (int i = 0; i < 8; ++i)
#pragma unroll
      for (int j = 0; j < 8; ++j) {
        int l2 = i * 8 + j;
        float4 s0 = *(const float4*)&SBC[l2 * 16 + 0];
        float4 s1 = *(const float4*)&SBC[l2 * 16 + 4];
        float4 s2 = *(const float4*)&SBC[l2 * 16 + 8];
        float4 s3 = *(const float4*)&SBC[l2 * 16 + 12];
        float pre = bb + w0 * s0.x + w1 * s0.y + w2 * s0.z + w3 * s0.w + w4 * s1.x + w5 * s1.y;
        float ex = __expf(pre);
        float opx = 1.f + ex;
        float e1 = __builtin_amdgcn_rcpf(opx);
        float delta = (pre > 15.f) ? pre : __logf(opx);
        float e2 = e1 * e1, e3 = e2 * e1, e4 = e2 * e2;
        float xv = bf2f((unsigned short)xr8[i][j]);
        float dx = delta * xv;
        h0 = e1 * h0 + dx * s1.z;
        h1 = e2 * h1 + dx * s1.w;
        h2 = e3 * h2 + dx * s2.x;
        h3 = e4 * h3 + dx * s2.y;
        yout[(size_t)l2 * 192] = f2bf(h0 * s2.z + h1 * s2.w + h2 * s3.x + h3 * s3.y + Dv * xv);
      }
  } else {
#pragma unroll
    for (int i = 0; i < 8; ++i)
#pragma unroll
      for (int j = 0; j < 8; ++j) {
        int l2 = i * 8 + j;
        float4 s0 = *(const float4*)&SBC[l2 * 16 + 0];
        float4 s1 = *(const float4*)&SBC[l2 * 16 + 4];
        float4 s2 = *(const float4*)&SBC[l2 * 16 + 8];
        float4 s3 = *(const float4*)&SBC[l2 * 16 + 12];
        float pre = bb + w0 * s0.x + w1 * s0.y + w2 * s0.z + w3 * s0.w + w4 * s1.x + w5 * s1.y;
        float ex = __expf(pre);
        float delta = (pre > 15.f) ? pre : __logf(1.f + ex);
        float xv = bf2f((unsigned short)xr8[i][j]);
        float dx = delta * xv;
        h0 = __expf(delta * A0) * h0 + dx * s1.z;
        h1 = __expf(delta * A1) * h1 + dx * s1.w;
        h2 = __expf(delta * A2) * h2 + dx * s2.x;
        h3 = __expf(delta * A3) * h3 + dx * s2.y;
        yout[(size_t)l2 * 192] = f2bf(h0 * s2.z + h1 * s2.w + h2 * s3.x + h3 * s3.y + Dv * xv);
      }
  }
}

// ---------------- fused LayerNorm + z-gate + out-proj + stream-fusion (bf16 MFMA) ----------------
__global__ __launch_bounds__(384) void k_outfuse(const unsigned short* __restrict__ ybufh,
                                                 const unsigned short* __restrict__ zbufh,
                                                 const float* __restrict__ lng,
                                                 const float* __restrict__ lnb,
                                                 const unsigned short* __restrict__ Mgb,
                                                 float* __restrict__ out) {
  __shared__ __align__(16) unsigned short Xbf[64 * 200];  // [t][k] pad 200
  int tile = blockIdx.x & 63, b = blockIdx.x >> 6;
  int n0 = tile * 64;
  int tid = threadIdx.x;
  int w = tid >> 6, lane = tid & 63;
  float lg0 = lng[lane], lg1 = lng[lane + 64], lg2 = lng[lane + 128];
  float lb0 = lnb[lane], lb1 = lnb[lane + 64], lb2 = lnb[lane + 128];

  const unsigned short* bb = Mgb + ((size_t)(w * 16 + (lane & 15))) * 192 + ((lane >> 4) * 8);
  short8_t bfr[2][6];
#pragma unroll
  for (int kc = 0; kc < 2; ++kc)
#pragma unroll
    for (int ks = 0; ks < 6; ++ks)
      bfr[kc][ks] = *(const short8_t*)(bb + kc * 96 * 192 + ks * 32);

  f32x4 acc[4];
  f32x4 zz = {0.f, 0.f, 0.f, 0.f};
#pragma unroll
  for (int mt = 0; mt < 4; ++mt) acc[mt] = zz;

  int arow = lane & 15, acol = (lane >> 4) * 8;
  for (int kc = 0; kc < 2; ++kc) {
    size_t tokb = (size_t)b * 8192 + (size_t)kc * 4096 + n0;
    if (kc) __syncthreads();
    for (int t = w; t < 64; t += 6) {
      const unsigned short* yr = ybufh + (tokb + t) * 192;
      const unsigned short* zr = zbufh + (tokb + t) * 192;
      float y0 = bf2f(yr[lane]), y1 = bf2f(yr[lane + 64]), y2 = bf2f(yr[lane + 128]);
      float z0 = bf2f(zr[lane]), z1 = bf2f(zr[lane + 64]), z2 = bf2f(zr[lane + 128]);
      float sm = y0 + y1 + y2;
      float sq = y0 * y0 + y1 * y1 + y2 * y2;
#pragma unroll
      for (int off = 32; off; off >>= 1) {
        sm += __shfl_xor(sm, off);
        sq += __shfl_xor(sq, off);
      }
      float mu = sm * (1.f / 192.f);
      float var = sq * (1.f / 192.f) - mu * mu;
      float rstd = rsqrtf(var + EPSV);
      Xbf[t * 200 + lane]       = f2bf(((y0 - mu) * rstd * lg0 + lb0) * siluf(z0));
      Xbf[t * 200 + lane + 64]  = f2bf(((y1 - mu) * rstd * lg1 + lb1) * siluf(z1));
      Xbf[t * 200 + lane + 128] = f2bf(((y2 - mu) * rstd * lg2 + lb2) * siluf(z2));
    }
    __syncthreads();
#pragma unroll
    for (int mt = 0; mt < 4; ++mt) {
      const unsigned short* ap = &Xbf[(mt * 16 + arow) * 200 + acol];
#pragma unroll
      for (int ks = 0; ks < 6; ++ks) {
        short8_t a = *(const short8_t*)(ap + ks * 32);
        acc[mt] = __builtin_amdgcn_mfma_f32_16x16x32_bf16(a, bfr[kc][ks], acc[mt], 0, 0, 0);
      }
    }
  }
  int rowoff = (lane >> 4) * 4;
  float* op = out + ((size_t)b * 96 + w * 16 + (lane & 15)) * 4096 + n0 + rowoff;
#pragma unroll
  for (int mt = 0; mt < 4; ++mt) {
    f32x4 a = acc[mt];
    *(float4*)&op[mt * 16] = make_float4(a[0], a[1], a[2], a[3]);
  }
}

extern "C" void kernel_launch(void* const* d_in, const int* in_sizes, int n_in,
                              void* d_out, int out_size, void* d_ws, size_t ws_size,
                              hipStream_t stream) {
  (void)in_sizes; (void)n_in; (void)out_size; (void)ws_size;
  const float* img  = (const float*)d_in[0];
  const float* text = (const float*)d_in[1];
  const float* Wii  = (const float*)d_in[2];
  const float* Wit  = (const float*)d_in[3];
  const float* cwi  = (const float*)d_in[4];
  const float* cbi  = (const float*)d_in[5];
  const float* bgi  = (const float*)d_in[6];
  const float* bbi  = (const float*)d_in[7];
  const float* bmi  = (const float*)d_in[8];
  const float* bvi  = (const float*)d_in[9];
  const float* cwt  = (const float*)d_in[10];
  const float* cbt  = (const float*)d_in[11];
  const float* bgt  = (const float*)d_in[12];
  const float* bbt  = (const float*)d_in[13];
  const float* bmt  = (const float*)d_in[14];
  const float* bvt  = (const float*)d_in[15];
  const float* xpw  = (const float*)d_in[16];
  const float* dtw  = (const float*)d_in[17];
  const float* dtb  = (const float*)d_in[18];
  const float* Alog = (const float*)d_in[19];
  const float* Dsk  = (const float*)d_in[20];
  const float* lng  = (const float*)d_in[21];
  const float* lnb  = (const float*)d_in[22];
  const float* Wout = (const float*)d_in[23];
  const float* Wfus = (const float*)d_in[24];

  float* ws    = (float*)d_ws;
  unsigned short* xsph  = (unsigned short*)ws;
  unsigned short* zbufh = (unsigned short*)(ws + N_XSP);
  unsigned short* xdh   = (unsigned short*)(ws + N_XSP + N_ZBUF);
  float* dtBC  = ws + N_XSP + N_ZBUF + N_XD;
  float* hend  = dtBC + N_DTBC;
  float* Pbuf  = hend + N_STATE;
  float* hinit = Pbuf + N_STATE;
  unsigned short* Mgb  = (unsigned short*)(hinit + N_STATE);
  unsigned short* Wxtb = Mgb + 36864;
  unsigned short* wbi  = Wxtb + 3072;
  unsigned short* wbt  = wbi + 36864;
  unsigned short* ybufh = xsph;  // xsph dead after k_conv
  float* out   = (float*)d_out;

  hipLaunchKernelGGL(k_prep, dim3(444), dim3(256), 0, stream, Wout, Wfus, Wii, Wit, xpw, Mgb, wbi, wbt, Wxtb);
  hipLaunchKernelGGL(k_inproj, dim3(1024), dim3(256), 0, stream, img, text, wbi, wbt, xsph, zbufh);
  hipLaunchKernelGGL(k_conv, dim3(1536), dim3(256), 0, stream, xsph,
                     cwi, cbi, bgi, bbi, bmi, bvi, cwt, cbt, bgt, bbt, bmt, bvt, xdh);

  // cooperative fused scan if co-residency is guaranteed; else fallback trio
  bool coop = false;
  int maxb = 0;
  if (hipOccupancyMaxActiveBlocksPerMultiprocessor(&maxb, k_scanfused2, 192, 0) == hipSuccess &&
      maxb >= 2) {
    void* kargs[] = {(void*)&xdh, (void*)&Wxtb, (void*)&dtw, (void*)&dtb, (void*)&Alog,
                     (void*)&Dsk, (void*)&hend, (void*)&Pbuf, (void*)&hinit, (void*)&ybufh};
    if (hipLaunchCooperativeKernel((void*)k_scanfused2, dim3(512), dim3(192), kargs, 0, stream)
        == hipSuccess)
      coop = true;
  }
  if (!coop) {
    hipLaunchKernelGGL(k_scanA, dim3(1024), dim3(192), 0, stream, xdh, Wxtb, dtw, dtb, Alog, dtBC, hend, Pbuf);
    hipLaunchKernelGGL(k_scan2, dim3(24), dim3(256), 0, stream, hend, Pbuf, hinit);
    hipLaunchKernelGGL(k_scanB, dim3(1024), dim3(192), 0, stream, xdh, dtBC, dtw, dtb, Alog, Dsk, hinit, ybufh);
  }

  hipLaunchKernelGGL(k_outfuse, dim3(512), dim3(384), 0, stream, ybufh, zbufh, lng, lnb, Mgb, out);
}

// Round 11
// 144.727 us; speedup vs baseline: 3.6288x; 1.0156x over previous
//
#include <hip/hip_runtime.h>
#include <math.h>

#define EPSV 1e-5f

typedef __attribute__((ext_vector_type(8))) short short8_t;   // 8 bf16 (4 VGPRs)
typedef __attribute__((ext_vector_type(4))) float f32x4;      // MFMA acc

// ---------------- workspace layout ----------------
// xsp slot : bf16 x-branch (2,8,192,4096) d-major (conv in) | reused as bf16 ybuf
// zbuf slot: bf16 z (8,8192,192) token-major
// xd  slot : bf16 conv output (2,8,192,4096) d-major
// dtBC : (65536,16) fp32; hend/Pbuf/hinit : (8,128,192,4)
// Mgb: bf16 [2*96][192]; Wxtb: bf16 [16][192]; wbi/wbt: bf16 W_in [384][96]
#define N_XSP   12582912
#define N_ZBUF  12582912
#define N_XD    12582912
#define N_DTBC  1048576
#define N_STATE 786432

__device__ __forceinline__ float siluf(float v) {
  return v / (1.f + __expf(-v));
}

__device__ __forceinline__ unsigned short f2bf(float f) {  // RTNE fp32->bf16
  unsigned int u = __float_as_uint(f);
  u += 0x7fffu + ((u >> 16) & 1u);
  return (unsigned short)(u >> 16);
}

__device__ __forceinline__ float bf2f(unsigned short h) {
  return __uint_as_float(((unsigned int)h) << 16);
}

// ---------------- prep: Mg(bf16) + bf16 W_in + bf16 x_proj ----------------
__global__ __launch_bounds__(256) void k_prep(const float* __restrict__ Wout,
                                              const float* __restrict__ Wf,
                                              const float* __restrict__ Wii,
                                              const float* __restrict__ Wit,
                                              const float* __restrict__ xpw,
                                              unsigned short* __restrict__ Mgb,
                                              unsigned short* __restrict__ wbi,
                                              unsigned short* __restrict__ wbt,
                                              unsigned short* __restrict__ Wxtb) {
  int e = blockIdx.x * 256 + threadIdx.x;
  if (e < 36864) {                     // Mg[k][o] = sum_j Wf[o][half*96+j]*Wout[j][k%192]
    int k = e / 96, o = e - k * 96;
    int half = (k >= 192) ? 1 : 0;
    int c = k - half * 192;
    const float* wfr = Wf + o * 192 + half * 96;
    float acc = 0.f;
#pragma unroll 4
    for (int j = 0; j < 96; ++j) acc += wfr[j] * Wout[j * 192 + c];
    Mgb[(half * 96 + o) * 192 + c] = f2bf(acc);
  } else if (e < 73728) {
    int i = e - 36864;
    wbi[i] = f2bf(Wii[i]);
  } else if (e < 110592) {
    int i = e - 73728;
    wbt[i] = f2bf(Wit[i]);
  } else if (e < 113664) {             // Wxtb[o][c] bf16, rows 14,15 zero
    int i = e - 110592;
    int o = i / 192;
    Wxtb[i] = (o < 14) ? f2bf(xpw[i]) : (unsigned short)0;
  }
}

// ---------------- in_proj via bf16 MFMA (nt-sequential, 4 blocks/CU) ----------------
__global__ __launch_bounds__(256, 4) void k_inproj(const float* __restrict__ img,
                                                   const float* __restrict__ text,
                                                   const unsigned short* __restrict__ wbi,
                                                   const unsigned short* __restrict__ wbt,
                                                   unsigned short* __restrict__ xsph,
                                                   unsigned short* __restrict__ zbufh) {
  __shared__ __align__(16) unsigned short Xbf[64 * 104];  // [t][k] pad 104
  int bx = blockIdx.x;
  int tile = bx & 63, b = (bx >> 6) & 7, s = bx >> 9;
  int n0 = tile * 64;
  int tid = threadIdx.x;
  int w = tid >> 6, lane = tid & 63;
  const float* src = s ? text : img;
  const unsigned short* wsel = s ? wbt : wbi;

  for (int idx = tid; idx < 6144; idx += 256) {
    int c = idx >> 6, t = idx & 63;
    Xbf[t * 104 + c] = f2bf(src[((size_t)b * 96 + c) * 4096 + n0 + t]);
  }
  __syncthreads();

  int arow = lane & 15;
  int acol = (lane >> 4) * 8;
  // hoist A-fragments once (12 x short8 = 48 VGPR)
  short8_t af[4][3];
#pragma unroll
  for (int mt = 0; mt < 4; ++mt) {
    const unsigned short* ap = &Xbf[(mt * 16 + arow) * 104 + acol];
    af[mt][0] = *(const short8_t*)(ap);
    af[mt][1] = *(const short8_t*)(ap + 32);
    af[mt][2] = *(const short8_t*)(ap + 64);
  }

  const unsigned short* wbase = wsel + ((size_t)(w * 96 + (lane & 15))) * 96 + ((lane >> 4) * 8);
  int rowoff = (lane >> 4) * 4;
  size_t tokb = (size_t)b * 8192 + (size_t)s * 4096 + n0;

  for (int nt = 0; nt < 6; ++nt) {
    short8_t b0 = *(const short8_t*)(wbase + nt * 16 * 96 + 0);
    short8_t b1 = *(const short8_t*)(wbase + nt * 16 * 96 + 32);
    short8_t b2 = *(const short8_t*)(wbase + nt * 16 * 96 + 64);
    f32x4 acc[4];
    f32x4 zz = {0.f, 0.f, 0.f, 0.f};
#pragma unroll
    for (int mt = 0; mt < 4; ++mt) acc[mt] = zz;
#pragma unroll
    for (int mt = 0; mt < 4; ++mt) {
      acc[mt] = __builtin_amdgcn_mfma_f32_16x16x32_bf16(af[mt][0], b0, acc[mt], 0, 0, 0);
      acc[mt] = __builtin_amdgcn_mfma_f32_16x16x32_bf16(af[mt][1], b1, acc[mt], 0, 0, 0);
      acc[mt] = __builtin_amdgcn_mfma_f32_16x16x32_bf16(af[mt][2], b2, acc[mt], 0, 0, 0);
    }
    if (w < 2) {   // x half -> d-major bf16
      int d = w * 96 + nt * 16 + (lane & 15);
      unsigned short* xp = xsph + (((size_t)s * 8 + b) * 192 + d) * 4096 + n0 + rowoff;
#pragma unroll
      for (int mt = 0; mt < 4; ++mt) {
        f32x4 a = acc[mt];
        uint2 pk;
        pk.x = (unsigned int)f2bf(a[0]) | ((unsigned int)f2bf(a[1]) << 16);
        pk.y = (unsigned int)f2bf(a[2]) | ((unsigned int)f2bf(a[3]) << 16);
        *(uint2*)&xp[mt * 16] = pk;
      }
    } else {       // z half -> token-major bf16
      int ch = (w - 2) * 96 + nt * 16 + (lane & 15);
#pragma unroll
      for (int mt = 0; mt < 4; ++mt) {
        f32x4 a = acc[mt];
        unsigned short* zp = zbufh + (tokb + mt * 16 + rowoff) * 192 + ch;
        zp[0] = f2bf(a[0]); zp[192] = f2bf(a[1]); zp[384] = f2bf(a[2]); zp[576] = f2bf(a[3]);
      }
    }
  }
}

// ---------------- depthwise 3x3 conv + BN + SiLU: bf16 in/out ----------------
__global__ __launch_bounds__(256) void k_conv(
    const unsigned short* __restrict__ xsph,
    const float* __restrict__ cwi, const float* __restrict__ cbi,
    const float* __restrict__ bgi, const float* __restrict__ bbi,
    const float* __restrict__ bmi, const float* __restrict__ bvi,
    const float* __restrict__ cwt, const float* __restrict__ cbt,
    const float* __restrict__ bgt, const float* __restrict__ bbt,
    const float* __restrict__ bmt, const float* __restrict__ bvt,
    unsigned short* __restrict__ xdh) {
  int bid = blockIdx.x;
  int img = bid / 96;                 // 0..15
  int d0 = (bid - img * 96) * 2;
  int widx = threadIdx.x >> 6;
  int lane = threadIdx.x & 63;
  int d = d0 + (widx >> 1);
  int half = widx & 1;
  int s = img >> 3;
  const float* cw = s ? cwt : cwi;
  const float* cb = s ? cbt : cbi;
  const float* bg = s ? bgt : bgi;
  const float* bb2 = s ? bbt : bbi;
  const float* bm = s ? bmt : bmi;
  const float* bv = s ? bvt : bvi;
  const unsigned short* src = xsph + ((size_t)img * 192 + d) * 4096;
  unsigned short* dst = xdh + ((size_t)img * 192 + d) * 4096;
  float c0 = cw[d * 9 + 0], c1 = cw[d * 9 + 1], c2 = cw[d * 9 + 2];
  float c3 = cw[d * 9 + 3], c4 = cw[d * 9 + 4], c5 = cw[d * 9 + 5];
  float c6 = cw[d * 9 + 6], c7 = cw[d * 9 + 7], c8 = cw[d * 9 + 8];
  float sc = bg[d] * rsqrtf(bv[d] + EPSV);
  float eb = (cb[d] - bm[d]) * sc + bb2[d];
  int h0 = half * 32;
  float pc = (h0 > 0) ? bf2f(src[(h0 - 1) * 64 + lane]) : 0.f;
  float cc = bf2f(src[h0 * 64 + lane]);
  float nc = bf2f(src[(h0 + 1) * 64 + lane]);
  float t;
  t = __shfl_up(pc, 1);  float pl = (lane == 0) ? 0.f : t;
  t = __shfl_down(pc, 1); float pr = (lane == 63) ? 0.f : t;
  t = __shfl_up(cc, 1);  float cl = (lane == 0) ? 0.f : t;
  t = __shfl_down(cc, 1); float cr = (lane == 63) ? 0.f : t;
#pragma unroll 4
  for (int i = 0; i < 32; ++i) {
    int h = h0 + i;
    float fut = (h + 2 <= 63) ? bf2f(src[(h + 2) * 64 + lane]) : 0.f;
    t = __shfl_up(nc, 1);  float nl = (lane == 0) ? 0.f : t;
    t = __shfl_down(nc, 1); float nr = (lane == 63) ? 0.f : t;
    float a = pl * c0 + pc * c1 + pr * c2
            + cl * c3 + cc * c4 + cr * c5
            + nl * c6 + nc * c7 + nr * c8;
    a = a * sc + eb;
    dst[h * 64 + lane] = f2bf(a / (1.f + __expf(-a)));
    pl = cl; pc = cc; pr = cr;
    cl = nl; cc = nc; cr = nr;
    nc = fut;
  }
}

// ---------------- scan pass A: staged-MFMA x_proj + chunk scan (low LDS) ----------------
__global__ __launch_bounds__(192) void k_scanA(const unsigned short* __restrict__ xdh,
                                               const unsigned short* __restrict__ Wxtb,
                                               const float* __restrict__ dtw,
                                               const float* __restrict__ dtbias,
                                               const float* __restrict__ Alog,
                                               float* __restrict__ dtBC,
                                               float* __restrict__ hend,
                                               float* __restrict__ Pbuf) {
  __shared__ __align__(16) unsigned short Xt16[16 * 200];  // one m-tile staging
  __shared__ __align__(16) float SBC[64 * 16];
  int c = blockIdx.x & 127, b = blockIdx.x >> 7;
  int s = c >> 6, cl = c & 63;
  int d = threadIdx.x;
  int w = d >> 6, lane = d & 63;
  int tokbase = b * 8192 + c * 64;

  const unsigned short* xrow = xdh + (((size_t)s * 8 + b) * 192 + d) * 4096 + cl * 64;
  short8_t xr8[8];
#pragma unroll
  for (int i = 0; i < 8; ++i) xr8[i] = *(const short8_t*)(xrow + i * 8);

  const unsigned short* wb = Wxtb + (size_t)(lane & 15) * 192 + ((lane >> 4) * 8);
  short8_t bfx[6];
#pragma unroll
  for (int ks = 0; ks < 6; ++ks) bfx[ks] = *(const short8_t*)(wb + ks * 32);

  float w0 = dtw[d * 6 + 0], w1 = dtw[d * 6 + 1], w2 = dtw[d * 6 + 2];
  float w3 = dtw[d * 6 + 3], w4 = dtw[d * 6 + 4], w5 = dtw[d * 6 + 5];
  float bb = dtbias[d];
  float4 al = *(const float4*)&Alog[d * 4];
  float A0 = -__expf(al.x), A1 = -__expf(al.y), A2 = -__expf(al.z), A3 = -__expf(al.w);

  int arow = lane & 15, acol = (lane >> 4) * 8;
  // 4 staged rounds: stage 16 tokens -> one wave does the 16x16 x_proj MFMA tile
#pragma unroll
  for (int r = 0; r < 4; ++r) {
    __syncthreads();   // previous round's MFMA reads of Xt16 complete
#pragma unroll
    for (int tt = 0; tt < 16; ++tt) {
      int i = (r * 16 + tt) >> 3, j = tt & 7;
      Xt16[tt * 200 + d] = (unsigned short)xr8[i][j];
    }
    __syncthreads();
    if (w == (r % 3)) {
      f32x4 a4 = {0.f, 0.f, 0.f, 0.f};
#pragma unroll
      for (int ks = 0; ks < 6; ++ks) {
        short8_t a = *(const short8_t*)&Xt16[arow * 200 + acol + ks * 32];
        a4 = __builtin_amdgcn_mfma_f32_16x16x32_bf16(a, bfx[ks], a4, 0, 0, 0);
      }
      int tt0 = r * 16 + (lane >> 4) * 4, o = lane & 15;
#pragma unroll
      for (int rr = 0; rr < 4; ++rr) {
        SBC[(tt0 + rr) * 16 + o] = a4[rr];
        dtBC[(size_t)(tokbase + tt0 + rr) * 16 + o] = a4[rr];
      }
    }
  }
  __syncthreads();

  bool fastp = fabsf(A0 + 1.f) < 1e-4f && fabsf(A1 + 2.f) < 2e-4f &&
               fabsf(A2 + 3.f) < 3e-4f && fabsf(A3 + 4.f) < 4e-4f;
  float h0 = 0.f, h1 = 0.f, h2 = 0.f, h3 = 0.f, sd = 0.f;
  if (fastp) {
#pragma unroll
    for (int i = 0; i < 8; ++i)
#pragma unroll
      for (int j = 0; j < 8; ++j) {
        int l2 = i * 8 + j;
        float4 s0 = *(const float4*)&SBC[l2 * 16 + 0];
        float4 s1 = *(const float4*)&SBC[l2 * 16 + 4];
        float4 s2 = *(const float4*)&SBC[l2 * 16 + 8];
        float pre = bb + w0 * s0.x + w1 * s0.y + w2 * s0.z + w3 * s0.w + w4 * s1.x + w5 * s1.y;
        float ex = __expf(pre);
        float opx = 1.f + ex;
        float e1 = __builtin_amdgcn_rcpf(opx);
        float delta = (pre > 15.f) ? pre : __logf(opx);
        sd += delta;
        float e2 = e1 * e1, e3 = e2 * e1, e4 = e2 * e2;
        float dx = delta * bf2f((unsigned short)xr8[i][j]);
        h0 = e1 * h0 + dx * s1.z;
        h1 = e2 * h1 + dx * s1.w;
        h2 = e3 * h2 + dx * s2.x;
        h3 = e4 * h3 + dx * s2.y;
      }
  } else {
#pragma unroll
    for (int i = 0; i < 8; ++i)
#pragma unroll
      for (int j = 0; j < 8; ++j) {
        int l2 = i * 8 + j;
        float4 s0 = *(const float4*)&SBC[l2 * 16 + 0];
        float4 s1 = *(const float4*)&SBC[l2 * 16 + 4];
        float4 s2 = *(const float4*)&SBC[l2 * 16 + 8];
        float pre = bb + w0 * s0.x + w1 * s0.y + w2 * s0.z + w3 * s0.w + w4 * s1.x + w5 * s1.y;
        float ex = __expf(pre);
        float delta = (pre > 15.f) ? pre : __logf(1.f + ex);
        sd += delta;
        float dx = delta * bf2f((unsigned short)xr8[i][j]);
        h0 = __expf(delta * A0) * h0 + dx * s1.z;
        h1 = __expf(delta * A1) * h1 + dx * s1.w;
        h2 = __expf(delta * A2) * h2 + dx * s2.x;
        h3 = __expf(delta * A3) * h3 + dx * s2.y;
      }
  }
  size_t o = (((size_t)b * 128 + c) * 192 + d) * 4;
  *(float4*)&hend[o] = make_float4(h0, h1, h2, h3);
  if (fastp) {
    float p1 = __expf(-sd);
    float p2 = p1 * p1;
    *(float4*)&Pbuf[o] = make_float4(p1, p2, p2 * p1, p2 * p2);
  } else {
    *(float4*)&Pbuf[o] = make_float4(__expf(A0 * sd), __expf(A1 * sd), __expf(A2 * sd), __expf(A3 * sd));
  }
}

// ---------------- scan pass 2: cross-chunk combine (128 chunks) ----------------
__global__ __launch_bounds__(256) void k_scan2(const float* __restrict__ hend,
                                               const float* __restrict__ Pbuf,
                                               float* __restrict__ hinit) {
  int e = blockIdx.x * 256 + threadIdx.x;
  if (e >= 8 * 768) return;
  int b = e / 768, r = e - b * 768;
  float h = 0.f;
#pragma unroll 4
  for (int c = 0; c < 128; ++c) {
    int a = (b * 128 + c) * 768 + r;
    hinit[a] = h;
    h = Pbuf[a] * h + hend[a];
  }
}

// ---------------- scan pass B: replay with h_init, write y bf16 token-major ----------------
__global__ __launch_bounds__(192) void k_scanB(const unsigned short* __restrict__ xdh,
                                               const float* __restrict__ dtBC,
                                               const float* __restrict__ dtw,
                                               const float* __restrict__ dtbias,
                                               const float* __restrict__ Alog,
                                               const float* __restrict__ Dskip,
                                               const float* __restrict__ hinit,
                                               unsigned short* __restrict__ ybufh) {
  __shared__ __align__(16) float SBC[64 * 16];
  int c = blockIdx.x & 127, b = blockIdx.x >> 7;
  int s = c >> 6, cl = c & 63;
  int d = threadIdx.x;
  float w0 = dtw[d * 6 + 0], w1 = dtw[d * 6 + 1], w2 = dtw[d * 6 + 2];
  float w3 = dtw[d * 6 + 3], w4 = dtw[d * 6 + 4], w5 = dtw[d * 6 + 5];
  float bb = dtbias[d];
  float4 al = *(const float4*)&Alog[d * 4];
  float A0 = -__expf(al.x), A1 = -__expf(al.y), A2 = -__expf(al.z), A3 = -__expf(al.w);
  float Dv = Dskip[d];
  int tokbase = b * 8192 + c * 64;
  for (int idx = d; idx < 1024; idx += 192) SBC[idx] = dtBC[(size_t)tokbase * 16 + idx];
  const unsigned short* xrow = xdh + (((size_t)s * 8 + b) * 192 + d) * 4096 + cl * 64;
  short8_t xr8[8];
#pragma unroll
  for (int i = 0; i < 8; ++i) xr8[i] = *(const short8_t*)(xrow + i * 8);
  size_t o = (((size_t)b * 128 + c) * 192 + d) * 4;
  float4 hv = *(const float4*)&hinit[o];
  float h0 = hv.x, h1 = hv.y, h2 = hv.z, h3 = hv.w;
  bool fastp = fabsf(A0 + 1.f) < 1e-4f && fabsf(A1 + 2.f) < 2e-4f &&
               fabsf(A2 + 3.f) < 3e-4f && fabsf(A3 + 4.f) < 4e-4f;
  __syncthreads();
  unsigned short* yout = ybufh + (size_t)tokbase * 192 + d;
  if (fastp) {
#pragma unroll
    for (int i = 0; i < 8; ++i)
#pragma unroll
      for (int j = 0; j < 8; ++j) {
        int l2 = i * 8 + j;
        float4 s0 = *(const float4*)&SBC[l2 * 16 + 0];
        float4 s1 = *(const float4*)&SBC[l2 * 16 + 4];
        float4 s2 = *(const float4*)&SBC[l2 * 16 + 8];
        float4 s3 = *(const float4*)&SBC[l2 * 16 + 12];
        float pre = bb + w0 * s0.x + w1 * s0.y + w2 * s0.z + w3 * s0.w + w4 * s1.x + w5 * s1.y;
        float ex = __expf(pre);
        float opx = 1.f + ex;
        float e1 = __builtin_amdgcn_rcpf(opx);
        float delta = (pre > 15.f) ? pre : __logf(opx);
        float e2 = e1 * e1, e3 = e2 * e1, e4 = e2 * e2;
        float xv = bf2f((unsigned short)xr8[i][j]);
        float dx = delta * xv;
        h0 = e1 * h0 + dx * s1.z;
        h1 = e2 * h1 + dx * s1.w;
        h2 = e3 * h2 + dx * s2.x;
        h3 = e4 * h3 + dx * s2.y;
        yout[(size_t)l2 * 192] = f2bf(h0 * s2.z + h1 * s2.w + h2 * s3.x + h3 * s3.y + Dv * xv);
      }
  } else {
#pragma unroll
    for (int i = 0; i < 8; ++i)
#pragma unroll
      for (int j = 0; j < 8; ++j) {
        int l2 = i * 8 + j;
        float4 s0 = *(const float4*)&SBC[l2 * 16 + 0];
        float4 s1 = *(const float4*)&SBC[l2 * 16 + 4];
        float4 s2 = *(const float4*)&SBC[l2 * 16 + 8];
        float4 s3 = *(const float4*)&SBC[l2 * 16 + 12];
        float pre = bb + w0 * s0.x + w1 * s0.y + w2 * s0.z + w3 * s0.w + w4 * s1.x + w5 * s1.y;
        float ex = __expf(pre);
        float delta = (pre > 15.f) ? pre : __logf(1.f + ex);
        float xv = bf2f((unsigned short)xr8[i][j]);
        float dx = delta * xv;
        h0 = __expf(delta * A0) * h0 + dx * s1.z;
        h1 = __expf(delta * A1) * h1 + dx * s1.w;
        h2 = __expf(delta * A2) * h2 + dx * s2.x;
        h3 = __expf(delta * A3) * h3 + dx * s2.y;
        yout[(size_t)l2 * 192] = f2bf(h0 * s2.z + h1 * s2.w + h2 * s3.x + h3 * s3.y + Dv * xv);
      }
  }
}

// ---------------- fused LayerNorm + z-gate + out-proj + stream-fusion (bf16 MFMA) ----------------
__global__ __launch_bounds__(384) void k_outfuse(const unsigned short* __restrict__ ybufh,
                                                 const unsigned short* __restrict__ zbufh,
                                                 const float* __restrict__ lng,
                                                 const float* __restrict__ lnb,
                                                 const unsigned short* __restrict__ Mgb,
                                                 float* __restrict__ out) {
  __shared__ __align__(16) unsigned short Xbf[64 * 200];  // [t][k] pad 200
  int tile = blockIdx.x & 63, b = blockIdx.x >> 6;
  int n0 = tile * 64;
  int tid = threadIdx.x;
  int w = tid >> 6, lane = tid & 63;
  float lg0 = lng[lane], lg1 = lng[lane + 64], lg2 = lng[lane + 128];
  float lb0 = lnb[lane], lb1 = lnb[lane + 64], lb2 = lnb[lane + 128];

  const unsigned short* bb = Mgb + ((size_t)(w * 16 + (lane & 15))) * 192 + ((lane >> 4) * 8);
  short8_t bfr[2][6];
#pragma unroll
  for (int kc = 0; kc < 2; ++kc)
#pragma unroll
    for (int ks = 0; ks < 6; ++ks)
      bfr[kc][ks] = *(const short8_t*)(bb + kc * 96 * 192 + ks * 32);

  f32x4 acc[4];
  f32x4 zz = {0.f, 0.f, 0.f, 0.f};
#pragma unroll
  for (int mt = 0; mt < 4; ++mt) acc[mt] = zz;

  int arow = lane & 15, acol = (lane >> 4) * 8;
  for (int kc = 0; kc < 2; ++kc) {
    size_t tokb = (size_t)b * 8192 + (size_t)kc * 4096 + n0;
    if (kc) __syncthreads();
    for (int t = w; t < 64; t += 6) {
      const unsigned short* yr = ybufh + (tokb + t) * 192;
      const unsigned short* zr = zbufh + (tokb + t) * 192;
      float y0 = bf2f(yr[lane]), y1 = bf2f(yr[lane + 64]), y2 = bf2f(yr[lane + 128]);
      float z0 = bf2f(zr[lane]), z1 = bf2f(zr[lane + 64]), z2 = bf2f(zr[lane + 128]);
      float sm = y0 + y1 + y2;
      float sq = y0 * y0 + y1 * y1 + y2 * y2;
#pragma unroll
      for (int off = 32; off; off >>= 1) {
        sm += __shfl_xor(sm, off);
        sq += __shfl_xor(sq, off);
      }
      float mu = sm * (1.f / 192.f);
      float var = sq * (1.f / 192.f) - mu * mu;
      float rstd = rsqrtf(var + EPSV);
      Xbf[t * 200 + lane]       = f2bf(((y0 - mu) * rstd * lg0 + lb0) * siluf(z0));
      Xbf[t * 200 + lane + 64]  = f2bf(((y1 - mu) * rstd * lg1 + lb1) * siluf(z1));
      Xbf[t * 200 + lane + 128] = f2bf(((y2 - mu) * rstd * lg2 + lb2) * siluf(z2));
    }
    __syncthreads();
#pragma unroll
    for (int mt = 0; mt < 4; ++mt) {
      const unsigned short* ap = &Xbf[(mt * 16 + arow) * 200 + acol];
#pragma unroll
      for (int ks = 0; ks < 6; ++ks) {
        short8_t a = *(const short8_t*)(ap + ks * 32);
        acc[mt] = __builtin_amdgcn_mfma_f32_16x16x32_bf16(a, bfr[kc][ks], acc[mt], 0, 0, 0);
      }
    }
  }
  int rowoff = (lane >> 4) * 4;
  float* op = out + ((size_t)b * 96 + w * 16 + (lane & 15)) * 4096 + n0 + rowoff;
#pragma unroll
  for (int mt = 0; mt < 4; ++mt) {
    f32x4 a = acc[mt];
    *(float4*)&op[mt * 16] = make_float4(a[0], a[1], a[2], a[3]);
  }
}

extern "C" void kernel_launch(void* const* d_in, const int* in_sizes, int n_in,
                              void* d_out, int out_size, void* d_ws, size_t ws_size,
                              hipStream_t stream) {
  (void)in_sizes; (void)n_in; (void)out_size; (void)ws_size;
  const float* img  = (const float*)d_in[0];
  const float* text = (const float*)d_in[1];
  const float* Wii  = (const float*)d_in[2];
  const float* Wit  = (const float*)d_in[3];
  const float* cwi  = (const float*)d_in[4];
  const float* cbi  = (const float*)d_in[5];
  const float* bgi  = (const float*)d_in[6];
  const float* bbi  = (const float*)d_in[7];
  const float* bmi  = (const float*)d_in[8];
  const float* bvi  = (const float*)d_in[9];
  const float* cwt  = (const float*)d_in[10];
  const float* cbt  = (const float*)d_in[11];
  const float* bgt  = (const float*)d_in[12];
  const float* bbt  = (const float*)d_in[13];
  const float* bmt  = (const float*)d_in[14];
  const float* bvt  = (const float*)d_in[15];
  const float* xpw  = (const float*)d_in[16];
  const float* dtw  = (const float*)d_in[17];
  const float* dtb  = (const float*)d_in[18];
  const float* Alog = (const float*)d_in[19];
  const float* Dsk  = (const float*)d_in[20];
  const float* lng  = (const float*)d_in[21];
  const float* lnb  = (const float*)d_in[22];
  const float* Wout = (const float*)d_in[23];
  const float* Wfus = (const float*)d_in[24];

  float* ws    = (float*)d_ws;
  unsigned short* xsph  = (unsigned short*)ws;
  unsigned short* zbufh = (unsigned short*)(ws + N_XSP);
  unsigned short* xdh   = (unsigned short*)(ws + N_XSP + N_ZBUF);
  float* dtBC  = ws + N_XSP + N_ZBUF + N_XD;
  float* hend  = dtBC + N_DTBC;
  float* Pbuf  = hend + N_STATE;
  float* hinit = Pbuf + N_STATE;
  unsigned short* Mgb  = (unsigned short*)(hinit + N_STATE);
  unsigned short* Wxtb = Mgb + 36864;
  unsigned short* wbi  = Wxtb + 3072;
  unsigned short* wbt  = wbi + 36864;
  unsigned short* ybufh = xsph;  // xsph dead after k_conv
  float* out   = (float*)d_out;

  hipLaunchKernelGGL(k_prep, dim3(444), dim3(256), 0, stream, Wout, Wfus, Wii, Wit, xpw, Mgb, wbi, wbt, Wxtb);
  hipLaunchKernelGGL(k_inproj, dim3(1024), dim3(256), 0, stream, img, text, wbi, wbt, xsph, zbufh);
  hipLaunchKernelGGL(k_conv, dim3(1536), dim3(256), 0, stream, xsph,
                     cwi, cbi, bgi, bbi, bmi, bvi, cwt, cbt, bgt, bbt, bmt, bvt, xdh);
  hipLaunchKernelGGL(k_scanA, dim3(1024), dim3(192), 0, stream, xdh, Wxtb, dtw, dtb, Alog, dtBC, hend, Pbuf);
  hipLaunchKernelGGL(k_scan2, dim3(24), dim3(256), 0, stream, hend, Pbuf, hinit);
  hipLaunchKernelGGL(k_scanB, dim3(1024), dim3(192), 0, stream, xdh, dtBC, dtw, dtb, Alog, Dsk, hinit, ybufh);
  hipLaunchKernelGGL(k_outfuse, dim3(512), dim3(384), 0, stream, ybufh, zbufh, lng, lnb, Mgb, out);
}